// Round 1
// baseline (1000.439 us; speedup 1.0000x reference)
//
#include <hip/hip_runtime.h>

// CausalGCN forward on MI355X. fp32 in/out; internal N x 128 tensors bf16.
// R8: MFMA bf16 GEMMs (W split hi+lo bf16 -> ~fp32 weight precision),
//     multi-block scan, hist+deg merged, degW folded into eatt2.

typedef unsigned short bf16_t;
typedef unsigned int   uint32;
typedef __attribute__((ext_vector_type(8))) short   bf16x8;
typedef __attribute__((ext_vector_type(4))) float   f32x4;

__device__ __forceinline__ float b2f(bf16_t v){ return __uint_as_float(((uint32)v) << 16); }
__device__ __forceinline__ bf16_t f2b(float f){
    uint32 u = __float_as_uint(f);
    return (bf16_t)((u + 0x7fffu + ((u >> 16) & 1u)) >> 16);   // RNE
}
__device__ __forceinline__ uint32 pack2(float lo, float hi){
    return (uint32)f2b(lo) | ((uint32)f2b(hi) << 16);
}
__device__ __forceinline__ float lo16(uint32 u){ return __uint_as_float(u << 16); }
__device__ __forceinline__ float hi16(uint32 u){ return __uint_as_float(u & 0xffff0000u); }

// ---------- BN stats ----------
__global__ void k_statsF(const float* __restrict__ a, float* __restrict__ st, int n){
    int tid = threadIdx.x;
    int feat = tid & 127;
    int row = blockIdx.x * 2 + (tid >> 7);
    float s = 0.f, sq = 0.f;
    for (; row < n; row += gridDim.x * 2){
        float v = a[(size_t)row * 128 + feat];
        s += v; sq += v * v;
    }
    atomicAdd(&st[feat], s);
    atomicAdd(&st[128 + feat], sq);
}
__global__ void k_statsB(const bf16_t* __restrict__ a, float* __restrict__ st, int n){
    int tid = threadIdx.x;
    int feat = tid & 127;
    int row = blockIdx.x * 2 + (tid >> 7);
    float s = 0.f, sq = 0.f;
    for (; row < n; row += gridDim.x * 2){
        float v = b2f(a[(size_t)row * 128 + feat]);
        s += v; sq += v * v;
    }
    atomicAdd(&st[feat], s);
    atomicAdd(&st[128 + feat], sq);
}
__global__ void k_stats2(const bf16_t* __restrict__ a, const float* __restrict__ natt,
                         float* __restrict__ st, int n){
    int tid = threadIdx.x;
    int feat = tid & 127;
    int row = blockIdx.x * 2 + (tid >> 7);
    float s0 = 0.f, q0 = 0.f, s1 = 0.f, q1 = 0.f;
    for (; row < n; row += gridDim.x * 2){
        float v = b2f(a[(size_t)row * 128 + feat]);
        float2 w = *(const float2*)&natt[(size_t)row * 2];
        float v0 = v * w.x, v1 = v * w.y;
        s0 += v0; q0 += v0 * v0; s1 += v1; q1 += v1 * v1;
    }
    atomicAdd(&st[feat], s0);       atomicAdd(&st[128 + feat], q0);
    atomicAdd(&st[256 + feat], s1); atomicAdd(&st[384 + feat], q1);
}
__global__ void k_finstats(const float* __restrict__ st, float* __restrict__ mrs, int n){
    int t = threadIdx.x;
    if (t < 128){
        float m = st[t] / n;
        float var = st[128 + t] / n - m * m;
        mrs[t] = m; mrs[128 + t] = rsqrtf(var + 1e-5f);
    }
}
__global__ void k_finstatsB(const float* __restrict__ st, float* __restrict__ mrsA,
                            float* __restrict__ mrsB, int n){
    int t = threadIdx.x;
    if (t < 128){
        float m = st[t] / n, var = st[128 + t] / n - m * m;
        mrsA[t] = m; mrsA[128 + t] = rsqrtf(var + 1e-5f);
        float m1 = st[256 + t] / n, v1 = st[384 + t] / n - m1 * m1;
        mrsB[t] = m1; mrsB[128 + t] = rsqrtf(v1 + 1e-5f);
    }
}

// ---------- MFMA GEMM: C[n, ccol0..+128 of ldc] = act( BN(scale*A) @ W ) ----------
// W fp32 split into bf16 hi+lo (two MFMAs) -> ~fp32 weight precision.
// LDS: As 64x136 bf16 (17.4KB) + Whi/Wlo 128x72 bf16 (18.4KB each) = 54.3KB -> 3 blk/CU.
template<int ACT, int INBF>  // ACT: 1=relu ; INBF: input bf16?
__global__ __launch_bounds__(256, 3) void k_gemm(const void* __restrict__ Av,
        const float* __restrict__ scale, int sch,
        const float* __restrict__ mrs, const float* __restrict__ W,
        bf16_t* __restrict__ C, int ldc, int ccol0, int n)
{
    __shared__ bf16_t As[64 * 136];
    __shared__ bf16_t Whi[128 * 72];
    __shared__ bf16_t Wlo[128 * 72];
    int tid = threadIdx.x;
    int wid = tid >> 6, lane = tid & 63;
    int row0 = blockIdx.x * 64;
    int m0 = wid * 16;
    int q8 = (lane >> 4) * 8, l15 = lane & 15;

    // stage A (BN applied, bf16) : 64 rows x 128 cols
    for (int i = tid; i < 64 * 16; i += 256){
        int r = i >> 4, c8 = (i & 15) * 8;
        int gr = row0 + r;
        float v[8];
        if (gr < n){
            float sc = scale ? scale[(size_t)gr * 2 + sch] : 1.f;
            if (INBF){
                const bf16_t* Ab = (const bf16_t*)Av;
                ushort4 qa = *(const ushort4*)&Ab[(size_t)gr * 128 + c8];
                ushort4 qb = *(const ushort4*)&Ab[(size_t)gr * 128 + c8 + 4];
                v[0]=b2f(qa.x); v[1]=b2f(qa.y); v[2]=b2f(qa.z); v[3]=b2f(qa.w);
                v[4]=b2f(qb.x); v[5]=b2f(qb.y); v[6]=b2f(qb.z); v[7]=b2f(qb.w);
            } else {
                const float* Af = (const float*)Av;
                float4 fa = *(const float4*)&Af[(size_t)gr * 128 + c8];
                float4 fb = *(const float4*)&Af[(size_t)gr * 128 + c8 + 4];
                v[0]=fa.x; v[1]=fa.y; v[2]=fa.z; v[3]=fa.w;
                v[4]=fb.x; v[5]=fb.y; v[6]=fb.z; v[7]=fb.w;
            }
            #pragma unroll
            for (int j = 0; j < 8; ++j)
                v[j] = (v[j] * sc - mrs[c8 + j]) * mrs[128 + c8 + j] + 1e-4f;
        } else {
            #pragma unroll
            for (int j = 0; j < 8; ++j) v[j] = 0.f;
        }
        #pragma unroll
        for (int j = 0; j < 8; ++j) As[r * 136 + c8 + j] = f2b(v[j]);
    }

    f32x4 acc[8];
    #pragma unroll
    for (int t = 0; t < 8; ++t) acc[t] = (f32x4){0.f, 0.f, 0.f, 0.f};

    for (int kc = 0; kc < 128; kc += 64){
        __syncthreads();
        // stage W chunk transposed, hi+lo: 64 k x 128 n
        for (int i = tid; i < 64 * 32; i += 256){
            int k = i >> 5;
            int n4 = (i & 31) * 4;
            float4 w = *(const float4*)&W[(size_t)(kc + k) * 128 + n4];
            float wv[4] = {w.x, w.y, w.z, w.w};
            #pragma unroll
            for (int j = 0; j < 4; ++j){
                bf16_t h = f2b(wv[j]);
                Whi[(n4 + j) * 72 + k] = h;
                Wlo[(n4 + j) * 72 + k] = f2b(wv[j] - b2f(h));
            }
        }
        __syncthreads();
        #pragma unroll
        for (int kbl = 0; kbl < 2; ++kbl){
            bf16x8 a = *(const bf16x8*)&As[(m0 + l15) * 136 + kc + kbl * 32 + q8];
            #pragma unroll
            for (int nt = 0; nt < 8; ++nt){
                bf16x8 bh = *(const bf16x8*)&Whi[(nt * 16 + l15) * 72 + kbl * 32 + q8];
                acc[nt] = __builtin_amdgcn_mfma_f32_16x16x32_bf16(a, bh, acc[nt], 0, 0, 0);
                bf16x8 bl = *(const bf16x8*)&Wlo[(nt * 16 + l15) * 72 + kbl * 32 + q8];
                acc[nt] = __builtin_amdgcn_mfma_f32_16x16x32_bf16(a, bl, acc[nt], 0, 0, 0);
            }
        }
    }

    // epilogue: acc -> LDS (bf16) -> coalesced store
    __syncthreads();
    #pragma unroll
    for (int nt = 0; nt < 8; ++nt){
        #pragma unroll
        for (int r = 0; r < 4; ++r){
            float v = acc[nt][r];
            if (ACT == 1) v = fmaxf(v, 0.f);
            As[(m0 + (lane >> 4) * 4 + r) * 136 + nt * 16 + l15] = f2b(v);
        }
    }
    __syncthreads();
    for (int i = tid; i < 64 * 16; i += 256){
        int r = i >> 4, c8 = (i & 15) * 8;
        int gr = row0 + r;
        if (gr < n)
            *(uint4*)&C[(size_t)gr * ldc + ccol0 + c8] = *(const uint4*)&As[r * 136 + c8];
    }
}

// ---------- CSR build (by dst) ----------
// in-degree by dst (int) + out-degree by src (float) in one pass
__global__ void k_hist2(const int* __restrict__ src, const int* __restrict__ dst,
                        int* __restrict__ cnt, float* __restrict__ degU, int e){
    int i = blockIdx.x * 256 + threadIdx.x;
    if (i < e){
        atomicAdd(&cnt[dst[i]], 1);
        atomicAdd(&degU[src[i]], 1.0f);
    }
}
__global__ __launch_bounds__(1024) void k_scanA(const int* __restrict__ cnt,
        int* __restrict__ ptr, int* __restrict__ bsum, int n){
    __shared__ int wsum[16];
    int t = threadIdx.x, lane = t & 63, wid = t >> 6;
    int i = blockIdx.x * 1024 + t;
    int v = (i < n) ? cnt[i] : 0;
    int s = v;
    for (int off = 1; off < 64; off <<= 1){
        int u = __shfl_up(s, off);
        if (lane >= off) s += u;
    }
    if (lane == 63) wsum[wid] = s;
    __syncthreads();
    if (wid == 0 && lane < 16){
        int ws = wsum[lane];
        for (int off = 1; off < 16; off <<= 1){
            int u = __shfl_up(ws, off);
            if (lane >= off) ws += u;
        }
        wsum[lane] = ws;
    }
    __syncthreads();
    int woff = wid ? wsum[wid - 1] : 0;
    if (i < n) ptr[i] = woff + s - v;
    if (t == 1023) bsum[blockIdx.x] = woff + s;
}
__global__ void k_scanB(int* __restrict__ bsum, int* __restrict__ ptrN, int nb){
    int lane = threadIdx.x;       // 64 threads
    int carry = 0;
    for (int base = 0; base < nb; base += 64){
        int i = base + lane;
        int v = (i < nb) ? bsum[i] : 0;
        int s = v;
        for (int off = 1; off < 64; off <<= 1){
            int u = __shfl_up(s, off);
            if (lane >= off) s += u;
        }
        if (i < nb) bsum[i] = carry + s - v;
        carry += __shfl(s, 63);
    }
    if (lane == 0) *ptrN = carry;
}
__global__ __launch_bounds__(1024) void k_scanC(int* __restrict__ ptr,
        const int* __restrict__ bsum, int* __restrict__ fill, int n){
    int i = blockIdx.x * 1024 + threadIdx.x;
    if (i < n){
        int p = ptr[i] + bsum[blockIdx.x];
        ptr[i] = p; fill[i] = p;
    }
}
__global__ void k_fill(const int* __restrict__ src, const int* __restrict__ dst,
                       int* __restrict__ fill, int* __restrict__ srcC,
                       int* __restrict__ slotOf, int e){
    int i = blockIdx.x * 256 + threadIdx.x;
    if (i < e){
        int slot = atomicAdd(&fill[dst[i]], 1);
        srcC[slot] = src[i];
        slotOf[i] = slot;
    }
}

// ---------- degree norms + edge weights ----------
__global__ void k_dis(const float* __restrict__ deg, float* __restrict__ dis, int n){
    int i = blockIdx.x * 256 + threadIdx.x;
    if (i < n) dis[i] = rsqrtf(deg[i] + 1.0f);
}
__global__ void k_dis2(const float* __restrict__ d0, const float* __restrict__ d1,
                       float* __restrict__ o0, float* __restrict__ o1, int n){
    int i = blockIdx.x * 256 + threadIdx.x;
    if (i < n){ o0[i] = rsqrtf(d0[i] + 1.0f); o1[i] = rsqrtf(d1[i] + 1.0f); }
}
__global__ void k_wU(const int* __restrict__ srcC, const float* __restrict__ disU,
                     float* __restrict__ wU, int e){
    int i = blockIdx.x * 256 + threadIdx.x;
    if (i < e) wU[i] = disU[srcC[i]];
}
__global__ void k_wB(const int* __restrict__ srcC, const float* __restrict__ dw0,
                     const float* __restrict__ dw1, float* __restrict__ w0,
                     float* __restrict__ w1, int e){
    int i = blockIdx.x * 256 + threadIdx.x;
    if (i < e){ int s = srcC[i]; w0[i] *= dw0[s]; w1[i] *= dw1[s]; }
}

// ---------- conv propagate: bf16 in/out, one wave/node ----------
__global__ __launch_bounds__(256) void k_gather0(const int* __restrict__ ptr,
        const int* __restrict__ srcC, const float* __restrict__ wE,
        const float* __restrict__ dis, const bf16_t* __restrict__ t,
        const float* __restrict__ bias, bf16_t* __restrict__ outB, int n)
{
    int node = blockIdx.x * 4 + (threadIdx.x >> 6);
    if (node >= n) return;
    int lane = threadIdx.x & 63;
    const uint32* T = (const uint32*)t;
    float dd = dis[node];
    uint32 sv = T[(size_t)node * 64 + lane];
    float a0 = 0.f, a1 = 0.f;
    int beg = ptr[node], end = ptr[node + 1];
    int k = beg;
    for (; k + 4 <= end; k += 4){
        int s0 = srcC[k], s1 = srcC[k + 1], s2 = srcC[k + 2], s3 = srcC[k + 3];
        float w0 = wE[k], w1 = wE[k + 1], w2 = wE[k + 2], w3 = wE[k + 3];
        uint32 v0 = T[(size_t)s0 * 64 + lane];
        uint32 v1 = T[(size_t)s1 * 64 + lane];
        uint32 v2 = T[(size_t)s2 * 64 + lane];
        uint32 v3 = T[(size_t)s3 * 64 + lane];
        a0 += w0 * lo16(v0) + w1 * lo16(v1) + w2 * lo16(v2) + w3 * lo16(v3);
        a1 += w0 * hi16(v0) + w1 * hi16(v1) + w2 * hi16(v2) + w3 * hi16(v3);
    }
    for (; k < end; ++k){
        int s = srcC[k];
        float w = wE[k];
        uint32 v = T[(size_t)s * 64 + lane];
        a0 += w * lo16(v); a1 += w * hi16(v);
    }
    a0 = fmaxf(dd * (a0 + dd * lo16(sv)) + bias[2 * lane],     0.f);
    a1 = fmaxf(dd * (a1 + dd * hi16(sv)) + bias[2 * lane + 1], 0.f);
    ((uint32*)outB)[(size_t)node * 64 + lane] = pack2(a0, a1);
}

// ---------- branch propagate: span-per-wave, register pool accumulation ----------
__global__ __launch_bounds__(256) void k_gatherP(const int* __restrict__ ptr,
        const int* __restrict__ srcC, const float* __restrict__ w0E,
        const float* __restrict__ w1E, const float* __restrict__ dis0,
        const float* __restrict__ dis1, const bf16_t* __restrict__ t,
        const float* __restrict__ biasC, const float* __restrict__ biasO,
        const int* __restrict__ batch, float* __restrict__ pool0,
        float* __restrict__ pool1, int n, int span)
{
    int wave = blockIdx.x * 4 + (threadIdx.x >> 6);
    int lane = threadIdx.x & 63;
    int nbeg = wave * span;
    if (nbeg >= n) return;
    int nend = min(n, nbeg + span);
    bool br0 = lane < 32;
    const float* wE  = br0 ? w0E : w1E;
    const float* dis = br0 ? dis0 : dis1;
    int c = 4 * lane;
    const float* bias = br0 ? (biasC + c) : (biasO + c - 128);
    float b0 = bias[0], b1 = bias[1], b2 = bias[2], b3 = bias[3];
    float* pool = br0 ? (pool0 + c) : (pool1 + c - 128);
    const uint2* T = (const uint2*)t;
    int curG = -1;
    float p0 = 0.f, p1 = 0.f, p2 = 0.f, p3 = 0.f;
    for (int node = nbeg; node < nend; ++node){
        float dd = dis[node];
        uint2 sv = T[(size_t)node * 64 + lane];
        float a0 = 0.f, a1 = 0.f, a2 = 0.f, a3 = 0.f;
        int beg = ptr[node], end = ptr[node + 1];
        int k = beg;
        for (; k + 4 <= end; k += 4){
            int s0 = srcC[k], s1 = srcC[k + 1], s2 = srcC[k + 2], s3 = srcC[k + 3];
            float w0 = wE[k], w1 = wE[k + 1], w2 = wE[k + 2], w3 = wE[k + 3];
            uint2 v0 = T[(size_t)s0 * 64 + lane];
            uint2 v1 = T[(size_t)s1 * 64 + lane];
            uint2 v2 = T[(size_t)s2 * 64 + lane];
            uint2 v3 = T[(size_t)s3 * 64 + lane];
            a0 += w0 * lo16(v0.x) + w1 * lo16(v1.x) + w2 * lo16(v2.x) + w3 * lo16(v3.x);
            a1 += w0 * hi16(v0.x) + w1 * hi16(v1.x) + w2 * hi16(v2.x) + w3 * hi16(v3.x);
            a2 += w0 * lo16(v0.y) + w1 * lo16(v1.y) + w2 * lo16(v2.y) + w3 * lo16(v3.y);
            a3 += w0 * hi16(v0.y) + w1 * hi16(v1.y) + w2 * hi16(v2.y) + w3 * hi16(v3.y);
        }
        for (; k < end; ++k){
            int s = srcC[k];
            float w = wE[k];
            uint2 v = T[(size_t)s * 64 + lane];
            a0 += w * lo16(v.x); a1 += w * hi16(v.x);
            a2 += w * lo16(v.y); a3 += w * hi16(v.y);
        }
        a0 = dd * (a0 + dd * lo16(sv.x)) + b0;
        a1 = dd * (a1 + dd * hi16(sv.x)) + b1;
        a2 = dd * (a2 + dd * lo16(sv.y)) + b2;
        a3 = dd * (a3 + dd * hi16(sv.y)) + b3;
        a0 = a0 > 0.f ? a0 : expm1f(a0);
        a1 = a1 > 0.f ? a1 : expm1f(a1);
        a2 = a2 > 0.f ? a2 : expm1f(a2);
        a3 = a3 > 0.f ? a3 : expm1f(a3);
        int g = batch[node];
        if (g != curG){
            if (curG >= 0){
                float* p = pool + (size_t)curG * 128;
                atomicAdd(&p[0], p0); atomicAdd(&p[1], p1);
                atomicAdd(&p[2], p2); atomicAdd(&p[3], p3);
            }
            curG = g; p0 = a0; p1 = a1; p2 = a2; p3 = a3;
        } else {
            p0 += a0; p1 += a1; p2 += a2; p3 += a3;
        }
    }
    if (curG >= 0){
        float* p = pool + (size_t)curG * 128;
        atomicAdd(&p[0], p0); atomicAdd(&p[1], p1);
        atomicAdd(&p[2], p2); atomicAdd(&p[3], p3);
    }
}

// ---------- attention ----------
__global__ __launch_bounds__(256) void k_prep(const bf16_t* __restrict__ h,
        const float* __restrict__ eW, const float* __restrict__ naW,
        float4* __restrict__ epre, float* __restrict__ ntT, int n)
{
    int i = blockIdx.x * 4 + (threadIdx.x >> 6);
    if (i >= n) return;
    int lane = threadIdx.x & 63;
    float h0 = b2f(h[(size_t)i * 128 + lane]), h1 = b2f(h[(size_t)i * 128 + 64 + lane]);
    float s0 = h0 * eW[lane * 2]             + h1 * eW[(64 + lane) * 2];
    float s1 = h0 * eW[lane * 2 + 1]         + h1 * eW[(64 + lane) * 2 + 1];
    float d0 = h0 * eW[(128 + lane) * 2]     + h1 * eW[(192 + lane) * 2];
    float d1 = h0 * eW[(128 + lane) * 2 + 1] + h1 * eW[(192 + lane) * 2 + 1];
    float n0 = h0 * naW[lane * 2]            + h1 * naW[(64 + lane) * 2];
    float n1 = h0 * naW[lane * 2 + 1]        + h1 * naW[(64 + lane) * 2 + 1];
    for (int off = 32; off; off >>= 1){
        s0 += __shfl_xor(s0, off); s1 += __shfl_xor(s1, off);
        d0 += __shfl_xor(d0, off); d1 += __shfl_xor(d1, off);
        n0 += __shfl_xor(n0, off); n1 += __shfl_xor(n1, off);
    }
    if (lane == 0){
        epre[i] = make_float4(s0, s1, d0, d1);
        ntT[2 * i] = n0; ntT[2 * i + 1] = n1;
    }
}
// edge softmax -> wB (CSR order) + weighted out-degree accumulation (was k_degW)
__global__ void k_eatt2(const int* __restrict__ src, const int* __restrict__ dst,
        const int* __restrict__ slotOf, const float4* __restrict__ epre,
        const float* __restrict__ eb, float* __restrict__ wB0,
        float* __restrict__ wB1, float* __restrict__ d0, float* __restrict__ d1, int e){
    int i = blockIdx.x * 256 + threadIdx.x;
    if (i >= e) return;
    int s = src[i];
    float4 ps = epre[s], pd = epre[dst[i]];
    float l0 = ps.x + pd.z + eb[0], l1 = ps.y + pd.w + eb[1];
    float m = fmaxf(l0, l1);
    float e0 = expf(l0 - m), e1 = expf(l1 - m);
    float inv = 1.f / (e0 + e1);
    e0 *= inv; e1 *= inv;
    int slot = slotOf[i];
    wB0[slot] = e0; wB1[slot] = e1;
    atomicAdd(&d0[s], e0); atomicAdd(&d1[s], e1);
}
__global__ void k_natt(const int* __restrict__ ptr, const int* __restrict__ srcC,
        const float* __restrict__ wU, const float* __restrict__ dis,
        const float* __restrict__ ntT, const float* __restrict__ nab,
        float* __restrict__ natt, int n){
    int i = blockIdx.x * 256 + threadIdx.x;
    if (i >= n) return;
    float dd = dis[i];
    float z0 = 0.f, z1 = 0.f;
    int end = ptr[i + 1];
    for (int k = ptr[i]; k < end; ++k){
        int s = srcC[k];
        float w = wU[k];
        z0 += w * ntT[2 * s]; z1 += w * ntT[2 * s + 1];
    }
    z0 = dd * (z0 + dd * ntT[2 * i])     + nab[0];
    z1 = dd * (z1 + dd * ntT[2 * i + 1]) + nab[1];
    float m = fmaxf(z0, z1);
    float e0 = expf(z0 - m), e1 = expf(z1 - m);
    float inv = 1.f / (e0 + e1);
    natt[2 * i] = e0 * inv; natt[2 * i + 1] = e1 * inv;
}

// ---------- heads (G=512, fp32) ----------
__global__ __launch_bounds__(1024) void k_gstats(const float* __restrict__ a,
        const float* __restrict__ b, int f, float* __restrict__ mrs, int n){
    __shared__ float red[2][1024];
    int col = threadIdx.x & (f - 1);
    int rpb = 1024 / f;
    int rw  = threadIdx.x / f;
    float s = 0.f, sq = 0.f;
    for (int r = rw; r < n; r += rpb){
        float v = (col < 128) ? a[(size_t)r * 128 + col] : b[(size_t)r * 128 + col - 128];
        s += v; sq += v * v;
    }
    red[0][threadIdx.x] = s; red[1][threadIdx.x] = sq;
    __syncthreads();
    if (threadIdx.x < (unsigned)f){
        float ts = 0.f, tq = 0.f;
        for (int w = 0; w < rpb; ++w){ ts += red[0][w * f + col]; tq += red[1][w * f + col]; }
        float m = ts / n, var = tq / n - m * m;
        mrs[col] = m; mrs[f + col] = rsqrtf(var + 1e-5f);
    }
}
__global__ __launch_bounds__(128) void k_hgemm(const float* __restrict__ a,
        const float* __restrict__ b2, int fin,
        const float* __restrict__ mrs, const float* __restrict__ W,
        const float* __restrict__ b, float* __restrict__ o, int act)
{
    __shared__ float as[256];
    int row = blockIdx.x, tid = threadIdx.x;
    for (int i = tid; i < fin; i += 128){
        float v = (i < 128) ? a[(size_t)row * 128 + i] : b2[(size_t)row * 128 + i - 128];
        as[i] = (v - mrs[i]) * mrs[fin + i] + 1e-4f;
    }
    __syncthreads();
    float s = 0.f;
    for (int k = 0; k < fin; ++k) s += as[k] * W[k * 128 + tid];
    s += b[tid];
    if (act == 1) s = fmaxf(s, 0.f);
    else { s = s > 0.f ? s : expm1f(s); s = s > 0.f ? s : expm1f(s); }
    o[(size_t)row * 128 + tid] = s;
}
__global__ __launch_bounds__(256) void k_hfinal(const float* __restrict__ a,
        const float* __restrict__ mrs, const float* __restrict__ W,
        const float* __restrict__ b, float* __restrict__ out, int nrows)
{
    int row = blockIdx.x * 4 + (threadIdx.x >> 6);
    if (row >= nrows) return;
    int lane = threadIdx.x & 63;
    float v0 = (a[(size_t)row * 128 + lane]      - mrs[lane])      * mrs[128 + lane]      + 1e-4f;
    float v1 = (a[(size_t)row * 128 + 64 + lane] - mrs[64 + lane]) * mrs[128 + 64 + lane] + 1e-4f;
    float logit[10];
    #pragma unroll
    for (int c = 0; c < 10; ++c){
        float p = v0 * W[lane * 10 + c] + v1 * W[(lane + 64) * 10 + c];
        for (int off = 32; off; off >>= 1) p += __shfl_xor(p, off);
        logit[c] = p + b[c];
    }
    float m = logit[0];
    #pragma unroll
    for (int c = 1; c < 10; ++c) m = fmaxf(m, logit[c]);
    float s = 0.f;
    #pragma unroll
    for (int c = 0; c < 10; ++c) s += expf(logit[c] - m);
    float lse = logf(s);
    if (lane < 10) out[row * 10 + lane] = logit[lane] - m - lse;
}

extern "C" void kernel_launch(void* const* d_in, const int* in_sizes, int n_in,
                              void* d_out, int out_size, void* d_ws, size_t ws_size,
                              hipStream_t stream)
{
    const int N = in_sizes[0] / 128;
    const int E = in_sizes[24];
    const int G = 512;
    const float* x    = (const float*)d_in[0];
    const float* Wf   = (const float*)d_in[1];
    const float* cWs  = (const float*)d_in[2];
    const float* cbs  = (const float*)d_in[3];
    const float* eW   = (const float*)d_in[4];
    const float* ebv  = (const float*)d_in[5];
    const float* naW  = (const float*)d_in[6];
    const float* nab  = (const float*)d_in[7];
    const float* xcW  = (const float*)d_in[8];
    const float* xcb  = (const float*)d_in[9];
    const float* xoW  = (const float*)d_in[10];
    const float* xob  = (const float*)d_in[11];
    const float* cW1  = (const float*)d_in[12];
    const float* cb1  = (const float*)d_in[13];
    const float* cW2  = (const float*)d_in[14];
    const float* cb2  = (const float*)d_in[15];
    const float* oW1  = (const float*)d_in[16];
    const float* ob1  = (const float*)d_in[17];
    const float* oW2  = (const float*)d_in[18];
    const float* ob2  = (const float*)d_in[19];
    const float* coW1 = (const float*)d_in[20];
    const float* cob1 = (const float*)d_in[21];
    const float* coW2 = (const float*)d_in[22];
    const float* cob2 = (const float*)d_in[23];
    const int* esrc  = (const int*)d_in[24];
    const int* edst  = (const int*)d_in[25];
    const int* batch = (const int*)d_in[26];
    float* out = (float*)d_out;

    size_t NH = (size_t)N * 128;
    bf16_t* B1  = (bf16_t*)d_ws;            // N*128
    bf16_t* B0  = B1 + NH;                  // N*128
    bf16_t* B0c = B0 + NH;                  // N*256 ([xc|xo])
    float* fbase = (float*)(B0c + 2 * NH);
    float* epreF = fbase;                   // 4N
    float* ntT   = epreF + 4 * (size_t)N;
    float* natt  = ntT + 2 * (size_t)N;
    float* disU  = natt + 2 * (size_t)N;
    float* disW0 = disU + N;
    float* disW1 = disW0 + N;
    float* mrsA  = disW1 + N;               // 256
    float* mrsB  = mrsA + 256;              // 256
    float* wU    = mrsB + 256;              // E (CSR order)
    float* wB0   = wU + E;                  // E
    float* wB1   = wB0 + E;                 // E
    float* gt2   = wB1 + E;                 // G*128
    // zero zone (single memset)
    float* zz    = gt2 + (size_t)G * 128;
    float* degU  = zz;                      // N
    float* degC0 = degU + N;                // N
    float* degC1 = degC0 + N;               // N
    float* stZ   = degC1 + N;               // 1536
    float* xcp   = stZ + 1536;              // G*128
    float* xop   = xcp + (size_t)G * 128;   // G*128
    int*   cntI  = (int*)(xop + (size_t)G * 128);   // N
    size_t zzBytes = ((size_t)(4 * N) + 1536 + 2 * (size_t)G * 128) * 4;
    int* ptrI   = cntI + N;                 // N+1
    int* fillI  = ptrI + N + 1;             // N
    int* srcC   = fillI + N;                // E
    int* slotOf = srcC + E;                 // E
    int* bsum   = slotOf + E;               // up to 64
    float4* epre = (float4*)epreF;

    int gridE = (E + 255) / 256;
    int gridN = (N + 255) / 256;
    int gridW = (N + 3) / 4;
    int gridG = (N + 63) / 64;
    int nb    = (N + 1023) / 1024;
    int span  = (N + 8191) / 8192;
    int gridP = (N + span * 4 - 1) / (span * 4);

    hipMemsetAsync(zz, 0, zzBytes, stream);

    // ---- CSR by dst + degrees + CSR weights ----
    k_hist2<<<gridE, 256, 0, stream>>>(esrc, edst, cntI, degU, E);
    k_scanA<<<nb, 1024, 0, stream>>>(cntI, ptrI, bsum, N);
    k_scanB<<<1, 64, 0, stream>>>(bsum, ptrI + N, nb);
    k_scanC<<<nb, 1024, 0, stream>>>(ptrI, bsum, fillI, N);
    k_fill<<<gridE, 256, 0, stream>>>(esrc, edst, fillI, srcC, slotOf, E);
    k_dis<<<gridN, 256, 0, stream>>>(degU, disU, N);
    k_wU<<<gridE, 256, 0, stream>>>(srcC, disU, wU, E);

    // ---- h = relu(BN(x) @ W_feat) -> B1 (bf16) ----
    k_statsF<<<256, 256, 0, stream>>>(x, stZ, N);
    k_finstats<<<1, 128, 0, stream>>>(stZ, mrsA, N);
    k_gemm<1, 0><<<gridG, 256, 0, stream>>>(x, nullptr, 0, mrsA, Wf, B1, 128, 0, N);

    // ---- 3 x [BN -> GCNConv -> relu] ----
    for (int i = 0; i < 3; ++i){
        float* st = stZ + 256 * (i + 1);
        k_statsB<<<256, 256, 0, stream>>>(B1, st, N);
        k_finstats<<<1, 128, 0, stream>>>(st, mrsA, N);
        k_gemm<0, 1><<<gridG, 256, 0, stream>>>(B1, nullptr, 0, mrsA,
                                                cWs + (size_t)i * 128 * 128, B0, 128, 0, N);
        k_gather0<<<gridW, 256, 0, stream>>>(ptrI, srcC, wU, disU, B0, cbs + i * 128, B1, N);
    }

    // ---- attention ----
    k_prep<<<gridW, 256, 0, stream>>>(B1, eW, naW, epre, ntT, N);
    k_eatt2<<<gridE, 256, 0, stream>>>(esrc, edst, slotOf, epre, ebv, wB0, wB1,
                                       degC0, degC1, E);
    k_natt<<<gridN, 256, 0, stream>>>(ptrI, srcC, wU, disU, ntT, nab, natt, N);

    // ---- branch stats + weighted degree norms + CSR branch weights ----
    k_stats2<<<256, 256, 0, stream>>>(B1, natt, stZ + 1024, N);
    k_finstatsB<<<1, 128, 0, stream>>>(stZ + 1024, mrsA, mrsB, N);
    k_dis2<<<gridN, 256, 0, stream>>>(degC0, degC1, disW0, disW1, N);
    k_wB<<<gridE, 256, 0, stream>>>(srcC, disW0, disW1, wB0, wB1, E);

    // ---- xc / xo branch GEMMs into combined B0c, then ONE gather ----
    k_gemm<0, 1><<<gridG, 256, 0, stream>>>(B1, natt, 0, mrsA, xcW, B0c, 256, 0, N);
    k_gemm<0, 1><<<gridG, 256, 0, stream>>>(B1, natt, 1, mrsB, xoW, B0c, 256, 128, N);
    k_gatherP<<<gridP, 256, 0, stream>>>(ptrI, srcC, wB0, wB1, disW0, disW1, B0c,
                                         xcb, xob, batch, xcp, xop, N, span);

    // ---- C head ----
    k_gstats<<<1, 1024, 0, stream>>>(xcp, xcp, 128, mrsA, G);
    k_hgemm<<<G, 128, 0, stream>>>(xcp, xcp, 128, mrsA, cW1, cb1, gt2, 1);
    k_gstats<<<1, 1024, 0, stream>>>(gt2, gt2, 128, mrsA, G);
    k_hfinal<<<(G + 3) / 4, 256, 0, stream>>>(gt2, mrsA, cW2, cb2, out, G);

    // ---- O head ----
    k_gstats<<<1, 1024, 0, stream>>>(xop, xop, 128, mrsA, G);
    k_hgemm<<<G, 128, 0, stream>>>(xop, xop, 128, mrsA, oW1, ob1, gt2, 1);
    k_gstats<<<1, 1024, 0, stream>>>(gt2, gt2, 128, mrsA, G);
    k_hfinal<<<(G + 3) / 4, 256, 0, stream>>>(gt2, mrsA, oW2, ob2, out + (size_t)G * 10, G);

    // ---- CO head ----
    k_gstats<<<1, 1024, 0, stream>>>(xcp, xop, 256, mrsA, G);
    k_hgemm<<<G, 128, 0, stream>>>(xcp, xop, 256, mrsA, coW1, cob1, gt2, 2);
    k_gstats<<<1, 1024, 0, stream>>>(gt2, gt2, 128, mrsA, G);
    k_hfinal<<<(G + 3) / 4, 256, 0, stream>>>(gt2, mrsA, coW2, cob2, out + 2 * (size_t)G * 10, G);
}

// Round 2
// 791.261 us; speedup vs baseline: 1.2644x; 1.2644x over previous
//
#include <hip/hip_runtime.h>

// CausalGCN forward on MI355X. fp32 in/out; internal N x 128 tensors bf16.
// R9: gathers unrolled 8 + gatherP 512-thr blocks + LDS group-combine (atomics /3),
//     W hi/lo pre-split once (k_wsplit) -> GEMM stages W via uint4 copies,
//     3 heads fused into 4 launches.

typedef unsigned short bf16_t;
typedef unsigned int   uint32;
typedef __attribute__((ext_vector_type(8))) short   bf16x8;
typedef __attribute__((ext_vector_type(4))) float   f32x4;

__device__ __forceinline__ float b2f(bf16_t v){ return __uint_as_float(((uint32)v) << 16); }
__device__ __forceinline__ bf16_t f2b(float f){
    uint32 u = __float_as_uint(f);
    return (bf16_t)((u + 0x7fffu + ((u >> 16) & 1u)) >> 16);   // RNE
}
__device__ __forceinline__ uint32 pack2(float lo, float hi){
    return (uint32)f2b(lo) | ((uint32)f2b(hi) << 16);
}
__device__ __forceinline__ float lo16(uint32 u){ return __uint_as_float(u << 16); }
__device__ __forceinline__ float hi16(uint32 u){ return __uint_as_float(u & 0xffff0000u); }

// ---------- BN stats ----------
__global__ void k_statsF(const float* __restrict__ a, float* __restrict__ st, int n){
    int tid = threadIdx.x;
    int feat = tid & 127;
    int row = blockIdx.x * 2 + (tid >> 7);
    float s = 0.f, sq = 0.f;
    for (; row < n; row += gridDim.x * 2){
        float v = a[(size_t)row * 128 + feat];
        s += v; sq += v * v;
    }
    atomicAdd(&st[feat], s);
    atomicAdd(&st[128 + feat], sq);
}
__global__ void k_statsB(const bf16_t* __restrict__ a, float* __restrict__ st, int n){
    int tid = threadIdx.x;
    int feat = tid & 127;
    int row = blockIdx.x * 2 + (tid >> 7);
    float s = 0.f, sq = 0.f;
    for (; row < n; row += gridDim.x * 2){
        float v = b2f(a[(size_t)row * 128 + feat]);
        s += v; sq += v * v;
    }
    atomicAdd(&st[feat], s);
    atomicAdd(&st[128 + feat], sq);
}
__global__ void k_stats2(const bf16_t* __restrict__ a, const float* __restrict__ natt,
                         float* __restrict__ st, int n){
    int tid = threadIdx.x;
    int feat = tid & 127;
    int row = blockIdx.x * 2 + (tid >> 7);
    float s0 = 0.f, q0 = 0.f, s1 = 0.f, q1 = 0.f;
    for (; row < n; row += gridDim.x * 2){
        float v = b2f(a[(size_t)row * 128 + feat]);
        float2 w = *(const float2*)&natt[(size_t)row * 2];
        float v0 = v * w.x, v1 = v * w.y;
        s0 += v0; q0 += v0 * v0; s1 += v1; q1 += v1 * v1;
    }
    atomicAdd(&st[feat], s0);       atomicAdd(&st[128 + feat], q0);
    atomicAdd(&st[256 + feat], s1); atomicAdd(&st[384 + feat], q1);
}
__global__ void k_finstats(const float* __restrict__ st, float* __restrict__ mrs, int n){
    int t = threadIdx.x;
    if (t < 128){
        float m = st[t] / n;
        float var = st[128 + t] / n - m * m;
        mrs[t] = m; mrs[128 + t] = rsqrtf(var + 1e-5f);
    }
}
__global__ void k_finstatsB(const float* __restrict__ st, float* __restrict__ mrsA,
                            float* __restrict__ mrsB, int n){
    int t = threadIdx.x;
    if (t < 128){
        float m = st[t] / n, var = st[128 + t] / n - m * m;
        mrsA[t] = m; mrsA[128 + t] = rsqrtf(var + 1e-5f);
        float m1 = st[256 + t] / n, v1 = st[384 + t] / n - m1 * m1;
        mrsB[t] = m1; mrsB[128 + t] = rsqrtf(v1 + 1e-5f);
    }
}

// ---------- W pre-split: fp32 [k][n] -> bf16 hi/lo transposed [n][k], 6 matrices ----------
__global__ void k_wsplit(const float* __restrict__ Wf, const float* __restrict__ cWs,
        const float* __restrict__ xcW, const float* __restrict__ xoW,
        bf16_t* __restrict__ whiT, bf16_t* __restrict__ wloT)
{
    int mat = blockIdx.y;
    const float* src = (mat == 0) ? Wf : (mat <= 3) ? cWs + (size_t)(mat - 1) * 16384
                      : (mat == 4) ? xcW : xoW;
    int i = (blockIdx.x * 256 + threadIdx.x) * 4;
    int nrow = i >> 7, k0 = i & 127;
    size_t off = (size_t)mat * 16384 + (size_t)nrow * 128 + k0;
    #pragma unroll
    for (int j = 0; j < 4; ++j){
        float w = src[(size_t)(k0 + j) * 128 + nrow];
        bf16_t h = f2b(w);
        whiT[off + j] = h;
        wloT[off + j] = f2b(w - b2f(h));
    }
}

// ---------- MFMA GEMM: C[n, ccol0..+128 of ldc] = act( BN(scale*A) @ W ) ----------
// W pre-split bf16 hi+lo (two MFMAs) -> ~fp32 weight precision.
// LDS: As 64x136 bf16 (17.4KB) + Whi/Wlo 128x72 bf16 (18.4KB each) = 54.3KB -> 3 blk/CU.
template<int ACT, int INBF>  // ACT: 1=relu ; INBF: input bf16?
__global__ __launch_bounds__(256, 3) void k_gemm(const void* __restrict__ Av,
        const float* __restrict__ scale, int sch,
        const float* __restrict__ mrs, const bf16_t* __restrict__ WhiT,
        const bf16_t* __restrict__ WloT,
        bf16_t* __restrict__ C, int ldc, int ccol0, int n)
{
    __shared__ bf16_t As[64 * 136];
    __shared__ bf16_t Whi[128 * 72];
    __shared__ bf16_t Wlo[128 * 72];
    int tid = threadIdx.x;
    int wid = tid >> 6, lane = tid & 63;
    int row0 = blockIdx.x * 64;
    int m0 = wid * 16;
    int q8 = (lane >> 4) * 8, l15 = lane & 15;

    // stage A (BN applied, bf16) : 64 rows x 128 cols
    for (int i = tid; i < 64 * 16; i += 256){
        int r = i >> 4, c8 = (i & 15) * 8;
        int gr = row0 + r;
        float v[8];
        if (gr < n){
            float sc = scale ? scale[(size_t)gr * 2 + sch] : 1.f;
            if (INBF){
                const bf16_t* Ab = (const bf16_t*)Av;
                ushort4 qa = *(const ushort4*)&Ab[(size_t)gr * 128 + c8];
                ushort4 qb = *(const ushort4*)&Ab[(size_t)gr * 128 + c8 + 4];
                v[0]=b2f(qa.x); v[1]=b2f(qa.y); v[2]=b2f(qa.z); v[3]=b2f(qa.w);
                v[4]=b2f(qb.x); v[5]=b2f(qb.y); v[6]=b2f(qb.z); v[7]=b2f(qb.w);
            } else {
                const float* Af = (const float*)Av;
                float4 fa = *(const float4*)&Af[(size_t)gr * 128 + c8];
                float4 fb = *(const float4*)&Af[(size_t)gr * 128 + c8 + 4];
                v[0]=fa.x; v[1]=fa.y; v[2]=fa.z; v[3]=fa.w;
                v[4]=fb.x; v[5]=fb.y; v[6]=fb.z; v[7]=fb.w;
            }
            #pragma unroll
            for (int j = 0; j < 8; ++j)
                v[j] = (v[j] * sc - mrs[c8 + j]) * mrs[128 + c8 + j] + 1e-4f;
        } else {
            #pragma unroll
            for (int j = 0; j < 8; ++j) v[j] = 0.f;
        }
        #pragma unroll
        for (int j = 0; j < 8; ++j) As[r * 136 + c8 + j] = f2b(v[j]);
    }

    f32x4 acc[8];
    #pragma unroll
    for (int t = 0; t < 8; ++t) acc[t] = (f32x4){0.f, 0.f, 0.f, 0.f};

    for (int kc = 0; kc < 128; kc += 64){
        __syncthreads();
        // stage W chunk (pre-split, pre-transposed): pure uint4 copies
        for (int i = tid; i < 128 * 8; i += 256){
            int nrow = i >> 3, k8 = (i & 7) * 8;
            *(uint4*)&Whi[nrow * 72 + k8] = *(const uint4*)&WhiT[(size_t)nrow * 128 + kc + k8];
            *(uint4*)&Wlo[nrow * 72 + k8] = *(const uint4*)&WloT[(size_t)nrow * 128 + kc + k8];
        }
        __syncthreads();
        #pragma unroll
        for (int kbl = 0; kbl < 2; ++kbl){
            bf16x8 a = *(const bf16x8*)&As[(m0 + l15) * 136 + kc + kbl * 32 + q8];
            #pragma unroll
            for (int nt = 0; nt < 8; ++nt){
                bf16x8 bh = *(const bf16x8*)&Whi[(nt * 16 + l15) * 72 + kbl * 32 + q8];
                acc[nt] = __builtin_amdgcn_mfma_f32_16x16x32_bf16(a, bh, acc[nt], 0, 0, 0);
                bf16x8 bl = *(const bf16x8*)&Wlo[(nt * 16 + l15) * 72 + kbl * 32 + q8];
                acc[nt] = __builtin_amdgcn_mfma_f32_16x16x32_bf16(a, bl, acc[nt], 0, 0, 0);
            }
        }
    }

    // epilogue: acc -> LDS (bf16) -> coalesced store
    __syncthreads();
    #pragma unroll
    for (int nt = 0; nt < 8; ++nt){
        #pragma unroll
        for (int r = 0; r < 4; ++r){
            float v = acc[nt][r];
            if (ACT == 1) v = fmaxf(v, 0.f);
            As[(m0 + (lane >> 4) * 4 + r) * 136 + nt * 16 + l15] = f2b(v);
        }
    }
    __syncthreads();
    for (int i = tid; i < 64 * 16; i += 256){
        int r = i >> 4, c8 = (i & 15) * 8;
        int gr = row0 + r;
        if (gr < n)
            *(uint4*)&C[(size_t)gr * ldc + ccol0 + c8] = *(const uint4*)&As[r * 136 + c8];
    }
}

// ---------- CSR build (by dst) ----------
__global__ void k_hist2(const int* __restrict__ src, const int* __restrict__ dst,
                        int* __restrict__ cnt, float* __restrict__ degU, int e){
    int i = blockIdx.x * 256 + threadIdx.x;
    if (i < e){
        atomicAdd(&cnt[dst[i]], 1);
        atomicAdd(&degU[src[i]], 1.0f);
    }
}
__global__ __launch_bounds__(1024) void k_scanA(const int* __restrict__ cnt,
        int* __restrict__ ptr, int* __restrict__ bsum, int n){
    __shared__ int wsum[16];
    int t = threadIdx.x, lane = t & 63, wid = t >> 6;
    int i = blockIdx.x * 1024 + t;
    int v = (i < n) ? cnt[i] : 0;
    int s = v;
    for (int off = 1; off < 64; off <<= 1){
        int u = __shfl_up(s, off);
        if (lane >= off) s += u;
    }
    if (lane == 63) wsum[wid] = s;
    __syncthreads();
    if (wid == 0 && lane < 16){
        int ws = wsum[lane];
        for (int off = 1; off < 16; off <<= 1){
            int u = __shfl_up(ws, off);
            if (lane >= off) ws += u;
        }
        wsum[lane] = ws;
    }
    __syncthreads();
    int woff = wid ? wsum[wid - 1] : 0;
    if (i < n) ptr[i] = woff + s - v;
    if (t == 1023) bsum[blockIdx.x] = woff + s;
}
__global__ void k_scanB(int* __restrict__ bsum, int* __restrict__ ptrN, int nb){
    int lane = threadIdx.x;       // 64 threads
    int carry = 0;
    for (int base = 0; base < nb; base += 64){
        int i = base + lane;
        int v = (i < nb) ? bsum[i] : 0;
        int s = v;
        for (int off = 1; off < 64; off <<= 1){
            int u = __shfl_up(s, off);
            if (lane >= off) s += u;
        }
        if (i < nb) bsum[i] = carry + s - v;
        carry += __shfl(s, 63);
    }
    if (lane == 0) *ptrN = carry;
}
__global__ __launch_bounds__(1024) void k_scanC(int* __restrict__ ptr,
        const int* __restrict__ bsum, int* __restrict__ fill, int n){
    int i = blockIdx.x * 1024 + threadIdx.x;
    if (i < n){
        int p = ptr[i] + bsum[blockIdx.x];
        ptr[i] = p; fill[i] = p;
    }
}
__global__ void k_fill(const int* __restrict__ src, const int* __restrict__ dst,
                       int* __restrict__ fill, int* __restrict__ srcC,
                       int* __restrict__ slotOf, int e){
    int i = blockIdx.x * 256 + threadIdx.x;
    if (i < e){
        int slot = atomicAdd(&fill[dst[i]], 1);
        srcC[slot] = src[i];
        slotOf[i] = slot;
    }
}

// ---------- degree norms + edge weights ----------
__global__ void k_dis(const float* __restrict__ deg, float* __restrict__ dis, int n){
    int i = blockIdx.x * 256 + threadIdx.x;
    if (i < n) dis[i] = rsqrtf(deg[i] + 1.0f);
}
__global__ void k_dis2(const float* __restrict__ d0, const float* __restrict__ d1,
                       float* __restrict__ o0, float* __restrict__ o1, int n){
    int i = blockIdx.x * 256 + threadIdx.x;
    if (i < n){ o0[i] = rsqrtf(d0[i] + 1.0f); o1[i] = rsqrtf(d1[i] + 1.0f); }
}
__global__ void k_wU(const int* __restrict__ srcC, const float* __restrict__ disU,
                     float* __restrict__ wU, int e){
    int i = blockIdx.x * 256 + threadIdx.x;
    if (i < e) wU[i] = disU[srcC[i]];
}
__global__ void k_wB(const int* __restrict__ srcC, const float* __restrict__ dw0,
                     const float* __restrict__ dw1, float* __restrict__ w0,
                     float* __restrict__ w1, int e){
    int i = blockIdx.x * 256 + threadIdx.x;
    if (i < e){ int s = srcC[i]; w0[i] *= dw0[s]; w1[i] *= dw1[s]; }
}

// ---------- conv propagate: bf16 in/out, one wave/node, unroll 8 ----------
__global__ __launch_bounds__(256) void k_gather0(const int* __restrict__ ptr,
        const int* __restrict__ srcC, const float* __restrict__ wE,
        const float* __restrict__ dis, const bf16_t* __restrict__ t,
        const float* __restrict__ bias, bf16_t* __restrict__ outB, int n)
{
    int node = blockIdx.x * 4 + (threadIdx.x >> 6);
    if (node >= n) return;
    int lane = threadIdx.x & 63;
    const uint32* T = (const uint32*)t;
    float dd = dis[node];
    uint32 sv = T[(size_t)node * 64 + lane];
    float a0 = 0.f, a1 = 0.f;
    int beg = ptr[node], end = ptr[node + 1];
    int k = beg;
    for (; k + 8 <= end; k += 8){
        int s0 = srcC[k],     s1 = srcC[k + 1], s2 = srcC[k + 2], s3 = srcC[k + 3];
        int s4 = srcC[k + 4], s5 = srcC[k + 5], s6 = srcC[k + 6], s7 = srcC[k + 7];
        float w0 = wE[k],     w1 = wE[k + 1], w2 = wE[k + 2], w3 = wE[k + 3];
        float w4 = wE[k + 4], w5 = wE[k + 5], w6 = wE[k + 6], w7 = wE[k + 7];
        uint32 v0 = T[(size_t)s0 * 64 + lane];
        uint32 v1 = T[(size_t)s1 * 64 + lane];
        uint32 v2 = T[(size_t)s2 * 64 + lane];
        uint32 v3 = T[(size_t)s3 * 64 + lane];
        uint32 v4 = T[(size_t)s4 * 64 + lane];
        uint32 v5 = T[(size_t)s5 * 64 + lane];
        uint32 v6 = T[(size_t)s6 * 64 + lane];
        uint32 v7 = T[(size_t)s7 * 64 + lane];
        a0 += w0 * lo16(v0) + w1 * lo16(v1) + w2 * lo16(v2) + w3 * lo16(v3);
        a1 += w0 * hi16(v0) + w1 * hi16(v1) + w2 * hi16(v2) + w3 * hi16(v3);
        a0 += w4 * lo16(v4) + w5 * lo16(v5) + w6 * lo16(v6) + w7 * lo16(v7);
        a1 += w4 * hi16(v4) + w5 * hi16(v5) + w6 * hi16(v6) + w7 * hi16(v7);
    }
    for (; k + 4 <= end; k += 4){
        int s0 = srcC[k], s1 = srcC[k + 1], s2 = srcC[k + 2], s3 = srcC[k + 3];
        float w0 = wE[k], w1 = wE[k + 1], w2 = wE[k + 2], w3 = wE[k + 3];
        uint32 v0 = T[(size_t)s0 * 64 + lane];
        uint32 v1 = T[(size_t)s1 * 64 + lane];
        uint32 v2 = T[(size_t)s2 * 64 + lane];
        uint32 v3 = T[(size_t)s3 * 64 + lane];
        a0 += w0 * lo16(v0) + w1 * lo16(v1) + w2 * lo16(v2) + w3 * lo16(v3);
        a1 += w0 * hi16(v0) + w1 * hi16(v1) + w2 * hi16(v2) + w3 * hi16(v3);
    }
    for (; k < end; ++k){
        int s = srcC[k];
        float w = wE[k];
        uint32 v = T[(size_t)s * 64 + lane];
        a0 += w * lo16(v); a1 += w * hi16(v);
    }
    a0 = fmaxf(dd * (a0 + dd * lo16(sv)) + bias[2 * lane],     0.f);
    a1 = fmaxf(dd * (a1 + dd * hi16(sv)) + bias[2 * lane + 1], 0.f);
    ((uint32*)outB)[(size_t)node * 64 + lane] = pack2(a0, a1);
}

// ---------- branch propagate: span-per-wave, LDS group-combine, unroll 8 ----------
#define GP_SLOTS 16
__global__ __launch_bounds__(512) void k_gatherP(const int* __restrict__ ptr,
        const int* __restrict__ srcC, const float* __restrict__ w0E,
        const float* __restrict__ w1E, const float* __restrict__ dis0,
        const float* __restrict__ dis1, const bf16_t* __restrict__ t,
        const float* __restrict__ biasC, const float* __restrict__ biasO,
        const int* __restrict__ batch, float* __restrict__ pool0,
        float* __restrict__ pool1, int n, int span)
{
    __shared__ int   sTag[GP_SLOTS];
    __shared__ float sAcc[GP_SLOTS][256];
    int tid = threadIdx.x;
    for (int j = tid; j < GP_SLOTS; j += 512) sTag[j] = -1;
    for (int j = tid; j < GP_SLOTS * 256; j += 512) ((float*)sAcc)[j] = 0.f;
    __syncthreads();

    int wave = blockIdx.x * 8 + (tid >> 6);
    int lane = tid & 63;
    int nbeg = wave * span;
    int nend = min(n, nbeg + span);
    bool br0 = lane < 32;
    const float* wE  = br0 ? w0E : w1E;
    const float* dis = br0 ? dis0 : dis1;
    int c = 4 * lane;                       // br0: 0..124 ; br1: 128..252
    const float* bias = br0 ? (biasC + c) : (biasO + c - 128);
    float b0 = bias[0], b1 = bias[1], b2 = bias[2], b3 = bias[3];
    const uint2* T = (const uint2*)t;
    int curG = -1;
    float p0 = 0.f, p1 = 0.f, p2 = 0.f, p3 = 0.f;

    auto flush = [&](int g){
        int slot = 0;
        if (lane == 0){
            slot = GP_SLOTS;
            for (int j = 0; j < GP_SLOTS; ++j){
                int old = atomicCAS(&sTag[j], -1, g);
                if (old == -1 || old == g){ slot = j; break; }
            }
        }
        slot = __shfl(slot, 0);
        if (slot < GP_SLOTS){
            atomicAdd(&sAcc[slot][c + 0], p0);
            atomicAdd(&sAcc[slot][c + 1], p1);
            atomicAdd(&sAcc[slot][c + 2], p2);
            atomicAdd(&sAcc[slot][c + 3], p3);
        } else {
            float* p = br0 ? &pool0[(size_t)g * 128 + c] : &pool1[(size_t)g * 128 + c - 128];
            atomicAdd(&p[0], p0); atomicAdd(&p[1], p1);
            atomicAdd(&p[2], p2); atomicAdd(&p[3], p3);
        }
    };

    for (int node = nbeg; node < nend; ++node){
        float dd = dis[node];
        uint2 sv = T[(size_t)node * 64 + lane];
        float a0 = 0.f, a1 = 0.f, a2 = 0.f, a3 = 0.f;
        int beg = ptr[node], end = ptr[node + 1];
        int k = beg;
        for (; k + 8 <= end; k += 8){
            int s0 = srcC[k],     s1 = srcC[k + 1], s2 = srcC[k + 2], s3 = srcC[k + 3];
            int s4 = srcC[k + 4], s5 = srcC[k + 5], s6 = srcC[k + 6], s7 = srcC[k + 7];
            float w0 = wE[k],     w1 = wE[k + 1], w2 = wE[k + 2], w3 = wE[k + 3];
            float w4 = wE[k + 4], w5 = wE[k + 5], w6 = wE[k + 6], w7 = wE[k + 7];
            uint2 v0 = T[(size_t)s0 * 64 + lane];
            uint2 v1 = T[(size_t)s1 * 64 + lane];
            uint2 v2 = T[(size_t)s2 * 64 + lane];
            uint2 v3 = T[(size_t)s3 * 64 + lane];
            uint2 v4 = T[(size_t)s4 * 64 + lane];
            uint2 v5 = T[(size_t)s5 * 64 + lane];
            uint2 v6 = T[(size_t)s6 * 64 + lane];
            uint2 v7 = T[(size_t)s7 * 64 + lane];
            a0 += w0 * lo16(v0.x) + w1 * lo16(v1.x) + w2 * lo16(v2.x) + w3 * lo16(v3.x);
            a1 += w0 * hi16(v0.x) + w1 * hi16(v1.x) + w2 * hi16(v2.x) + w3 * hi16(v3.x);
            a2 += w0 * lo16(v0.y) + w1 * lo16(v1.y) + w2 * lo16(v2.y) + w3 * lo16(v3.y);
            a3 += w0 * hi16(v0.y) + w1 * hi16(v1.y) + w2 * hi16(v2.y) + w3 * hi16(v3.y);
            a0 += w4 * lo16(v4.x) + w5 * lo16(v5.x) + w6 * lo16(v6.x) + w7 * lo16(v7.x);
            a1 += w4 * hi16(v4.x) + w5 * hi16(v5.x) + w6 * hi16(v6.x) + w7 * hi16(v7.x);
            a2 += w4 * lo16(v4.y) + w5 * lo16(v5.y) + w6 * lo16(v6.y) + w7 * lo16(v7.y);
            a3 += w4 * hi16(v4.y) + w5 * hi16(v5.y) + w6 * hi16(v6.y) + w7 * hi16(v7.y);
        }
        for (; k + 4 <= end; k += 4){
            int s0 = srcC[k], s1 = srcC[k + 1], s2 = srcC[k + 2], s3 = srcC[k + 3];
            float w0 = wE[k], w1 = wE[k + 1], w2 = wE[k + 2], w3 = wE[k + 3];
            uint2 v0 = T[(size_t)s0 * 64 + lane];
            uint2 v1 = T[(size_t)s1 * 64 + lane];
            uint2 v2 = T[(size_t)s2 * 64 + lane];
            uint2 v3 = T[(size_t)s3 * 64 + lane];
            a0 += w0 * lo16(v0.x) + w1 * lo16(v1.x) + w2 * lo16(v2.x) + w3 * lo16(v3.x);
            a1 += w0 * hi16(v0.x) + w1 * hi16(v1.x) + w2 * hi16(v2.x) + w3 * hi16(v3.x);
            a2 += w0 * lo16(v0.y) + w1 * lo16(v1.y) + w2 * lo16(v2.y) + w3 * lo16(v3.y);
            a3 += w0 * hi16(v0.y) + w1 * hi16(v1.y) + w2 * hi16(v2.y) + w3 * hi16(v3.y);
        }
        for (; k < end; ++k){
            int s = srcC[k];
            float w = wE[k];
            uint2 v = T[(size_t)s * 64 + lane];
            a0 += w * lo16(v.x); a1 += w * hi16(v.x);
            a2 += w * lo16(v.y); a3 += w * hi16(v.y);
        }
        a0 = dd * (a0 + dd * lo16(sv.x)) + b0;
        a1 = dd * (a1 + dd * hi16(sv.x)) + b1;
        a2 = dd * (a2 + dd * lo16(sv.y)) + b2;
        a3 = dd * (a3 + dd * hi16(sv.y)) + b3;
        a0 = a0 > 0.f ? a0 : expm1f(a0);
        a1 = a1 > 0.f ? a1 : expm1f(a1);
        a2 = a2 > 0.f ? a2 : expm1f(a2);
        a3 = a3 > 0.f ? a3 : expm1f(a3);
        int g = batch[node];
        if (g != curG){
            if (curG >= 0) flush(curG);
            curG = g; p0 = a0; p1 = a1; p2 = a2; p3 = a3;
        } else {
            p0 += a0; p1 += a1; p2 += a2; p3 += a3;
        }
    }
    if (curG >= 0) flush(curG);

    __syncthreads();
    // block-level flush: one global atomic per (slot, column)
    for (int j = (tid >> 8); j < GP_SLOTS; j += 2){
        int g = sTag[j];
        if (g < 0) continue;
        int col = tid & 255;
        float v = sAcc[j][col];
        if (v != 0.f){
            float* dst = (col < 128) ? &pool0[(size_t)g * 128 + col]
                                     : &pool1[(size_t)g * 128 + col - 128];
            atomicAdd(dst, v);
        }
    }
}

// ---------- attention ----------
__global__ __launch_bounds__(256) void k_prep(const bf16_t* __restrict__ h,
        const float* __restrict__ eW, const float* __restrict__ naW,
        float4* __restrict__ epre, float* __restrict__ ntT, int n)
{
    int i = blockIdx.x * 4 + (threadIdx.x >> 6);
    if (i >= n) return;
    int lane = threadIdx.x & 63;
    float h0 = b2f(h[(size_t)i * 128 + lane]), h1 = b2f(h[(size_t)i * 128 + 64 + lane]);
    float s0 = h0 * eW[lane * 2]             + h1 * eW[(64 + lane) * 2];
    float s1 = h0 * eW[lane * 2 + 1]         + h1 * eW[(64 + lane) * 2 + 1];
    float d0 = h0 * eW[(128 + lane) * 2]     + h1 * eW[(192 + lane) * 2];
    float d1 = h0 * eW[(128 + lane) * 2 + 1] + h1 * eW[(192 + lane) * 2 + 1];
    float n0 = h0 * naW[lane * 2]            + h1 * naW[(64 + lane) * 2];
    float n1 = h0 * naW[lane * 2 + 1]        + h1 * naW[(64 + lane) * 2 + 1];
    for (int off = 32; off; off >>= 1){
        s0 += __shfl_xor(s0, off); s1 += __shfl_xor(s1, off);
        d0 += __shfl_xor(d0, off); d1 += __shfl_xor(d1, off);
        n0 += __shfl_xor(n0, off); n1 += __shfl_xor(n1, off);
    }
    if (lane == 0){
        epre[i] = make_float4(s0, s1, d0, d1);
        ntT[2 * i] = n0; ntT[2 * i + 1] = n1;
    }
}
__global__ void k_eatt2(const int* __restrict__ src, const int* __restrict__ dst,
        const int* __restrict__ slotOf, const float4* __restrict__ epre,
        const float* __restrict__ eb, float* __restrict__ wB0,
        float* __restrict__ wB1, float* __restrict__ d0, float* __restrict__ d1, int e){
    int i = blockIdx.x * 256 + threadIdx.x;
    if (i >= e) return;
    int s = src[i];
    float4 ps = epre[s], pd = epre[dst[i]];
    float l0 = ps.x + pd.z + eb[0], l1 = ps.y + pd.w + eb[1];
    float m = fmaxf(l0, l1);
    float e0 = expf(l0 - m), e1 = expf(l1 - m);
    float inv = 1.f / (e0 + e1);
    e0 *= inv; e1 *= inv;
    int slot = slotOf[i];
    wB0[slot] = e0; wB1[slot] = e1;
    atomicAdd(&d0[s], e0); atomicAdd(&d1[s], e1);
}
__global__ void k_natt(const int* __restrict__ ptr, const int* __restrict__ srcC,
        const float* __restrict__ wU, const float* __restrict__ dis,
        const float* __restrict__ ntT, const float* __restrict__ nab,
        float* __restrict__ natt, int n){
    int i = blockIdx.x * 256 + threadIdx.x;
    if (i >= n) return;
    float dd = dis[i];
    float z0 = 0.f, z1 = 0.f;
    int end = ptr[i + 1];
    for (int k = ptr[i]; k < end; ++k){
        int s = srcC[k];
        float w = wU[k];
        z0 += w * ntT[2 * s]; z1 += w * ntT[2 * s + 1];
    }
    z0 = dd * (z0 + dd * ntT[2 * i])     + nab[0];
    z1 = dd * (z1 + dd * ntT[2 * i + 1]) + nab[1];
    float m = fmaxf(z0, z1);
    float e0 = expf(z0 - m), e1 = expf(z1 - m);
    float inv = 1.f / (e0 + e1);
    natt[2 * i] = e0 * inv; natt[2 * i + 1] = e1 * inv;
}

// ---------- heads (G=512, fp32), 3 heads fused per stage ----------
__global__ __launch_bounds__(1024) void k_gstats3(const float* __restrict__ xcp,
        const float* __restrict__ xop, float* __restrict__ mrsH, int n){
    __shared__ float red[2][1024];
    int head = blockIdx.x;
    const float* a = (head == 1) ? xop : xcp;
    const float* b = (head == 0) ? xcp : xop;
    int f = (head == 2) ? 256 : 128;
    float* mrs = mrsH + head * 512;
    int col = threadIdx.x & (f - 1);
    int rpb = 1024 / f;
    int rw  = threadIdx.x / f;
    float s = 0.f, sq = 0.f;
    for (int r = rw; r < n; r += rpb){
        float v = (col < 128) ? a[(size_t)r * 128 + col] : b[(size_t)r * 128 + col - 128];
        s += v; sq += v * v;
    }
    red[0][threadIdx.x] = s; red[1][threadIdx.x] = sq;
    __syncthreads();
    if (threadIdx.x < (unsigned)f){
        float ts = 0.f, tq = 0.f;
        for (int w = 0; w < rpb; ++w){ ts += red[0][w * f + col]; tq += red[1][w * f + col]; }
        float m = ts / n, var = tq / n - m * m;
        mrs[col] = m; mrs[f + col] = rsqrtf(var + 1e-5f);
    }
}
__global__ __launch_bounds__(128) void k_hgemm3(const float* __restrict__ xcp,
        const float* __restrict__ xop, const float* __restrict__ mrsH,
        const float* __restrict__ cW1, const float* __restrict__ cb1,
        const float* __restrict__ oW1, const float* __restrict__ ob1,
        const float* __restrict__ coW1, const float* __restrict__ cob1,
        float* __restrict__ gt3)
{
    __shared__ float as[256];
    int head = blockIdx.y, row = blockIdx.x, tid = threadIdx.x;
    const float* a  = (head == 1) ? xop : xcp;
    const float* b2 = (head == 0) ? xcp : xop;
    int fin = (head == 2) ? 256 : 128;
    const float* mrs = mrsH + head * 512;
    const float* W  = (head == 0) ? cW1 : (head == 1) ? oW1 : coW1;
    const float* bb = (head == 0) ? cb1 : (head == 1) ? ob1 : cob1;
    float* o = gt3 + (size_t)head * 512 * 128;
    for (int i = tid; i < fin; i += 128){
        float v = (i < 128) ? a[(size_t)row * 128 + i] : b2[(size_t)row * 128 + i - 128];
        as[i] = (v - mrs[i]) * mrs[fin + i] + 1e-4f;
    }
    __syncthreads();
    float s = 0.f;
    for (int k = 0; k < fin; ++k) s += as[k] * W[k * 128 + tid];
    s += bb[tid];
    if (head < 2) s = fmaxf(s, 0.f);
    else { s = s > 0.f ? s : expm1f(s); s = s > 0.f ? s : expm1f(s); }
    o[(size_t)row * 128 + tid] = s;
}
__global__ __launch_bounds__(1024) void k_gstats3b(const float* __restrict__ gt3,
        float* __restrict__ mrsH2, int n){
    __shared__ float red[2][1024];
    int head = blockIdx.x;
    const float* a = gt3 + (size_t)head * 512 * 128;
    float* mrs = mrsH2 + head * 256;
    int col = threadIdx.x & 127;
    int rw  = threadIdx.x >> 7;    // 8 rows/block-pass
    float s = 0.f, sq = 0.f;
    for (int r = rw; r < n; r += 8){
        float v = a[(size_t)r * 128 + col];
        s += v; sq += v * v;
    }
    red[0][threadIdx.x] = s; red[1][threadIdx.x] = sq;
    __syncthreads();
    if (threadIdx.x < 128u){
        float ts = 0.f, tq = 0.f;
        for (int w = 0; w < 8; ++w){ ts += red[0][w * 128 + col]; tq += red[1][w * 128 + col]; }
        float m = ts / n, var = tq / n - m * m;
        mrs[col] = m; mrs[128 + col] = rsqrtf(var + 1e-5f);
    }
}
__global__ __launch_bounds__(256) void k_hfinal3(const float* __restrict__ gt3,
        const float* __restrict__ mrsH2,
        const float* __restrict__ cW2, const float* __restrict__ cb2,
        const float* __restrict__ oW2, const float* __restrict__ ob2,
        const float* __restrict__ coW2, const float* __restrict__ cob2,
        float* __restrict__ out, int nrows)
{
    int head = blockIdx.y;
    int row = blockIdx.x * 4 + (threadIdx.x >> 6);
    if (row >= nrows) return;
    int lane = threadIdx.x & 63;
    const float* a   = gt3 + (size_t)head * 512 * 128;
    const float* mrs = mrsH2 + head * 256;
    const float* W = (head == 0) ? cW2 : (head == 1) ? oW2 : coW2;
    const float* b = (head == 0) ? cb2 : (head == 1) ? ob2 : cob2;
    float* o = out + (size_t)head * nrows * 10;
    float v0 = (a[(size_t)row * 128 + lane]      - mrs[lane])      * mrs[128 + lane]      + 1e-4f;
    float v1 = (a[(size_t)row * 128 + 64 + lane] - mrs[64 + lane]) * mrs[128 + 64 + lane] + 1e-4f;
    float logit[10];
    #pragma unroll
    for (int c = 0; c < 10; ++c){
        float p = v0 * W[lane * 10 + c] + v1 * W[(lane + 64) * 10 + c];
        for (int off = 32; off; off >>= 1) p += __shfl_xor(p, off);
        logit[c] = p + b[c];
    }
    float m = logit[0];
    #pragma unroll
    for (int c = 1; c < 10; ++c) m = fmaxf(m, logit[c]);
    float s = 0.f;
    #pragma unroll
    for (int c = 0; c < 10; ++c) s += expf(logit[c] - m);
    float lse = logf(s);
    if (lane < 10) o[row * 10 + lane] = logit[lane] - m - lse;
}

extern "C" void kernel_launch(void* const* d_in, const int* in_sizes, int n_in,
                              void* d_out, int out_size, void* d_ws, size_t ws_size,
                              hipStream_t stream)
{
    const int N = in_sizes[0] / 128;
    const int E = in_sizes[24];
    const int G = 512;
    const float* x    = (const float*)d_in[0];
    const float* Wf   = (const float*)d_in[1];
    const float* cWs  = (const float*)d_in[2];
    const float* cbs  = (const float*)d_in[3];
    const float* eW   = (const float*)d_in[4];
    const float* ebv  = (const float*)d_in[5];
    const float* naW  = (const float*)d_in[6];
    const float* nab  = (const float*)d_in[7];
    const float* xcW  = (const float*)d_in[8];
    const float* xcb  = (const float*)d_in[9];
    const float* xoW  = (const float*)d_in[10];
    const float* xob  = (const float*)d_in[11];
    const float* cW1  = (const float*)d_in[12];
    const float* cb1  = (const float*)d_in[13];
    const float* cW2  = (const float*)d_in[14];
    const float* cb2  = (const float*)d_in[15];
    const float* oW1  = (const float*)d_in[16];
    const float* ob1  = (const float*)d_in[17];
    const float* oW2  = (const float*)d_in[18];
    const float* ob2  = (const float*)d_in[19];
    const float* coW1 = (const float*)d_in[20];
    const float* cob1 = (const float*)d_in[21];
    const float* coW2 = (const float*)d_in[22];
    const float* cob2 = (const float*)d_in[23];
    const int* esrc  = (const int*)d_in[24];
    const int* edst  = (const int*)d_in[25];
    const int* batch = (const int*)d_in[26];
    float* out = (float*)d_out;

    size_t NH = (size_t)N * 128;
    bf16_t* B1  = (bf16_t*)d_ws;            // N*128
    bf16_t* B0  = B1 + NH;                  // N*128
    bf16_t* B0c = B0 + NH;                  // N*256 ([xc|xo])
    float* fbase = (float*)(B0c + 2 * NH);
    float* epreF = fbase;                   // 4N
    float* ntT   = epreF + 4 * (size_t)N;
    float* natt  = ntT + 2 * (size_t)N;
    float* disU  = natt + 2 * (size_t)N;
    float* disW0 = disU + N;
    float* disW1 = disW0 + N;
    float* mrsA  = disW1 + N;               // 256
    float* mrsB  = mrsA + 256;              // 256
    float* mrsH  = mrsB + 256;              // 1536 (3 heads x 512)
    float* mrsH2 = mrsH + 1536;             // 768  (3 heads x 256)
    float* wU    = mrsH2 + 768;             // E (CSR order)
    float* wB0   = wU + E;                  // E
    float* wB1   = wB0 + E;                 // E
    float* gt3   = wB1 + E;                 // 3*G*128
    // zero zone (single memset)
    float* zz    = gt3 + (size_t)3 * G * 128;
    float* degU  = zz;                      // N
    float* degC0 = degU + N;                // N
    float* degC1 = degC0 + N;               // N
    float* stZ   = degC1 + N;               // 1536
    float* xcp   = stZ + 1536;              // G*128
    float* xop   = xcp + (size_t)G * 128;   // G*128
    int*   cntI  = (int*)(xop + (size_t)G * 128);   // N (zeroed: part of zz span)
    size_t zzBytes = ((size_t)(4 * N) + 1536 + 2 * (size_t)G * 128) * 4;
    int* ptrI   = cntI + N;                 // N+1
    int* fillI  = ptrI + N + 1;             // N
    int* srcC   = fillI + N;                // E
    int* slotOf = srcC + E;                 // E
    int* bsum   = slotOf + E;               // up to 64
    bf16_t* whiT = (bf16_t*)((((size_t)(bsum + 64)) + 15) & ~(size_t)15);  // 6*16384
    bf16_t* wloT = whiT + 6 * 16384;                                       // 6*16384
    float4* epre = (float4*)epreF;

    int gridE = (E + 255) / 256;
    int gridN = (N + 255) / 256;
    int gridW = (N + 3) / 4;
    int gridG = (N + 63) / 64;
    int nb    = (N + 1023) / 1024;
    int span  = N / 16384; if (span < 1) span = 1;
    int gridP = (N + span * 8 - 1) / (span * 8);

    hipMemsetAsync(zz, 0, zzBytes, stream);

    // ---- weight pre-split (independent of everything else) ----
    k_wsplit<<<dim3(16, 6), 256, 0, stream>>>(Wf, cWs, xcW, xoW, whiT, wloT);

    // ---- CSR by dst + degrees + CSR weights ----
    k_hist2<<<gridE, 256, 0, stream>>>(esrc, edst, cntI, degU, E);
    k_scanA<<<nb, 1024, 0, stream>>>(cntI, ptrI, bsum, N);
    k_scanB<<<1, 64, 0, stream>>>(bsum, ptrI + N, nb);
    k_scanC<<<nb, 1024, 0, stream>>>(ptrI, bsum, fillI, N);
    k_fill<<<gridE, 256, 0, stream>>>(esrc, edst, fillI, srcC, slotOf, E);
    k_dis<<<gridN, 256, 0, stream>>>(degU, disU, N);
    k_wU<<<gridE, 256, 0, stream>>>(srcC, disU, wU, E);

    // ---- h = relu(BN(x) @ W_feat) -> B1 (bf16) ----
    k_statsF<<<256, 256, 0, stream>>>(x, stZ, N);
    k_finstats<<<1, 128, 0, stream>>>(stZ, mrsA, N);
    k_gemm<1, 0><<<gridG, 256, 0, stream>>>(x, nullptr, 0, mrsA, whiT, wloT, B1, 128, 0, N);

    // ---- 3 x [BN -> GCNConv -> relu] ----
    for (int i = 0; i < 3; ++i){
        float* st = stZ + 256 * (i + 1);
        k_statsB<<<256, 256, 0, stream>>>(B1, st, N);
        k_finstats<<<1, 128, 0, stream>>>(st, mrsA, N);
        k_gemm<0, 1><<<gridG, 256, 0, stream>>>(B1, nullptr, 0, mrsA,
                whiT + (size_t)(i + 1) * 16384, wloT + (size_t)(i + 1) * 16384,
                B0, 128, 0, N);
        k_gather0<<<gridW, 256, 0, stream>>>(ptrI, srcC, wU, disU, B0, cbs + i * 128, B1, N);
    }

    // ---- attention ----
    k_prep<<<gridW, 256, 0, stream>>>(B1, eW, naW, epre, ntT, N);
    k_eatt2<<<gridE, 256, 0, stream>>>(esrc, edst, slotOf, epre, ebv, wB0, wB1,
                                       degC0, degC1, E);
    k_natt<<<gridN, 256, 0, stream>>>(ptrI, srcC, wU, disU, ntT, nab, natt, N);

    // ---- branch stats + weighted degree norms + CSR branch weights ----
    k_stats2<<<256, 256, 0, stream>>>(B1, natt, stZ + 1024, N);
    k_finstatsB<<<1, 128, 0, stream>>>(stZ + 1024, mrsA, mrsB, N);
    k_dis2<<<gridN, 256, 0, stream>>>(degC0, degC1, disW0, disW1, N);
    k_wB<<<gridE, 256, 0, stream>>>(srcC, disW0, disW1, wB0, wB1, E);

    // ---- xc / xo branch GEMMs into combined B0c, then ONE gather ----
    k_gemm<0, 1><<<gridG, 256, 0, stream>>>(B1, natt, 0, mrsA,
            whiT + (size_t)4 * 16384, wloT + (size_t)4 * 16384, B0c, 256, 0, N);
    k_gemm<0, 1><<<gridG, 256, 0, stream>>>(B1, natt, 1, mrsB,
            whiT + (size_t)5 * 16384, wloT + (size_t)5 * 16384, B0c, 256, 128, N);
    k_gatherP<<<gridP, 512, 0, stream>>>(ptrI, srcC, wB0, wB1, disW0, disW1, B0c,
                                         xcb, xob, batch, xcp, xop, N, span);

    // ---- heads: 3 heads fused per stage ----
    k_gstats3<<<3, 1024, 0, stream>>>(xcp, xop, mrsH, G);
    k_hgemm3<<<dim3(G, 3), 128, 0, stream>>>(xcp, xop, mrsH, cW1, cb1, oW1, ob1,
                                             coW1, cob1, gt3);
    k_gstats3b<<<3, 1024, 0, stream>>>(gt3, mrsH2, G);
    k_hfinal3<<<dim3((G + 3) / 4, 3), 256, 0, stream>>>(gt3, mrsH2, cW2, cb2, oW2, ob2,
                                                        coW2, cob2, out, G);
}

// Round 3
// 770.031 us; speedup vs baseline: 1.2992x; 1.0276x over previous
//
#include <hip/hip_runtime.h>

// CausalGCN forward on MI355X. fp32 in/out; internal N x 128 tensors bf16.
// R10: gatherP reverted to reg-pool/256-thr (R9 LDS-combine regressed: latency-bound,
//      concurrency > atomic-write savings) + unroll 8. eatt2 CSR-ordered (coalesced
//      writes). finstats/dis folded into consumers (-7 launches).

typedef unsigned short bf16_t;
typedef unsigned int   uint32;
typedef __attribute__((ext_vector_type(8))) short   bf16x8;
typedef __attribute__((ext_vector_type(4))) float   f32x4;

__device__ __forceinline__ float b2f(bf16_t v){ return __uint_as_float(((uint32)v) << 16); }
__device__ __forceinline__ bf16_t f2b(float f){
    uint32 u = __float_as_uint(f);
    return (bf16_t)((u + 0x7fffu + ((u >> 16) & 1u)) >> 16);   // RNE
}
__device__ __forceinline__ uint32 pack2(float lo, float hi){
    return (uint32)f2b(lo) | ((uint32)f2b(hi) << 16);
}
__device__ __forceinline__ float lo16(uint32 u){ return __uint_as_float(u << 16); }
__device__ __forceinline__ float hi16(uint32 u){ return __uint_as_float(u & 0xffff0000u); }

// ---------- BN stats (raw sum/sumsq; mean/rstd derived in consumers) ----------
__global__ void k_statsF(const float* __restrict__ a, float* __restrict__ st, int n){
    int tid = threadIdx.x;
    int feat = tid & 127;
    int row = blockIdx.x * 2 + (tid >> 7);
    float s = 0.f, sq = 0.f;
    for (; row < n; row += gridDim.x * 2){
        float v = a[(size_t)row * 128 + feat];
        s += v; sq += v * v;
    }
    atomicAdd(&st[feat], s);
    atomicAdd(&st[128 + feat], sq);
}
__global__ void k_statsB(const bf16_t* __restrict__ a, float* __restrict__ st, int n){
    int tid = threadIdx.x;
    int feat = tid & 127;
    int row = blockIdx.x * 2 + (tid >> 7);
    float s = 0.f, sq = 0.f;
    for (; row < n; row += gridDim.x * 2){
        float v = b2f(a[(size_t)row * 128 + feat]);
        s += v; sq += v * v;
    }
    atomicAdd(&st[feat], s);
    atomicAdd(&st[128 + feat], sq);
}
__global__ void k_stats2(const bf16_t* __restrict__ a, const float* __restrict__ natt,
                         float* __restrict__ st, int n){
    int tid = threadIdx.x;
    int feat = tid & 127;
    int row = blockIdx.x * 2 + (tid >> 7);
    float s0 = 0.f, q0 = 0.f, s1 = 0.f, q1 = 0.f;
    for (; row < n; row += gridDim.x * 2){
        float v = b2f(a[(size_t)row * 128 + feat]);
        float2 w = *(const float2*)&natt[(size_t)row * 2];
        float v0 = v * w.x, v1 = v * w.y;
        s0 += v0; q0 += v0 * v0; s1 += v1; q1 += v1 * v1;
    }
    atomicAdd(&st[feat], s0);       atomicAdd(&st[128 + feat], q0);
    atomicAdd(&st[256 + feat], s1); atomicAdd(&st[384 + feat], q1);
}

// ---------- W pre-split: fp32 [k][n] -> bf16 hi/lo transposed [n][k], 6 matrices ----------
__global__ void k_wsplit(const float* __restrict__ Wf, const float* __restrict__ cWs,
        const float* __restrict__ xcW, const float* __restrict__ xoW,
        bf16_t* __restrict__ whiT, bf16_t* __restrict__ wloT)
{
    int mat = blockIdx.y;
    const float* src = (mat == 0) ? Wf : (mat <= 3) ? cWs + (size_t)(mat - 1) * 16384
                      : (mat == 4) ? xcW : xoW;
    int i = (blockIdx.x * 256 + threadIdx.x) * 4;
    int nrow = i >> 7, k0 = i & 127;
    size_t off = (size_t)mat * 16384 + (size_t)nrow * 128 + k0;
    #pragma unroll
    for (int j = 0; j < 4; ++j){
        float w = src[(size_t)(k0 + j) * 128 + nrow];
        bf16_t h = f2b(w);
        whiT[off + j] = h;
        wloT[off + j] = f2b(w - b2f(h));
    }
}

// ---------- MFMA GEMM: C[n, ccol0..+128 of ldc] = act( BN(scale*A) @ W ) ----------
// W pre-split bf16 hi+lo (two MFMAs) -> ~fp32 weight precision. BN mean/rstd derived
// from raw sums per-thread (each staging thread owns 8 fixed columns).
// LDS: As 64x136 bf16 + Whi/Wlo 128x72 bf16 = 54.3KB -> 3 blk/CU.
template<int ACT, int INBF>  // ACT: 1=relu ; INBF: input bf16?
__global__ __launch_bounds__(256, 3) void k_gemm(const void* __restrict__ Av,
        const float* __restrict__ scale, int sch,
        const float* __restrict__ st, const bf16_t* __restrict__ WhiT,
        const bf16_t* __restrict__ WloT,
        bf16_t* __restrict__ C, int ldc, int ccol0, int n)
{
    __shared__ bf16_t As[64 * 136];
    __shared__ bf16_t Whi[128 * 72];
    __shared__ bf16_t Wlo[128 * 72];
    int tid = threadIdx.x;
    int wid = tid >> 6, lane = tid & 63;
    int row0 = blockIdx.x * 64;
    int m0 = wid * 16;
    int q8 = (lane >> 4) * 8, l15 = lane & 15;

    // per-thread BN params for its 8 fixed columns
    int c8t = (tid & 15) * 8;
    float sM[8], sR[8];
    #pragma unroll
    for (int j = 0; j < 8; ++j){
        float m = st[c8t + j] / n;
        float var = st[128 + c8t + j] / n - m * m;
        sM[j] = m; sR[j] = rsqrtf(var + 1e-5f);
    }

    // stage A (BN applied, bf16) : 64 rows x 128 cols
    for (int i = tid; i < 64 * 16; i += 256){
        int r = i >> 4, c8 = (i & 15) * 8;   // c8 == c8t for all iterations
        int gr = row0 + r;
        float v[8];
        if (gr < n){
            float sc = scale ? scale[(size_t)gr * 2 + sch] : 1.f;
            if (INBF){
                const bf16_t* Ab = (const bf16_t*)Av;
                ushort4 qa = *(const ushort4*)&Ab[(size_t)gr * 128 + c8];
                ushort4 qb = *(const ushort4*)&Ab[(size_t)gr * 128 + c8 + 4];
                v[0]=b2f(qa.x); v[1]=b2f(qa.y); v[2]=b2f(qa.z); v[3]=b2f(qa.w);
                v[4]=b2f(qb.x); v[5]=b2f(qb.y); v[6]=b2f(qb.z); v[7]=b2f(qb.w);
            } else {
                const float* Af = (const float*)Av;
                float4 fa = *(const float4*)&Af[(size_t)gr * 128 + c8];
                float4 fb = *(const float4*)&Af[(size_t)gr * 128 + c8 + 4];
                v[0]=fa.x; v[1]=fa.y; v[2]=fa.z; v[3]=fa.w;
                v[4]=fb.x; v[5]=fb.y; v[6]=fb.z; v[7]=fb.w;
            }
            #pragma unroll
            for (int j = 0; j < 8; ++j)
                v[j] = (v[j] * sc - sM[j]) * sR[j] + 1e-4f;
        } else {
            #pragma unroll
            for (int j = 0; j < 8; ++j) v[j] = 0.f;
        }
        #pragma unroll
        for (int j = 0; j < 8; ++j) As[r * 136 + c8 + j] = f2b(v[j]);
    }

    f32x4 acc[8];
    #pragma unroll
    for (int t = 0; t < 8; ++t) acc[t] = (f32x4){0.f, 0.f, 0.f, 0.f};

    for (int kc = 0; kc < 128; kc += 64){
        __syncthreads();
        // stage W chunk (pre-split, pre-transposed): pure uint4 copies
        for (int i = tid; i < 128 * 8; i += 256){
            int nrow = i >> 3, k8 = (i & 7) * 8;
            *(uint4*)&Whi[nrow * 72 + k8] = *(const uint4*)&WhiT[(size_t)nrow * 128 + kc + k8];
            *(uint4*)&Wlo[nrow * 72 + k8] = *(const uint4*)&WloT[(size_t)nrow * 128 + kc + k8];
        }
        __syncthreads();
        #pragma unroll
        for (int kbl = 0; kbl < 2; ++kbl){
            bf16x8 a = *(const bf16x8*)&As[(m0 + l15) * 136 + kc + kbl * 32 + q8];
            #pragma unroll
            for (int nt = 0; nt < 8; ++nt){
                bf16x8 bh = *(const bf16x8*)&Whi[(nt * 16 + l15) * 72 + kbl * 32 + q8];
                acc[nt] = __builtin_amdgcn_mfma_f32_16x16x32_bf16(a, bh, acc[nt], 0, 0, 0);
                bf16x8 bl = *(const bf16x8*)&Wlo[(nt * 16 + l15) * 72 + kbl * 32 + q8];
                acc[nt] = __builtin_amdgcn_mfma_f32_16x16x32_bf16(a, bl, acc[nt], 0, 0, 0);
            }
        }
    }

    // epilogue: acc -> LDS (bf16) -> coalesced store
    __syncthreads();
    #pragma unroll
    for (int nt = 0; nt < 8; ++nt){
        #pragma unroll
        for (int r = 0; r < 4; ++r){
            float v = acc[nt][r];
            if (ACT == 1) v = fmaxf(v, 0.f);
            As[(m0 + (lane >> 4) * 4 + r) * 136 + nt * 16 + l15] = f2b(v);
        }
    }
    __syncthreads();
    for (int i = tid; i < 64 * 16; i += 256){
        int r = i >> 4, c8 = (i & 15) * 8;
        int gr = row0 + r;
        if (gr < n)
            *(uint4*)&C[(size_t)gr * ldc + ccol0 + c8] = *(const uint4*)&As[r * 136 + c8];
    }
}

// ---------- CSR build (by dst) ----------
__global__ void k_hist2(const int* __restrict__ src, const int* __restrict__ dst,
                        int* __restrict__ cnt, float* __restrict__ degU, int e){
    int i = blockIdx.x * 256 + threadIdx.x;
    if (i < e){
        atomicAdd(&cnt[dst[i]], 1);
        atomicAdd(&degU[src[i]], 1.0f);
    }
}
__global__ __launch_bounds__(1024) void k_scanA(const int* __restrict__ cnt,
        int* __restrict__ ptr, int* __restrict__ bsum, int n){
    __shared__ int wsum[16];
    int t = threadIdx.x, lane = t & 63, wid = t >> 6;
    int i = blockIdx.x * 1024 + t;
    int v = (i < n) ? cnt[i] : 0;
    int s = v;
    for (int off = 1; off < 64; off <<= 1){
        int u = __shfl_up(s, off);
        if (lane >= off) s += u;
    }
    if (lane == 63) wsum[wid] = s;
    __syncthreads();
    if (wid == 0 && lane < 16){
        int ws = wsum[lane];
        for (int off = 1; off < 16; off <<= 1){
            int u = __shfl_up(ws, off);
            if (lane >= off) ws += u;
        }
        wsum[lane] = ws;
    }
    __syncthreads();
    int woff = wid ? wsum[wid - 1] : 0;
    if (i < n) ptr[i] = woff + s - v;
    if (t == 1023) bsum[blockIdx.x] = woff + s;
}
__global__ void k_scanB(int* __restrict__ bsum, int* __restrict__ ptrN, int nb){
    int lane = threadIdx.x;       // 64 threads
    int carry = 0;
    for (int base = 0; base < nb; base += 64){
        int i = base + lane;
        int v = (i < nb) ? bsum[i] : 0;
        int s = v;
        for (int off = 1; off < 64; off <<= 1){
            int u = __shfl_up(s, off);
            if (lane >= off) s += u;
        }
        if (i < nb) bsum[i] = carry + s - v;
        carry += __shfl(s, 63);
    }
    if (lane == 0) *ptrN = carry;
}
__global__ __launch_bounds__(1024) void k_scanC(int* __restrict__ ptr,
        const int* __restrict__ bsum, int* __restrict__ fill, int n){
    int i = blockIdx.x * 1024 + threadIdx.x;
    if (i < n){
        int p = ptr[i] + bsum[blockIdx.x];
        ptr[i] = p; fill[i] = p;
    }
}
__global__ void k_fill(const int* __restrict__ src, const int* __restrict__ dst,
                       int* __restrict__ fill, int* __restrict__ srcC,
                       int* __restrict__ dstC, int e){
    int i = blockIdx.x * 256 + threadIdx.x;
    if (i < e){
        int d = dst[i];
        int slot = atomicAdd(&fill[d], 1);
        srcC[slot] = src[i];
        dstC[slot] = d;
    }
}

// ---------- edge weights (rsqrt fused) ----------
__global__ void k_wU(const int* __restrict__ srcC, const float* __restrict__ degU,
                     float* __restrict__ wU, int e){
    int i = blockIdx.x * 256 + threadIdx.x;
    if (i < e) wU[i] = rsqrtf(degU[srcC[i]] + 1.0f);
}
__global__ void k_wB(const int* __restrict__ srcC, const float* __restrict__ degC0,
                     const float* __restrict__ degC1, float* __restrict__ w0,
                     float* __restrict__ w1, int e){
    int i = blockIdx.x * 256 + threadIdx.x;
    if (i < e){
        int s = srcC[i];
        w0[i] *= rsqrtf(degC0[s] + 1.0f);
        w1[i] *= rsqrtf(degC1[s] + 1.0f);
    }
}

// ---------- conv propagate: bf16 in/out, one wave/node, unroll 8 ----------
__global__ __launch_bounds__(256) void k_gather0(const int* __restrict__ ptr,
        const int* __restrict__ srcC, const float* __restrict__ wE,
        const float* __restrict__ degU, const bf16_t* __restrict__ t,
        const float* __restrict__ bias, bf16_t* __restrict__ outB, int n)
{
    int node = blockIdx.x * 4 + (threadIdx.x >> 6);
    if (node >= n) return;
    int lane = threadIdx.x & 63;
    const uint32* T = (const uint32*)t;
    float dd = rsqrtf(degU[node] + 1.0f);
    uint32 sv = T[(size_t)node * 64 + lane];
    float a0 = 0.f, a1 = 0.f;
    int beg = ptr[node], end = ptr[node + 1];
    int k = beg;
    for (; k + 8 <= end; k += 8){
        int s0 = srcC[k],     s1 = srcC[k + 1], s2 = srcC[k + 2], s3 = srcC[k + 3];
        int s4 = srcC[k + 4], s5 = srcC[k + 5], s6 = srcC[k + 6], s7 = srcC[k + 7];
        float w0 = wE[k],     w1 = wE[k + 1], w2 = wE[k + 2], w3 = wE[k + 3];
        float w4 = wE[k + 4], w5 = wE[k + 5], w6 = wE[k + 6], w7 = wE[k + 7];
        uint32 v0 = T[(size_t)s0 * 64 + lane];
        uint32 v1 = T[(size_t)s1 * 64 + lane];
        uint32 v2 = T[(size_t)s2 * 64 + lane];
        uint32 v3 = T[(size_t)s3 * 64 + lane];
        uint32 v4 = T[(size_t)s4 * 64 + lane];
        uint32 v5 = T[(size_t)s5 * 64 + lane];
        uint32 v6 = T[(size_t)s6 * 64 + lane];
        uint32 v7 = T[(size_t)s7 * 64 + lane];
        a0 += w0 * lo16(v0) + w1 * lo16(v1) + w2 * lo16(v2) + w3 * lo16(v3);
        a1 += w0 * hi16(v0) + w1 * hi16(v1) + w2 * hi16(v2) + w3 * hi16(v3);
        a0 += w4 * lo16(v4) + w5 * lo16(v5) + w6 * lo16(v6) + w7 * lo16(v7);
        a1 += w4 * hi16(v4) + w5 * hi16(v5) + w6 * hi16(v6) + w7 * hi16(v7);
    }
    for (; k + 4 <= end; k += 4){
        int s0 = srcC[k], s1 = srcC[k + 1], s2 = srcC[k + 2], s3 = srcC[k + 3];
        float w0 = wE[k], w1 = wE[k + 1], w2 = wE[k + 2], w3 = wE[k + 3];
        uint32 v0 = T[(size_t)s0 * 64 + lane];
        uint32 v1 = T[(size_t)s1 * 64 + lane];
        uint32 v2 = T[(size_t)s2 * 64 + lane];
        uint32 v3 = T[(size_t)s3 * 64 + lane];
        a0 += w0 * lo16(v0) + w1 * lo16(v1) + w2 * lo16(v2) + w3 * lo16(v3);
        a1 += w0 * hi16(v0) + w1 * hi16(v1) + w2 * hi16(v2) + w3 * hi16(v3);
    }
    for (; k < end; ++k){
        int s = srcC[k];
        float w = wE[k];
        uint32 v = T[(size_t)s * 64 + lane];
        a0 += w * lo16(v); a1 += w * hi16(v);
    }
    a0 = fmaxf(dd * (a0 + dd * lo16(sv)) + bias[2 * lane],     0.f);
    a1 = fmaxf(dd * (a1 + dd * hi16(sv)) + bias[2 * lane + 1], 0.f);
    ((uint32*)outB)[(size_t)node * 64 + lane] = pack2(a0, a1);
}

// ---------- branch propagate: span-per-wave, register pool accumulation, unroll 8 ----------
__global__ __launch_bounds__(256) void k_gatherP(const int* __restrict__ ptr,
        const int* __restrict__ srcC, const float* __restrict__ w0E,
        const float* __restrict__ w1E, const float* __restrict__ degC0,
        const float* __restrict__ degC1, const bf16_t* __restrict__ t,
        const float* __restrict__ biasC, const float* __restrict__ biasO,
        const int* __restrict__ batch, float* __restrict__ pool0,
        float* __restrict__ pool1, int n, int span)
{
    int wave = blockIdx.x * 4 + (threadIdx.x >> 6);
    int lane = threadIdx.x & 63;
    int nbeg = wave * span;
    if (nbeg >= n) return;
    int nend = min(n, nbeg + span);
    bool br0 = lane < 32;
    const float* wE  = br0 ? w0E : w1E;
    const float* deg = br0 ? degC0 : degC1;
    int c = 4 * lane;
    const float* bias = br0 ? (biasC + c) : (biasO + c - 128);
    float b0 = bias[0], b1 = bias[1], b2 = bias[2], b3 = bias[3];
    float* pool = br0 ? (pool0 + c) : (pool1 + c - 128);
    const uint2* T = (const uint2*)t;
    int curG = -1;
    float p0 = 0.f, p1 = 0.f, p2 = 0.f, p3 = 0.f;
    for (int node = nbeg; node < nend; ++node){
        float dd = rsqrtf(deg[node] + 1.0f);
        uint2 sv = T[(size_t)node * 64 + lane];
        float a0 = 0.f, a1 = 0.f, a2 = 0.f, a3 = 0.f;
        int beg = ptr[node], end = ptr[node + 1];
        int k = beg;
        for (; k + 8 <= end; k += 8){
            int s0 = srcC[k],     s1 = srcC[k + 1], s2 = srcC[k + 2], s3 = srcC[k + 3];
            int s4 = srcC[k + 4], s5 = srcC[k + 5], s6 = srcC[k + 6], s7 = srcC[k + 7];
            float w0 = wE[k],     w1 = wE[k + 1], w2 = wE[k + 2], w3 = wE[k + 3];
            float w4 = wE[k + 4], w5 = wE[k + 5], w6 = wE[k + 6], w7 = wE[k + 7];
            uint2 v0 = T[(size_t)s0 * 64 + lane];
            uint2 v1 = T[(size_t)s1 * 64 + lane];
            uint2 v2 = T[(size_t)s2 * 64 + lane];
            uint2 v3 = T[(size_t)s3 * 64 + lane];
            uint2 v4 = T[(size_t)s4 * 64 + lane];
            uint2 v5 = T[(size_t)s5 * 64 + lane];
            uint2 v6 = T[(size_t)s6 * 64 + lane];
            uint2 v7 = T[(size_t)s7 * 64 + lane];
            a0 += w0 * lo16(v0.x) + w1 * lo16(v1.x) + w2 * lo16(v2.x) + w3 * lo16(v3.x);
            a1 += w0 * hi16(v0.x) + w1 * hi16(v1.x) + w2 * hi16(v2.x) + w3 * hi16(v3.x);
            a2 += w0 * lo16(v0.y) + w1 * lo16(v1.y) + w2 * lo16(v2.y) + w3 * lo16(v3.y);
            a3 += w0 * hi16(v0.y) + w1 * hi16(v1.y) + w2 * hi16(v2.y) + w3 * hi16(v3.y);
            a0 += w4 * lo16(v4.x) + w5 * lo16(v5.x) + w6 * lo16(v6.x) + w7 * lo16(v7.x);
            a1 += w4 * hi16(v4.x) + w5 * hi16(v5.x) + w6 * hi16(v6.x) + w7 * hi16(v7.x);
            a2 += w4 * lo16(v4.y) + w5 * lo16(v5.y) + w6 * lo16(v6.y) + w7 * lo16(v7.y);
            a3 += w4 * hi16(v4.y) + w5 * hi16(v5.y) + w6 * hi16(v6.y) + w7 * hi16(v7.y);
        }
        for (; k + 4 <= end; k += 4){
            int s0 = srcC[k], s1 = srcC[k + 1], s2 = srcC[k + 2], s3 = srcC[k + 3];
            float w0 = wE[k], w1 = wE[k + 1], w2 = wE[k + 2], w3 = wE[k + 3];
            uint2 v0 = T[(size_t)s0 * 64 + lane];
            uint2 v1 = T[(size_t)s1 * 64 + lane];
            uint2 v2 = T[(size_t)s2 * 64 + lane];
            uint2 v3 = T[(size_t)s3 * 64 + lane];
            a0 += w0 * lo16(v0.x) + w1 * lo16(v1.x) + w2 * lo16(v2.x) + w3 * lo16(v3.x);
            a1 += w0 * hi16(v0.x) + w1 * hi16(v1.x) + w2 * hi16(v2.x) + w3 * hi16(v3.x);
            a2 += w0 * lo16(v0.y) + w1 * lo16(v1.y) + w2 * lo16(v2.y) + w3 * lo16(v3.y);
            a3 += w0 * hi16(v0.y) + w1 * hi16(v1.y) + w2 * hi16(v2.y) + w3 * hi16(v3.y);
        }
        for (; k < end; ++k){
            int s = srcC[k];
            float w = wE[k];
            uint2 v = T[(size_t)s * 64 + lane];
            a0 += w * lo16(v.x); a1 += w * hi16(v.x);
            a2 += w * lo16(v.y); a3 += w * hi16(v.y);
        }
        a0 = dd * (a0 + dd * lo16(sv.x)) + b0;
        a1 = dd * (a1 + dd * hi16(sv.x)) + b1;
        a2 = dd * (a2 + dd * lo16(sv.y)) + b2;
        a3 = dd * (a3 + dd * hi16(sv.y)) + b3;
        a0 = a0 > 0.f ? a0 : expm1f(a0);
        a1 = a1 > 0.f ? a1 : expm1f(a1);
        a2 = a2 > 0.f ? a2 : expm1f(a2);
        a3 = a3 > 0.f ? a3 : expm1f(a3);
        int g = batch[node];
        if (g != curG){
            if (curG >= 0){
                float* p = pool + (size_t)curG * 128;
                atomicAdd(&p[0], p0); atomicAdd(&p[1], p1);
                atomicAdd(&p[2], p2); atomicAdd(&p[3], p3);
            }
            curG = g; p0 = a0; p1 = a1; p2 = a2; p3 = a3;
        } else {
            p0 += a0; p1 += a1; p2 += a2; p3 += a3;
        }
    }
    if (curG >= 0){
        float* p = pool + (size_t)curG * 128;
        atomicAdd(&p[0], p0); atomicAdd(&p[1], p1);
        atomicAdd(&p[2], p2); atomicAdd(&p[3], p3);
    }
}

// ---------- attention ----------
__global__ __launch_bounds__(256) void k_prep(const bf16_t* __restrict__ h,
        const float* __restrict__ eW, const float* __restrict__ naW,
        float4* __restrict__ epre, float* __restrict__ ntT, int n)
{
    int i = blockIdx.x * 4 + (threadIdx.x >> 6);
    if (i >= n) return;
    int lane = threadIdx.x & 63;
    float h0 = b2f(h[(size_t)i * 128 + lane]), h1 = b2f(h[(size_t)i * 128 + 64 + lane]);
    float s0 = h0 * eW[lane * 2]             + h1 * eW[(64 + lane) * 2];
    float s1 = h0 * eW[lane * 2 + 1]         + h1 * eW[(64 + lane) * 2 + 1];
    float d0 = h0 * eW[(128 + lane) * 2]     + h1 * eW[(192 + lane) * 2];
    float d1 = h0 * eW[(128 + lane) * 2 + 1] + h1 * eW[(192 + lane) * 2 + 1];
    float n0 = h0 * naW[lane * 2]            + h1 * naW[(64 + lane) * 2];
    float n1 = h0 * naW[lane * 2 + 1]        + h1 * naW[(64 + lane) * 2 + 1];
    for (int off = 32; off; off >>= 1){
        s0 += __shfl_xor(s0, off); s1 += __shfl_xor(s1, off);
        d0 += __shfl_xor(d0, off); d1 += __shfl_xor(d1, off);
        n0 += __shfl_xor(n0, off); n1 += __shfl_xor(n1, off);
    }
    if (lane == 0){
        epre[i] = make_float4(s0, s1, d0, d1);
        ntT[2 * i] = n0; ntT[2 * i + 1] = n1;
    }
}
// edge softmax in CSR order: coalesced reads (srcC,dstC) + coalesced writes (wB0,wB1)
__global__ void k_eatt2(const int* __restrict__ srcC, const int* __restrict__ dstC,
        const float4* __restrict__ epre, const float* __restrict__ eb,
        float* __restrict__ wB0, float* __restrict__ wB1,
        float* __restrict__ d0, float* __restrict__ d1, int e){
    int i = blockIdx.x * 256 + threadIdx.x;
    if (i >= e) return;
    int s = srcC[i];
    float4 ps = epre[s], pd = epre[dstC[i]];
    float l0 = ps.x + pd.z + eb[0], l1 = ps.y + pd.w + eb[1];
    float m = fmaxf(l0, l1);
    float e0 = expf(l0 - m), e1 = expf(l1 - m);
    float inv = 1.f / (e0 + e1);
    e0 *= inv; e1 *= inv;
    wB0[i] = e0; wB1[i] = e1;
    atomicAdd(&d0[s], e0); atomicAdd(&d1[s], e1);
}
__global__ void k_natt(const int* __restrict__ ptr, const int* __restrict__ srcC,
        const float* __restrict__ wU, const float* __restrict__ degU,
        const float* __restrict__ ntT, const float* __restrict__ nab,
        float* __restrict__ natt, int n){
    int i = blockIdx.x * 256 + threadIdx.x;
    if (i >= n) return;
    float dd = rsqrtf(degU[i] + 1.0f);
    float z0 = 0.f, z1 = 0.f;
    int end = ptr[i + 1];
    for (int k = ptr[i]; k < end; ++k){
        int s = srcC[k];
        float w = wU[k];
        z0 += w * ntT[2 * s]; z1 += w * ntT[2 * s + 1];
    }
    z0 = dd * (z0 + dd * ntT[2 * i])     + nab[0];
    z1 = dd * (z1 + dd * ntT[2 * i + 1]) + nab[1];
    float m = fmaxf(z0, z1);
    float e0 = expf(z0 - m), e1 = expf(z1 - m);
    float inv = 1.f / (e0 + e1);
    natt[2 * i] = e0 * inv; natt[2 * i + 1] = e1 * inv;
}

// ---------- heads (G=512, fp32), 3 heads fused per stage ----------
__global__ __launch_bounds__(1024) void k_gstats3(const float* __restrict__ xcp,
        const float* __restrict__ xop, float* __restrict__ mrsH, int n){
    __shared__ float red[2][1024];
    int head = blockIdx.x;
    const float* a = (head == 1) ? xop : xcp;
    const float* b = (head == 0) ? xcp : xop;
    int f = (head == 2) ? 256 : 128;
    float* mrs = mrsH + head * 512;
    int col = threadIdx.x & (f - 1);
    int rpb = 1024 / f;
    int rw  = threadIdx.x / f;
    float s = 0.f, sq = 0.f;
    for (int r = rw; r < n; r += rpb){
        float v = (col < 128) ? a[(size_t)r * 128 + col] : b[(size_t)r * 128 + col - 128];
        s += v; sq += v * v;
    }
    red[0][threadIdx.x] = s; red[1][threadIdx.x] = sq;
    __syncthreads();
    if (threadIdx.x < (unsigned)f){
        float ts = 0.f, tq = 0.f;
        for (int w = 0; w < rpb; ++w){ ts += red[0][w * f + col]; tq += red[1][w * f + col]; }
        float m = ts / n, var = tq / n - m * m;
        mrs[col] = m; mrs[f + col] = rsqrtf(var + 1e-5f);
    }
}
__global__ __launch_bounds__(128) void k_hgemm3(const float* __restrict__ xcp,
        const float* __restrict__ xop, const float* __restrict__ mrsH,
        const float* __restrict__ cW1, const float* __restrict__ cb1,
        const float* __restrict__ oW1, const float* __restrict__ ob1,
        const float* __restrict__ coW1, const float* __restrict__ cob1,
        float* __restrict__ gt3)
{
    __shared__ float as[256];
    int head = blockIdx.y, row = blockIdx.x, tid = threadIdx.x;
    const float* a  = (head == 1) ? xop : xcp;
    const float* b2 = (head == 0) ? xcp : xop;
    int fin = (head == 2) ? 256 : 128;
    const float* mrs = mrsH + head * 512;
    const float* W  = (head == 0) ? cW1 : (head == 1) ? oW1 : coW1;
    const float* bb = (head == 0) ? cb1 : (head == 1) ? ob1 : cob1;
    float* o = gt3 + (size_t)head * 512 * 128;
    for (int i = tid; i < fin; i += 128){
        float v = (i < 128) ? a[(size_t)row * 128 + i] : b2[(size_t)row * 128 + i - 128];
        as[i] = (v - mrs[i]) * mrs[fin + i] + 1e-4f;
    }
    __syncthreads();
    float s = 0.f;
    for (int k = 0; k < fin; ++k) s += as[k] * W[k * 128 + tid];
    s += bb[tid];
    if (head < 2) s = fmaxf(s, 0.f);
    else { s = s > 0.f ? s : expm1f(s); s = s > 0.f ? s : expm1f(s); }
    o[(size_t)row * 128 + tid] = s;
}
__global__ __launch_bounds__(1024) void k_gstats3b(const float* __restrict__ gt3,
        float* __restrict__ mrsH2, int n){
    __shared__ float red[2][1024];
    int head = blockIdx.x;
    const float* a = gt3 + (size_t)head * 512 * 128;
    float* mrs = mrsH2 + head * 256;
    int col = threadIdx.x & 127;
    int rw  = threadIdx.x >> 7;    // 8 rows/block-pass
    float s = 0.f, sq = 0.f;
    for (int r = rw; r < n; r += 8){
        float v = a[(size_t)r * 128 + col];
        s += v; sq += v * v;
    }
    red[0][threadIdx.x] = s; red[1][threadIdx.x] = sq;
    __syncthreads();
    if (threadIdx.x < 128u){
        float ts = 0.f, tq = 0.f;
        for (int w = 0; w < 8; ++w){ ts += red[0][w * 128 + col]; tq += red[1][w * 128 + col]; }
        float m = ts / n, var = tq / n - m * m;
        mrs[col] = m; mrs[128 + col] = rsqrtf(var + 1e-5f);
    }
}
__global__ __launch_bounds__(256) void k_hfinal3(const float* __restrict__ gt3,
        const float* __restrict__ mrsH2,
        const float* __restrict__ cW2, const float* __restrict__ cb2,
        const float* __restrict__ oW2, const float* __restrict__ ob2,
        const float* __restrict__ coW2, const float* __restrict__ cob2,
        float* __restrict__ out, int nrows)
{
    int head = blockIdx.y;
    int row = blockIdx.x * 4 + (threadIdx.x >> 6);
    if (row >= nrows) return;
    int lane = threadIdx.x & 63;
    const float* a   = gt3 + (size_t)head * 512 * 128;
    const float* mrs = mrsH2 + head * 256;
    const float* W = (head == 0) ? cW2 : (head == 1) ? oW2 : coW2;
    const float* b = (head == 0) ? cb2 : (head == 1) ? ob2 : cob2;
    float* o = out + (size_t)head * nrows * 10;
    float v0 = (a[(size_t)row * 128 + lane]      - mrs[lane])      * mrs[128 + lane]      + 1e-4f;
    float v1 = (a[(size_t)row * 128 + 64 + lane] - mrs[64 + lane]) * mrs[128 + 64 + lane] + 1e-4f;
    float logit[10];
    #pragma unroll
    for (int c = 0; c < 10; ++c){
        float p = v0 * W[lane * 10 + c] + v1 * W[(lane + 64) * 10 + c];
        for (int off = 32; off; off >>= 1) p += __shfl_xor(p, off);
        logit[c] = p + b[c];
    }
    float m = logit[0];
    #pragma unroll
    for (int c = 1; c < 10; ++c) m = fmaxf(m, logit[c]);
    float s = 0.f;
    #pragma unroll
    for (int c = 0; c < 10; ++c) s += expf(logit[c] - m);
    float lse = logf(s);
    if (lane < 10) o[row * 10 + lane] = logit[lane] - m - lse;
}

extern "C" void kernel_launch(void* const* d_in, const int* in_sizes, int n_in,
                              void* d_out, int out_size, void* d_ws, size_t ws_size,
                              hipStream_t stream)
{
    const int N = in_sizes[0] / 128;
    const int E = in_sizes[24];
    const int G = 512;
    const float* x    = (const float*)d_in[0];
    const float* Wf   = (const float*)d_in[1];
    const float* cWs  = (const float*)d_in[2];
    const float* cbs  = (const float*)d_in[3];
    const float* eW   = (const float*)d_in[4];
    const float* ebv  = (const float*)d_in[5];
    const float* naW  = (const float*)d_in[6];
    const float* nab  = (const float*)d_in[7];
    const float* xcW  = (const float*)d_in[8];
    const float* xcb  = (const float*)d_in[9];
    const float* xoW  = (const float*)d_in[10];
    const float* xob  = (const float*)d_in[11];
    const float* cW1  = (const float*)d_in[12];
    const float* cb1  = (const float*)d_in[13];
    const float* cW2  = (const float*)d_in[14];
    const float* cb2  = (const float*)d_in[15];
    const float* oW1  = (const float*)d_in[16];
    const float* ob1  = (const float*)d_in[17];
    const float* oW2  = (const float*)d_in[18];
    const float* ob2  = (const float*)d_in[19];
    const float* coW1 = (const float*)d_in[20];
    const float* cob1 = (const float*)d_in[21];
    const float* coW2 = (const float*)d_in[22];
    const float* cob2 = (const float*)d_in[23];
    const int* esrc  = (const int*)d_in[24];
    const int* edst  = (const int*)d_in[25];
    const int* batch = (const int*)d_in[26];
    float* out = (float*)d_out;

    size_t NH = (size_t)N * 128;
    bf16_t* B1  = (bf16_t*)d_ws;            // N*128
    bf16_t* B0  = B1 + NH;                  // N*128
    bf16_t* B0c = B0 + NH;                  // N*256 ([xc|xo])
    float* fbase = (float*)(B0c + 2 * NH);
    float* epreF = fbase;                   // 4N
    float* ntT   = epreF + 4 * (size_t)N;
    float* natt  = ntT + 2 * (size_t)N;
    float* mrsH  = natt + 2 * (size_t)N;    // 1536 (3 heads x 512)
    float* mrsH2 = mrsH + 1536;             // 768  (3 heads x 256)
    float* wU    = mrsH2 + 768;             // E (CSR order)
    float* wB0   = wU + E;                  // E
    float* wB1   = wB0 + E;                 // E
    float* gt3   = wB1 + E;                 // 3*G*128
    // zero zone (single memset)
    float* zz    = gt3 + (size_t)3 * G * 128;
    float* degU  = zz;                      // N
    float* degC0 = degU + N;                // N
    float* degC1 = degC0 + N;               // N
    float* stZ   = degC1 + N;               // 1536
    float* xcp   = stZ + 1536;              // G*128
    float* xop   = xcp + (size_t)G * 128;   // G*128
    int*   cntI  = (int*)(xop + (size_t)G * 128);   // N (zeroed: part of zz span)
    size_t zzBytes = ((size_t)(4 * N) + 1536 + 2 * (size_t)G * 128) * 4;
    int* ptrI   = cntI + N;                 // N+1
    int* fillI  = ptrI + N + 1;             // N
    int* srcC   = fillI + N;                // E
    int* dstC   = srcC + E;                 // E
    int* bsum   = dstC + E;                 // up to 64
    bf16_t* whiT = (bf16_t*)((((size_t)(bsum + 64)) + 15) & ~(size_t)15);  // 6*16384
    bf16_t* wloT = whiT + 6 * 16384;                                       // 6*16384
    float4* epre = (float4*)epreF;

    int gridE = (E + 255) / 256;
    int gridN = (N + 255) / 256;
    int gridW = (N + 3) / 4;
    int gridG = (N + 63) / 64;
    int nb    = (N + 1023) / 1024;
    int span  = (N + 8191) / 8192;
    int gridP = (N + span * 4 - 1) / (span * 4);

    hipMemsetAsync(zz, 0, zzBytes, stream);

    // ---- weight pre-split (independent of everything else) ----
    k_wsplit<<<dim3(16, 6), 256, 0, stream>>>(Wf, cWs, xcW, xoW, whiT, wloT);

    // ---- CSR by dst + degrees + CSR weights ----
    k_hist2<<<gridE, 256, 0, stream>>>(esrc, edst, cntI, degU, E);
    k_scanA<<<nb, 1024, 0, stream>>>(cntI, ptrI, bsum, N);
    k_scanB<<<1, 64, 0, stream>>>(bsum, ptrI + N, nb);
    k_scanC<<<nb, 1024, 0, stream>>>(ptrI, bsum, fillI, N);
    k_fill<<<gridE, 256, 0, stream>>>(esrc, edst, fillI, srcC, dstC, E);
    k_wU<<<gridE, 256, 0, stream>>>(srcC, degU, wU, E);

    // ---- h = relu(BN(x) @ W_feat) -> B1 (bf16) ----
    k_statsF<<<256, 256, 0, stream>>>(x, stZ, N);
    k_gemm<1, 0><<<gridG, 256, 0, stream>>>(x, nullptr, 0, stZ, whiT, wloT, B1, 128, 0, N);

    // ---- 3 x [BN -> GCNConv -> relu] ----
    for (int i = 0; i < 3; ++i){
        float* st = stZ + 256 * (i + 1);
        k_statsB<<<256, 256, 0, stream>>>(B1, st, N);
        k_gemm<0, 1><<<gridG, 256, 0, stream>>>(B1, nullptr, 0, st,
                whiT + (size_t)(i + 1) * 16384, wloT + (size_t)(i + 1) * 16384,
                B0, 128, 0, N);
        k_gather0<<<gridW, 256, 0, stream>>>(ptrI, srcC, wU, degU, B0, cbs + i * 128, B1, N);
    }

    // ---- attention ----
    k_prep<<<gridW, 256, 0, stream>>>(B1, eW, naW, epre, ntT, N);
    k_eatt2<<<gridE, 256, 0, stream>>>(srcC, dstC, epre, ebv, wB0, wB1,
                                       degC0, degC1, E);
    k_natt<<<gridN, 256, 0, stream>>>(ptrI, srcC, wU, degU, ntT, nab, natt, N);

    // ---- branch stats + CSR branch weights ----
    k_stats2<<<256, 256, 0, stream>>>(B1, natt, stZ + 1024, N);
    k_wB<<<gridE, 256, 0, stream>>>(srcC, degC0, degC1, wB0, wB1, E);

    // ---- xc / xo branch GEMMs into combined B0c, then ONE gather ----
    k_gemm<0, 1><<<gridG, 256, 0, stream>>>(B1, natt, 0, stZ + 1024,
            whiT + (size_t)4 * 16384, wloT + (size_t)4 * 16384, B0c, 256, 0, N);
    k_gemm<0, 1><<<gridG, 256, 0, stream>>>(B1, natt, 1, stZ + 1024 + 256,
            whiT + (size_t)5 * 16384, wloT + (size_t)5 * 16384, B0c, 256, 128, N);
    k_gatherP<<<gridP, 256, 0, stream>>>(ptrI, srcC, wB0, wB1, degC0, degC1, B0c,
                                         xcb, xob, batch, xcp, xop, N, span);

    // ---- heads: 3 heads fused per stage ----
    k_gstats3<<<3, 1024, 0, stream>>>(xcp, xop, mrsH, G);
    k_hgemm3<<<dim3(G, 3), 128, 0, stream>>>(xcp, xop, mrsH, cW1, cb1, oW1, ob1,
                                             coW1, cob1, gt3);
    k_gstats3b<<<3, 1024, 0, stream>>>(gt3, mrsH2, G);
    k_hfinal3<<<dim3((G + 3) / 4, 3), 256, 0, stream>>>(gt3, mrsH2, cW2, cb2, oW2, ob2,
                                                        coW2, cob2, out, G);
}

// Round 4
// 766.023 us; speedup vs baseline: 1.3060x; 1.0052x over previous
//
#include <hip/hip_runtime.h>

// CausalGCN forward on MI355X. fp32 in/out; internal N x 128 tensors bf16.
// R11: gatherP branch-split (uint32 rows, 2KB-in-flight regime, 2x waves),
//      wU folded into k_fill. Theory: random-gather waves saturate at ~2KB
//      outstanding row data; 512B-row x8 unroll (4KB) measured slower.

typedef unsigned short bf16_t;
typedef unsigned int   uint32;
typedef __attribute__((ext_vector_type(8))) short   bf16x8;
typedef __attribute__((ext_vector_type(4))) float   f32x4;

__device__ __forceinline__ float b2f(bf16_t v){ return __uint_as_float(((uint32)v) << 16); }
__device__ __forceinline__ bf16_t f2b(float f){
    uint32 u = __float_as_uint(f);
    return (bf16_t)((u + 0x7fffu + ((u >> 16) & 1u)) >> 16);   // RNE
}
__device__ __forceinline__ uint32 pack2(float lo, float hi){
    return (uint32)f2b(lo) | ((uint32)f2b(hi) << 16);
}
__device__ __forceinline__ float lo16(uint32 u){ return __uint_as_float(u << 16); }
__device__ __forceinline__ float hi16(uint32 u){ return __uint_as_float(u & 0xffff0000u); }

// ---------- BN stats (raw sum/sumsq; mean/rstd derived in consumers) ----------
__global__ void k_statsF(const float* __restrict__ a, float* __restrict__ st, int n){
    int tid = threadIdx.x;
    int feat = tid & 127;
    int row = blockIdx.x * 2 + (tid >> 7);
    float s = 0.f, sq = 0.f;
    for (; row < n; row += gridDim.x * 2){
        float v = a[(size_t)row * 128 + feat];
        s += v; sq += v * v;
    }
    atomicAdd(&st[feat], s);
    atomicAdd(&st[128 + feat], sq);
}
__global__ void k_statsB(const bf16_t* __restrict__ a, float* __restrict__ st, int n){
    int tid = threadIdx.x;
    int feat = tid & 127;
    int row = blockIdx.x * 2 + (tid >> 7);
    float s = 0.f, sq = 0.f;
    for (; row < n; row += gridDim.x * 2){
        float v = b2f(a[(size_t)row * 128 + feat]);
        s += v; sq += v * v;
    }
    atomicAdd(&st[feat], s);
    atomicAdd(&st[128 + feat], sq);
}
__global__ void k_stats2(const bf16_t* __restrict__ a, const float* __restrict__ natt,
                         float* __restrict__ st, int n){
    int tid = threadIdx.x;
    int feat = tid & 127;
    int row = blockIdx.x * 2 + (tid >> 7);
    float s0 = 0.f, q0 = 0.f, s1 = 0.f, q1 = 0.f;
    for (; row < n; row += gridDim.x * 2){
        float v = b2f(a[(size_t)row * 128 + feat]);
        float2 w = *(const float2*)&natt[(size_t)row * 2];
        float v0 = v * w.x, v1 = v * w.y;
        s0 += v0; q0 += v0 * v0; s1 += v1; q1 += v1 * v1;
    }
    atomicAdd(&st[feat], s0);       atomicAdd(&st[128 + feat], q0);
    atomicAdd(&st[256 + feat], s1); atomicAdd(&st[384 + feat], q1);
}

// ---------- W pre-split: fp32 [k][n] -> bf16 hi/lo transposed [n][k], 6 matrices ----------
__global__ void k_wsplit(const float* __restrict__ Wf, const float* __restrict__ cWs,
        const float* __restrict__ xcW, const float* __restrict__ xoW,
        bf16_t* __restrict__ whiT, bf16_t* __restrict__ wloT)
{
    int mat = blockIdx.y;
    const float* src = (mat == 0) ? Wf : (mat <= 3) ? cWs + (size_t)(mat - 1) * 16384
                      : (mat == 4) ? xcW : xoW;
    int i = (blockIdx.x * 256 + threadIdx.x) * 4;
    int nrow = i >> 7, k0 = i & 127;
    size_t off = (size_t)mat * 16384 + (size_t)nrow * 128 + k0;
    #pragma unroll
    for (int j = 0; j < 4; ++j){
        float w = src[(size_t)(k0 + j) * 128 + nrow];
        bf16_t h = f2b(w);
        whiT[off + j] = h;
        wloT[off + j] = f2b(w - b2f(h));
    }
}

// ---------- MFMA GEMM: C[n, ccol0..+128 of ldc] = act( BN(scale*A) @ W ) ----------
// W pre-split bf16 hi+lo (two MFMAs) -> ~fp32 weight precision. BN mean/rstd derived
// from raw sums per-thread (each staging thread owns 8 fixed columns).
// LDS: As 64x136 bf16 + Whi/Wlo 128x72 bf16 = 54.3KB.
template<int ACT, int INBF>  // ACT: 1=relu ; INBF: input bf16?
__global__ __launch_bounds__(256, 3) void k_gemm(const void* __restrict__ Av,
        const float* __restrict__ scale, int sch,
        const float* __restrict__ st, const bf16_t* __restrict__ WhiT,
        const bf16_t* __restrict__ WloT,
        bf16_t* __restrict__ C, int ldc, int ccol0, int n)
{
    __shared__ bf16_t As[64 * 136];
    __shared__ bf16_t Whi[128 * 72];
    __shared__ bf16_t Wlo[128 * 72];
    int tid = threadIdx.x;
    int wid = tid >> 6, lane = tid & 63;
    int row0 = blockIdx.x * 64;
    int m0 = wid * 16;
    int q8 = (lane >> 4) * 8, l15 = lane & 15;

    // per-thread BN params for its 8 fixed columns
    int c8t = (tid & 15) * 8;
    float sM[8], sR[8];
    #pragma unroll
    for (int j = 0; j < 8; ++j){
        float m = st[c8t + j] / n;
        float var = st[128 + c8t + j] / n - m * m;
        sM[j] = m; sR[j] = rsqrtf(var + 1e-5f);
    }

    // stage A (BN applied, bf16) : 64 rows x 128 cols
    for (int i = tid; i < 64 * 16; i += 256){
        int r = i >> 4, c8 = (i & 15) * 8;   // c8 == c8t for all iterations
        int gr = row0 + r;
        float v[8];
        if (gr < n){
            float sc = scale ? scale[(size_t)gr * 2 + sch] : 1.f;
            if (INBF){
                const bf16_t* Ab = (const bf16_t*)Av;
                ushort4 qa = *(const ushort4*)&Ab[(size_t)gr * 128 + c8];
                ushort4 qb = *(const ushort4*)&Ab[(size_t)gr * 128 + c8 + 4];
                v[0]=b2f(qa.x); v[1]=b2f(qa.y); v[2]=b2f(qa.z); v[3]=b2f(qa.w);
                v[4]=b2f(qb.x); v[5]=b2f(qb.y); v[6]=b2f(qb.z); v[7]=b2f(qb.w);
            } else {
                const float* Af = (const float*)Av;
                float4 fa = *(const float4*)&Af[(size_t)gr * 128 + c8];
                float4 fb = *(const float4*)&Af[(size_t)gr * 128 + c8 + 4];
                v[0]=fa.x; v[1]=fa.y; v[2]=fa.z; v[3]=fa.w;
                v[4]=fb.x; v[5]=fb.y; v[6]=fb.z; v[7]=fb.w;
            }
            #pragma unroll
            for (int j = 0; j < 8; ++j)
                v[j] = (v[j] * sc - sM[j]) * sR[j] + 1e-4f;
        } else {
            #pragma unroll
            for (int j = 0; j < 8; ++j) v[j] = 0.f;
        }
        #pragma unroll
        for (int j = 0; j < 8; ++j) As[r * 136 + c8 + j] = f2b(v[j]);
    }

    f32x4 acc[8];
    #pragma unroll
    for (int t = 0; t < 8; ++t) acc[t] = (f32x4){0.f, 0.f, 0.f, 0.f};

    for (int kc = 0; kc < 128; kc += 64){
        __syncthreads();
        // stage W chunk (pre-split, pre-transposed): pure uint4 copies
        for (int i = tid; i < 128 * 8; i += 256){
            int nrow = i >> 3, k8 = (i & 7) * 8;
            *(uint4*)&Whi[nrow * 72 + k8] = *(const uint4*)&WhiT[(size_t)nrow * 128 + kc + k8];
            *(uint4*)&Wlo[nrow * 72 + k8] = *(const uint4*)&WloT[(size_t)nrow * 128 + kc + k8];
        }
        __syncthreads();
        #pragma unroll
        for (int kbl = 0; kbl < 2; ++kbl){
            bf16x8 a = *(const bf16x8*)&As[(m0 + l15) * 136 + kc + kbl * 32 + q8];
            #pragma unroll
            for (int nt = 0; nt < 8; ++nt){
                bf16x8 bh = *(const bf16x8*)&Whi[(nt * 16 + l15) * 72 + kbl * 32 + q8];
                acc[nt] = __builtin_amdgcn_mfma_f32_16x16x32_bf16(a, bh, acc[nt], 0, 0, 0);
                bf16x8 bl = *(const bf16x8*)&Wlo[(nt * 16 + l15) * 72 + kbl * 32 + q8];
                acc[nt] = __builtin_amdgcn_mfma_f32_16x16x32_bf16(a, bl, acc[nt], 0, 0, 0);
            }
        }
    }

    // epilogue: acc -> LDS (bf16) -> coalesced store
    __syncthreads();
    #pragma unroll
    for (int nt = 0; nt < 8; ++nt){
        #pragma unroll
        for (int r = 0; r < 4; ++r){
            float v = acc[nt][r];
            if (ACT == 1) v = fmaxf(v, 0.f);
            As[(m0 + (lane >> 4) * 4 + r) * 136 + nt * 16 + l15] = f2b(v);
        }
    }
    __syncthreads();
    for (int i = tid; i < 64 * 16; i += 256){
        int r = i >> 4, c8 = (i & 15) * 8;
        int gr = row0 + r;
        if (gr < n)
            *(uint4*)&C[(size_t)gr * ldc + ccol0 + c8] = *(const uint4*)&As[r * 136 + c8];
    }
}

// ---------- CSR build (by dst) ----------
__global__ void k_hist2(const int* __restrict__ src, const int* __restrict__ dst,
                        int* __restrict__ cnt, float* __restrict__ degU, int e){
    int i = blockIdx.x * 256 + threadIdx.x;
    if (i < e){
        atomicAdd(&cnt[dst[i]], 1);
        atomicAdd(&degU[src[i]], 1.0f);
    }
}
__global__ __launch_bounds__(1024) void k_scanA(const int* __restrict__ cnt,
        int* __restrict__ ptr, int* __restrict__ bsum, int n){
    __shared__ int wsum[16];
    int t = threadIdx.x, lane = t & 63, wid = t >> 6;
    int i = blockIdx.x * 1024 + t;
    int v = (i < n) ? cnt[i] : 0;
    int s = v;
    for (int off = 1; off < 64; off <<= 1){
        int u = __shfl_up(s, off);
        if (lane >= off) s += u;
    }
    if (lane == 63) wsum[wid] = s;
    __syncthreads();
    if (wid == 0 && lane < 16){
        int ws = wsum[lane];
        for (int off = 1; off < 16; off <<= 1){
            int u = __shfl_up(ws, off);
            if (lane >= off) ws += u;
        }
        wsum[lane] = ws;
    }
    __syncthreads();
    int woff = wid ? wsum[wid - 1] : 0;
    if (i < n) ptr[i] = woff + s - v;
    if (t == 1023) bsum[blockIdx.x] = woff + s;
}
__global__ void k_scanB(int* __restrict__ bsum, int* __restrict__ ptrN, int nb){
    int lane = threadIdx.x;       // 64 threads
    int carry = 0;
    for (int base = 0; base < nb; base += 64){
        int i = base + lane;
        int v = (i < nb) ? bsum[i] : 0;
        int s = v;
        for (int off = 1; off < 64; off <<= 1){
            int u = __shfl_up(s, off);
            if (lane >= off) s += u;
        }
        if (i < nb) bsum[i] = carry + s - v;
        carry += __shfl(s, 63);
    }
    if (lane == 0) *ptrN = carry;
}
__global__ __launch_bounds__(1024) void k_scanC(int* __restrict__ ptr,
        const int* __restrict__ bsum, int* __restrict__ fill, int n){
    int i = blockIdx.x * 1024 + threadIdx.x;
    if (i < n){
        int p = ptr[i] + bsum[blockIdx.x];
        ptr[i] = p; fill[i] = p;
    }
}
// fill CSR + wU = rsqrt(degU[src]+1) in one pass (wU folded in, R11)
__global__ void k_fill(const int* __restrict__ src, const int* __restrict__ dst,
                       int* __restrict__ fill, int* __restrict__ srcC,
                       int* __restrict__ dstC, const float* __restrict__ degU,
                       float* __restrict__ wU, int e){
    int i = blockIdx.x * 256 + threadIdx.x;
    if (i < e){
        int s = src[i];
        int d = dst[i];
        int slot = atomicAdd(&fill[d], 1);
        srcC[slot] = s;
        dstC[slot] = d;
        wU[slot] = rsqrtf(degU[s] + 1.0f);
    }
}

// ---------- branch edge weights (rsqrt fused) ----------
__global__ void k_wB(const int* __restrict__ srcC, const float* __restrict__ degC0,
                     const float* __restrict__ degC1, float* __restrict__ w0,
                     float* __restrict__ w1, int e){
    int i = blockIdx.x * 256 + threadIdx.x;
    if (i < e){
        int s = srcC[i];
        w0[i] *= rsqrtf(degC0[s] + 1.0f);
        w1[i] *= rsqrtf(degC1[s] + 1.0f);
    }
}

// ---------- conv propagate: bf16 in/out, one wave/node, unroll 8 ----------
__global__ __launch_bounds__(256) void k_gather0(const int* __restrict__ ptr,
        const int* __restrict__ srcC, const float* __restrict__ wE,
        const float* __restrict__ degU, const bf16_t* __restrict__ t,
        const float* __restrict__ bias, bf16_t* __restrict__ outB, int n)
{
    int node = blockIdx.x * 4 + (threadIdx.x >> 6);
    if (node >= n) return;
    int lane = threadIdx.x & 63;
    const uint32* T = (const uint32*)t;
    float dd = rsqrtf(degU[node] + 1.0f);
    uint32 sv = T[(size_t)node * 64 + lane];
    float a0 = 0.f, a1 = 0.f;
    int beg = ptr[node], end = ptr[node + 1];
    int k = beg;
    for (; k + 8 <= end; k += 8){
        int s0 = srcC[k],     s1 = srcC[k + 1], s2 = srcC[k + 2], s3 = srcC[k + 3];
        int s4 = srcC[k + 4], s5 = srcC[k + 5], s6 = srcC[k + 6], s7 = srcC[k + 7];
        float w0 = wE[k],     w1 = wE[k + 1], w2 = wE[k + 2], w3 = wE[k + 3];
        float w4 = wE[k + 4], w5 = wE[k + 5], w6 = wE[k + 6], w7 = wE[k + 7];
        uint32 v0 = T[(size_t)s0 * 64 + lane];
        uint32 v1 = T[(size_t)s1 * 64 + lane];
        uint32 v2 = T[(size_t)s2 * 64 + lane];
        uint32 v3 = T[(size_t)s3 * 64 + lane];
        uint32 v4 = T[(size_t)s4 * 64 + lane];
        uint32 v5 = T[(size_t)s5 * 64 + lane];
        uint32 v6 = T[(size_t)s6 * 64 + lane];
        uint32 v7 = T[(size_t)s7 * 64 + lane];
        a0 += w0 * lo16(v0) + w1 * lo16(v1) + w2 * lo16(v2) + w3 * lo16(v3);
        a1 += w0 * hi16(v0) + w1 * hi16(v1) + w2 * hi16(v2) + w3 * hi16(v3);
        a0 += w4 * lo16(v4) + w5 * lo16(v5) + w6 * lo16(v6) + w7 * lo16(v7);
        a1 += w4 * hi16(v4) + w5 * hi16(v5) + w6 * hi16(v6) + w7 * hi16(v7);
    }
    for (; k + 4 <= end; k += 4){
        int s0 = srcC[k], s1 = srcC[k + 1], s2 = srcC[k + 2], s3 = srcC[k + 3];
        float w0 = wE[k], w1 = wE[k + 1], w2 = wE[k + 2], w3 = wE[k + 3];
        uint32 v0 = T[(size_t)s0 * 64 + lane];
        uint32 v1 = T[(size_t)s1 * 64 + lane];
        uint32 v2 = T[(size_t)s2 * 64 + lane];
        uint32 v3 = T[(size_t)s3 * 64 + lane];
        a0 += w0 * lo16(v0) + w1 * lo16(v1) + w2 * lo16(v2) + w3 * lo16(v3);
        a1 += w0 * hi16(v0) + w1 * hi16(v1) + w2 * hi16(v2) + w3 * hi16(v3);
    }
    for (; k < end; ++k){
        int s = srcC[k];
        float w = wE[k];
        uint32 v = T[(size_t)s * 64 + lane];
        a0 += w * lo16(v); a1 += w * hi16(v);
    }
    a0 = fmaxf(dd * (a0 + dd * lo16(sv)) + bias[2 * lane],     0.f);
    a1 = fmaxf(dd * (a1 + dd * hi16(sv)) + bias[2 * lane + 1], 0.f);
    ((uint32*)outB)[(size_t)node * 64 + lane] = pack2(a0, a1);
}

// ---------- branch propagate, branch-split: one wave = one branch of a node span ----
// Each lane reads uint32 (2 bf16 cols) -> 256B rows; unroll 8 = 2KB in flight.
__global__ __launch_bounds__(256) void k_gatherP2(const int* __restrict__ ptr,
        const int* __restrict__ srcC, const float* __restrict__ w0E,
        const float* __restrict__ w1E, const float* __restrict__ degC0,
        const float* __restrict__ degC1, const bf16_t* __restrict__ t,
        const float* __restrict__ biasC, const float* __restrict__ biasO,
        const int* __restrict__ batch, float* __restrict__ pool0,
        float* __restrict__ pool1, int n, int span)
{
    int br   = blockIdx.x & 1;
    int wave = (blockIdx.x >> 1) * 4 + (threadIdx.x >> 6);
    int lane = threadIdx.x & 63;
    int nbeg = wave * span;
    if (nbeg >= n) return;
    int nend = min(n, nbeg + span);
    const float* wE   = br ? w1E : w0E;
    const float* deg  = br ? degC1 : degC0;
    const float* bias = br ? biasO : biasC;
    float* pool       = br ? pool1 : pool0;
    float b0 = bias[2 * lane], b1 = bias[2 * lane + 1];
    const uint32* T = (const uint32*)t;       // B0c row = 128 uint32
    int rowoff = (br ? 64 : 0) + lane;
    int curG = -1;
    float p0 = 0.f, p1 = 0.f;
    for (int node = nbeg; node < nend; ++node){
        float dd = rsqrtf(deg[node] + 1.0f);
        uint32 sv = T[(size_t)node * 128 + rowoff];
        float a0 = 0.f, a1 = 0.f;
        int k = ptr[node], end = ptr[node + 1];
        for (; k + 8 <= end; k += 8){
            int s0 = srcC[k],     s1 = srcC[k + 1], s2 = srcC[k + 2], s3 = srcC[k + 3];
            int s4 = srcC[k + 4], s5 = srcC[k + 5], s6 = srcC[k + 6], s7 = srcC[k + 7];
            float w0 = wE[k],     w1 = wE[k + 1], w2 = wE[k + 2], w3 = wE[k + 3];
            float w4 = wE[k + 4], w5 = wE[k + 5], w6 = wE[k + 6], w7 = wE[k + 7];
            uint32 v0 = T[(size_t)s0 * 128 + rowoff];
            uint32 v1 = T[(size_t)s1 * 128 + rowoff];
            uint32 v2 = T[(size_t)s2 * 128 + rowoff];
            uint32 v3 = T[(size_t)s3 * 128 + rowoff];
            uint32 v4 = T[(size_t)s4 * 128 + rowoff];
            uint32 v5 = T[(size_t)s5 * 128 + rowoff];
            uint32 v6 = T[(size_t)s6 * 128 + rowoff];
            uint32 v7 = T[(size_t)s7 * 128 + rowoff];
            a0 += w0 * lo16(v0) + w1 * lo16(v1) + w2 * lo16(v2) + w3 * lo16(v3);
            a1 += w0 * hi16(v0) + w1 * hi16(v1) + w2 * hi16(v2) + w3 * hi16(v3);
            a0 += w4 * lo16(v4) + w5 * lo16(v5) + w6 * lo16(v6) + w7 * lo16(v7);
            a1 += w4 * hi16(v4) + w5 * hi16(v5) + w6 * hi16(v6) + w7 * hi16(v7);
        }
        for (; k + 4 <= end; k += 4){
            int s0 = srcC[k], s1 = srcC[k + 1], s2 = srcC[k + 2], s3 = srcC[k + 3];
            float w0 = wE[k], w1 = wE[k + 1], w2 = wE[k + 2], w3 = wE[k + 3];
            uint32 v0 = T[(size_t)s0 * 128 + rowoff];
            uint32 v1 = T[(size_t)s1 * 128 + rowoff];
            uint32 v2 = T[(size_t)s2 * 128 + rowoff];
            uint32 v3 = T[(size_t)s3 * 128 + rowoff];
            a0 += w0 * lo16(v0) + w1 * lo16(v1) + w2 * lo16(v2) + w3 * lo16(v3);
            a1 += w0 * hi16(v0) + w1 * hi16(v1) + w2 * hi16(v2) + w3 * hi16(v3);
        }
        for (; k < end; ++k){
            int s = srcC[k];
            float w = wE[k];
            uint32 v = T[(size_t)s * 128 + rowoff];
            a0 += w * lo16(v); a1 += w * hi16(v);
        }
        a0 = dd * (a0 + dd * lo16(sv)) + b0;
        a1 = dd * (a1 + dd * hi16(sv)) + b1;
        a0 = a0 > 0.f ? a0 : expm1f(a0);
        a1 = a1 > 0.f ? a1 : expm1f(a1);
        int g = batch[node];
        if (g != curG){
            if (curG >= 0){
                float* p = pool + (size_t)curG * 128 + 2 * lane;
                atomicAdd(&p[0], p0); atomicAdd(&p[1], p1);
            }
            curG = g; p0 = a0; p1 = a1;
        } else {
            p0 += a0; p1 += a1;
        }
    }
    if (curG >= 0){
        float* p = pool + (size_t)curG * 128 + 2 * lane;
        atomicAdd(&p[0], p0); atomicAdd(&p[1], p1);
    }
}

// ---------- attention ----------
__global__ __launch_bounds__(256) void k_prep(const bf16_t* __restrict__ h,
        const float* __restrict__ eW, const float* __restrict__ naW,
        float4* __restrict__ epre, float* __restrict__ ntT, int n)
{
    int i = blockIdx.x * 4 + (threadIdx.x >> 6);
    if (i >= n) return;
    int lane = threadIdx.x & 63;
    float h0 = b2f(h[(size_t)i * 128 + lane]), h1 = b2f(h[(size_t)i * 128 + 64 + lane]);
    float s0 = h0 * eW[lane * 2]             + h1 * eW[(64 + lane) * 2];
    float s1 = h0 * eW[lane * 2 + 1]         + h1 * eW[(64 + lane) * 2 + 1];
    float d0 = h0 * eW[(128 + lane) * 2]     + h1 * eW[(192 + lane) * 2];
    float d1 = h0 * eW[(128 + lane) * 2 + 1] + h1 * eW[(192 + lane) * 2 + 1];
    float n0 = h0 * naW[lane * 2]            + h1 * naW[(64 + lane) * 2];
    float n1 = h0 * naW[lane * 2 + 1]        + h1 * naW[(64 + lane) * 2 + 1];
    for (int off = 32; off; off >>= 1){
        s0 += __shfl_xor(s0, off); s1 += __shfl_xor(s1, off);
        d0 += __shfl_xor(d0, off); d1 += __shfl_xor(d1, off);
        n0 += __shfl_xor(n0, off); n1 += __shfl_xor(n1, off);
    }
    if (lane == 0){
        epre[i] = make_float4(s0, s1, d0, d1);
        ntT[2 * i] = n0; ntT[2 * i + 1] = n1;
    }
}
// edge softmax in CSR order: coalesced reads (srcC,dstC) + coalesced writes (wB0,wB1)
__global__ void k_eatt2(const int* __restrict__ srcC, const int* __restrict__ dstC,
        const float4* __restrict__ epre, const float* __restrict__ eb,
        float* __restrict__ wB0, float* __restrict__ wB1,
        float* __restrict__ d0, float* __restrict__ d1, int e){
    int i = blockIdx.x * 256 + threadIdx.x;
    if (i >= e) return;
    int s = srcC[i];
    float4 ps = epre[s], pd = epre[dstC[i]];
    float l0 = ps.x + pd.z + eb[0], l1 = ps.y + pd.w + eb[1];
    float m = fmaxf(l0, l1);
    float e0 = expf(l0 - m), e1 = expf(l1 - m);
    float inv = 1.f / (e0 + e1);
    e0 *= inv; e1 *= inv;
    wB0[i] = e0; wB1[i] = e1;
    atomicAdd(&d0[s], e0); atomicAdd(&d1[s], e1);
}
__global__ void k_natt(const int* __restrict__ ptr, const int* __restrict__ srcC,
        const float* __restrict__ wU, const float* __restrict__ degU,
        const float* __restrict__ ntT, const float* __restrict__ nab,
        float* __restrict__ natt, int n){
    int i = blockIdx.x * 256 + threadIdx.x;
    if (i >= n) return;
    float dd = rsqrtf(degU[i] + 1.0f);
    float z0 = 0.f, z1 = 0.f;
    int end = ptr[i + 1];
    for (int k = ptr[i]; k < end; ++k){
        int s = srcC[k];
        float w = wU[k];
        z0 += w * ntT[2 * s]; z1 += w * ntT[2 * s + 1];
    }
    z0 = dd * (z0 + dd * ntT[2 * i])     + nab[0];
    z1 = dd * (z1 + dd * ntT[2 * i + 1]) + nab[1];
    float m = fmaxf(z0, z1);
    float e0 = expf(z0 - m), e1 = expf(z1 - m);
    float inv = 1.f / (e0 + e1);
    natt[2 * i] = e0 * inv; natt[2 * i + 1] = e1 * inv;
}

// ---------- heads (G=512, fp32), 3 heads fused per stage ----------
__global__ __launch_bounds__(1024) void k_gstats3(const float* __restrict__ xcp,
        const float* __restrict__ xop, float* __restrict__ mrsH, int n){
    __shared__ float red[2][1024];
    int head = blockIdx.x;
    const float* a = (head == 1) ? xop : xcp;
    const float* b = (head == 0) ? xcp : xop;
    int f = (head == 2) ? 256 : 128;
    float* mrs = mrsH + head * 512;
    int col = threadIdx.x & (f - 1);
    int rpb = 1024 / f;
    int rw  = threadIdx.x / f;
    float s = 0.f, sq = 0.f;
    for (int r = rw; r < n; r += rpb){
        float v = (col < 128) ? a[(size_t)r * 128 + col] : b[(size_t)r * 128 + col - 128];
        s += v; sq += v * v;
    }
    red[0][threadIdx.x] = s; red[1][threadIdx.x] = sq;
    __syncthreads();
    if (threadIdx.x < (unsigned)f){
        float ts = 0.f, tq = 0.f;
        for (int w = 0; w < rpb; ++w){ ts += red[0][w * f + col]; tq += red[1][w * f + col]; }
        float m = ts / n, var = tq / n - m * m;
        mrs[col] = m; mrs[f + col] = rsqrtf(var + 1e-5f);
    }
}
__global__ __launch_bounds__(128) void k_hgemm3(const float* __restrict__ xcp,
        const float* __restrict__ xop, const float* __restrict__ mrsH,
        const float* __restrict__ cW1, const float* __restrict__ cb1,
        const float* __restrict__ oW1, const float* __restrict__ ob1,
        const float* __restrict__ coW1, const float* __restrict__ cob1,
        float* __restrict__ gt3)
{
    __shared__ float as[256];
    int head = blockIdx.y, row = blockIdx.x, tid = threadIdx.x;
    const float* a  = (head == 1) ? xop : xcp;
    const float* b2 = (head == 0) ? xcp : xop;
    int fin = (head == 2) ? 256 : 128;
    const float* mrs = mrsH + head * 512;
    const float* W  = (head == 0) ? cW1 : (head == 1) ? oW1 : coW1;
    const float* bb = (head == 0) ? cb1 : (head == 1) ? ob1 : cob1;
    float* o = gt3 + (size_t)head * 512 * 128;
    for (int i = tid; i < fin; i += 128){
        float v = (i < 128) ? a[(size_t)row * 128 + i] : b2[(size_t)row * 128 + i - 128];
        as[i] = (v - mrs[i]) * mrs[fin + i] + 1e-4f;
    }
    __syncthreads();
    float s = 0.f;
    for (int k = 0; k < fin; ++k) s += as[k] * W[k * 128 + tid];
    s += bb[tid];
    if (head < 2) s = fmaxf(s, 0.f);
    else { s = s > 0.f ? s : expm1f(s); s = s > 0.f ? s : expm1f(s); }
    o[(size_t)row * 128 + tid] = s;
}
__global__ __launch_bounds__(1024) void k_gstats3b(const float* __restrict__ gt3,
        float* __restrict__ mrsH2, int n){
    __shared__ float red[2][1024];
    int head = blockIdx.x;
    const float* a = gt3 + (size_t)head * 512 * 128;
    float* mrs = mrsH2 + head * 256;
    int col = threadIdx.x & 127;
    int rw  = threadIdx.x >> 7;    // 8 rows/block-pass
    float s = 0.f, sq = 0.f;
    for (int r = rw; r < n; r += 8){
        float v = a[(size_t)r * 128 + col];
        s += v; sq += v * v;
    }
    red[0][threadIdx.x] = s; red[1][threadIdx.x] = sq;
    __syncthreads();
    if (threadIdx.x < 128u){
        float ts = 0.f, tq = 0.f;
        for (int w = 0; w < 8; ++w){ ts += red[0][w * 128 + col]; tq += red[1][w * 128 + col]; }
        float m = ts / n, var = tq / n - m * m;
        mrs[col] = m; mrs[128 + col] = rsqrtf(var + 1e-5f);
    }
}
__global__ __launch_bounds__(256) void k_hfinal3(const float* __restrict__ gt3,
        const float* __restrict__ mrsH2,
        const float* __restrict__ cW2, const float* __restrict__ cb2,
        const float* __restrict__ oW2, const float* __restrict__ ob2,
        const float* __restrict__ coW2, const float* __restrict__ cob2,
        float* __restrict__ out, int nrows)
{
    int head = blockIdx.y;
    int row = blockIdx.x * 4 + (threadIdx.x >> 6);
    if (row >= nrows) return;
    int lane = threadIdx.x & 63;
    const float* a   = gt3 + (size_t)head * 512 * 128;
    const float* mrs = mrsH2 + head * 256;
    const float* W = (head == 0) ? cW2 : (head == 1) ? oW2 : coW2;
    const float* b = (head == 0) ? cb2 : (head == 1) ? ob2 : cob2;
    float* o = out + (size_t)head * nrows * 10;
    float v0 = (a[(size_t)row * 128 + lane]      - mrs[lane])      * mrs[128 + lane]      + 1e-4f;
    float v1 = (a[(size_t)row * 128 + 64 + lane] - mrs[64 + lane]) * mrs[128 + 64 + lane] + 1e-4f;
    float logit[10];
    #pragma unroll
    for (int c = 0; c < 10; ++c){
        float p = v0 * W[lane * 10 + c] + v1 * W[(lane + 64) * 10 + c];
        for (int off = 32; off; off >>= 1) p += __shfl_xor(p, off);
        logit[c] = p + b[c];
    }
    float m = logit[0];
    #pragma unroll
    for (int c = 1; c < 10; ++c) m = fmaxf(m, logit[c]);
    float s = 0.f;
    #pragma unroll
    for (int c = 0; c < 10; ++c) s += expf(logit[c] - m);
    float lse = logf(s);
    if (lane < 10) o[row * 10 + lane] = logit[lane] - m - lse;
}

extern "C" void kernel_launch(void* const* d_in, const int* in_sizes, int n_in,
                              void* d_out, int out_size, void* d_ws, size_t ws_size,
                              hipStream_t stream)
{
    const int N = in_sizes[0] / 128;
    const int E = in_sizes[24];
    const int G = 512;
    const float* x    = (const float*)d_in[0];
    const float* Wf   = (const float*)d_in[1];
    const float* cWs  = (const float*)d_in[2];
    const float* cbs  = (const float*)d_in[3];
    const float* eW   = (const float*)d_in[4];
    const float* ebv  = (const float*)d_in[5];
    const float* naW  = (const float*)d_in[6];
    const float* nab  = (const float*)d_in[7];
    const float* xcW  = (const float*)d_in[8];
    const float* xcb  = (const float*)d_in[9];
    const float* xoW  = (const float*)d_in[10];
    const float* xob  = (const float*)d_in[11];
    const float* cW1  = (const float*)d_in[12];
    const float* cb1  = (const float*)d_in[13];
    const float* cW2  = (const float*)d_in[14];
    const float* cb2  = (const float*)d_in[15];
    const float* oW1  = (const float*)d_in[16];
    const float* ob1  = (const float*)d_in[17];
    const float* oW2  = (const float*)d_in[18];
    const float* ob2  = (const float*)d_in[19];
    const float* coW1 = (const float*)d_in[20];
    const float* cob1 = (const float*)d_in[21];
    const float* coW2 = (const float*)d_in[22];
    const float* cob2 = (const float*)d_in[23];
    const int* esrc  = (const int*)d_in[24];
    const int* edst  = (const int*)d_in[25];
    const int* batch = (const int*)d_in[26];
    float* out = (float*)d_out;

    size_t NH = (size_t)N * 128;
    bf16_t* B1  = (bf16_t*)d_ws;            // N*128
    bf16_t* B0  = B1 + NH;                  // N*128
    bf16_t* B0c = B0 + NH;                  // N*256 ([xc|xo])
    float* fbase = (float*)(B0c + 2 * NH);
    float* epreF = fbase;                   // 4N
    float* ntT   = epreF + 4 * (size_t)N;
    float* natt  = ntT + 2 * (size_t)N;
    float* mrsH  = natt + 2 * (size_t)N;    // 1536 (3 heads x 512)
    float* mrsH2 = mrsH + 1536;             // 768  (3 heads x 256)
    float* wU    = mrsH2 + 768;             // E (CSR order)
    float* wB0   = wU + E;                  // E
    float* wB1   = wB0 + E;                 // E
    float* gt3   = wB1 + E;                 // 3*G*128
    // zero zone (single memset)
    float* zz    = gt3 + (size_t)3 * G * 128;
    float* degU  = zz;                      // N
    float* degC0 = degU + N;                // N
    float* degC1 = degC0 + N;               // N
    float* stZ   = degC1 + N;               // 1536
    float* xcp   = stZ + 1536;              // G*128
    float* xop   = xcp + (size_t)G * 128;   // G*128
    int*   cntI  = (int*)(xop + (size_t)G * 128);   // N (zeroed: part of zz span)
    size_t zzBytes = ((size_t)(4 * N) + 1536 + 2 * (size_t)G * 128) * 4;
    int* ptrI   = cntI + N;                 // N+1
    int* fillI  = ptrI + N + 1;             // N
    int* srcC   = fillI + N;                // E
    int* dstC   = srcC + E;                 // E
    int* bsum   = dstC + E;                 // up to 64
    bf16_t* whiT = (bf16_t*)((((size_t)(bsum + 64)) + 15) & ~(size_t)15);  // 6*16384
    bf16_t* wloT = whiT + 6 * 16384;                                       // 6*16384
    float4* epre = (float4*)epreF;

    int gridE = (E + 255) / 256;
    int gridN = (N + 255) / 256;
    int gridW = (N + 3) / 4;
    int gridG = (N + 63) / 64;
    int nb    = (N + 1023) / 1024;
    int span  = (N + 8191) / 8192;
    int gridP = (N + span * 4 - 1) / (span * 4);

    hipMemsetAsync(zz, 0, zzBytes, stream);

    // ---- weight pre-split (independent of everything else) ----
    k_wsplit<<<dim3(16, 6), 256, 0, stream>>>(Wf, cWs, xcW, xoW, whiT, wloT);

    // ---- CSR by dst + degrees + CSR weights ----
    k_hist2<<<gridE, 256, 0, stream>>>(esrc, edst, cntI, degU, E);
    k_scanA<<<nb, 1024, 0, stream>>>(cntI, ptrI, bsum, N);
    k_scanB<<<1, 64, 0, stream>>>(bsum, ptrI + N, nb);
    k_scanC<<<nb, 1024, 0, stream>>>(ptrI, bsum, fillI, N);
    k_fill<<<gridE, 256, 0, stream>>>(esrc, edst, fillI, srcC, dstC, degU, wU, E);

    // ---- h = relu(BN(x) @ W_feat) -> B1 (bf16) ----
    k_statsF<<<256, 256, 0, stream>>>(x, stZ, N);
    k_gemm<1, 0><<<gridG, 256, 0, stream>>>(x, nullptr, 0, stZ, whiT, wloT, B1, 128, 0, N);

    // ---- 3 x [BN -> GCNConv -> relu] ----
    for (int i = 0; i < 3; ++i){
        float* st = stZ + 256 * (i + 1);
        k_statsB<<<256, 256, 0, stream>>>(B1, st, N);
        k_gemm<0, 1><<<gridG, 256, 0, stream>>>(B1, nullptr, 0, st,
                whiT + (size_t)(i + 1) * 16384, wloT + (size_t)(i + 1) * 16384,
                B0, 128, 0, N);
        k_gather0<<<gridW, 256, 0, stream>>>(ptrI, srcC, wU, degU, B0, cbs + i * 128, B1, N);
    }

    // ---- attention ----
    k_prep<<<gridW, 256, 0, stream>>>(B1, eW, naW, epre, ntT, N);
    k_eatt2<<<gridE, 256, 0, stream>>>(srcC, dstC, epre, ebv, wB0, wB1,
                                       degC0, degC1, E);
    k_natt<<<gridN, 256, 0, stream>>>(ptrI, srcC, wU, degU, ntT, nab, natt, N);

    // ---- branch stats + CSR branch weights ----
    k_stats2<<<256, 256, 0, stream>>>(B1, natt, stZ + 1024, N);
    k_wB<<<gridE, 256, 0, stream>>>(srcC, degC0, degC1, wB0, wB1, E);

    // ---- xc / xo branch GEMMs into combined B0c, then ONE branch-split gather ----
    k_gemm<0, 1><<<gridG, 256, 0, stream>>>(B1, natt, 0, stZ + 1024,
            whiT + (size_t)4 * 16384, wloT + (size_t)4 * 16384, B0c, 256, 0, N);
    k_gemm<0, 1><<<gridG, 256, 0, stream>>>(B1, natt, 1, stZ + 1024 + 256,
            whiT + (size_t)5 * 16384, wloT + (size_t)5 * 16384, B0c, 256, 128, N);
    k_gatherP2<<<2 * gridP, 256, 0, stream>>>(ptrI, srcC, wB0, wB1, degC0, degC1, B0c,
                                              xcb, xob, batch, xcp, xop, N, span);

    // ---- heads: 3 heads fused per stage ----
    k_gstats3<<<3, 1024, 0, stream>>>(xcp, xop, mrsH, G);
    k_hgemm3<<<dim3(G, 3), 128, 0, stream>>>(xcp, xop, mrsH, cW1, cb1, oW1, ob1,
                                             coW1, cob1, gt3);
    k_gstats3b<<<3, 1024, 0, stream>>>(gt3, mrsH2, G);
    k_hfinal3<<<dim3((G + 3) / 4, 3), 256, 0, stream>>>(gt3, mrsH2, cW2, cb2, oW2, ob2,
                                                        coW2, cob2, out, G);
}

// Round 6
// 720.947 us; speedup vs baseline: 1.3877x; 1.0625x over previous
//
#include <hip/hip_runtime.h>

// CausalGCN forward on MI355X. fp32 in/out; internal N x 128 tensors bf16.
// R13 = R12 + fix: fused-prep eW dst-half base offset 512 -> 256 (OOB read caused
//       absmax 2.09). R12 changes: readlane index-broadcast gathers, span 4,
//       prep fused into 3rd gather0, merged prologue/eattnatt/stats2wB, dual GEMM.

typedef unsigned short bf16_t;
typedef unsigned int   uint32;
typedef __attribute__((ext_vector_type(8))) short   bf16x8;
typedef __attribute__((ext_vector_type(4))) float   f32x4;

__device__ __forceinline__ float b2f(bf16_t v){ return __uint_as_float(((uint32)v) << 16); }
__device__ __forceinline__ bf16_t f2b(float f){
    uint32 u = __float_as_uint(f);
    return (bf16_t)((u + 0x7fffu + ((u >> 16) & 1u)) >> 16);   // RNE
}
__device__ __forceinline__ uint32 pack2(float lo, float hi){
    return (uint32)f2b(lo) | ((uint32)f2b(hi) << 16);
}
__device__ __forceinline__ float lo16(uint32 u){ return __uint_as_float(u << 16); }
__device__ __forceinline__ float hi16(uint32 u){ return __uint_as_float(u & 0xffff0000u); }
__device__ __forceinline__ int   rl (int v, int l){ return __builtin_amdgcn_readlane(v, l); }
__device__ __forceinline__ float rlf(float v, int l){
    return __int_as_float(__builtin_amdgcn_readlane(__float_as_int(v), l));
}

// ---------- prologue: wsplit (96 blocks) | hist2 (gridE) | statsF (256) ----------
__global__ void k_prologue(const float* __restrict__ Wf, const float* __restrict__ cWs,
        const float* __restrict__ xcW, const float* __restrict__ xoW,
        bf16_t* __restrict__ whiT, bf16_t* __restrict__ wloT,
        const int* __restrict__ esrc, const int* __restrict__ edst,
        int* __restrict__ cnt, float* __restrict__ degU, int e,
        const float* __restrict__ x, float* __restrict__ st, int n, int gridE)
{
    int bx = blockIdx.x, tid = threadIdx.x;
    if (bx < 96){
        // W pre-split: fp32 [k][n] -> bf16 hi/lo transposed [n][k], 6 matrices
        int mat = bx >> 4, sub = bx & 15;
        const float* src = (mat == 0) ? Wf : (mat <= 3) ? cWs + (size_t)(mat - 1) * 16384
                          : (mat == 4) ? xcW : xoW;
        int i = (sub * 256 + tid) * 4;
        int nrow = i >> 7, k0 = i & 127;
        size_t off = (size_t)mat * 16384 + (size_t)nrow * 128 + k0;
        #pragma unroll
        for (int j = 0; j < 4; ++j){
            float w = src[(size_t)(k0 + j) * 128 + nrow];
            bf16_t h = f2b(w);
            whiT[off + j] = h;
            wloT[off + j] = f2b(w - b2f(h));
        }
    } else if (bx < 96 + gridE){
        int i = (bx - 96) * 256 + tid;
        if (i < e){
            atomicAdd(&cnt[edst[i]], 1);
            atomicAdd(&degU[esrc[i]], 1.0f);
        }
    } else {
        int bb = bx - 96 - gridE;
        int feat = tid & 127;
        int row = bb * 2 + (tid >> 7);
        float s = 0.f, sq = 0.f;
        for (; row < n; row += 512){
            float v = x[(size_t)row * 128 + feat];
            s += v; sq += v * v;
        }
        atomicAdd(&st[feat], s);
        atomicAdd(&st[128 + feat], sq);
    }
}

// ---------- BN stats (raw sum/sumsq; mean/rstd derived in consumers) ----------
__global__ void k_statsB(const bf16_t* __restrict__ a, float* __restrict__ st, int n){
    int tid = threadIdx.x;
    int feat = tid & 127;
    int row = blockIdx.x * 2 + (tid >> 7);
    float s = 0.f, sq = 0.f;
    for (; row < n; row += gridDim.x * 2){
        float v = b2f(a[(size_t)row * 128 + feat]);
        s += v; sq += v * v;
    }
    atomicAdd(&st[feat], s);
    atomicAdd(&st[128 + feat], sq);
}

// ---------- MFMA GEMM: C[n, ccol0..+128 of ldc] = act( BN(scale*A) @ W ) ----------
template<int ACT, int INBF>  // ACT: 1=relu ; INBF: input bf16?
__global__ __launch_bounds__(256, 3) void k_gemm(const void* __restrict__ Av,
        const float* __restrict__ scale, int sch,
        const float* __restrict__ st, const bf16_t* __restrict__ WhiT,
        const bf16_t* __restrict__ WloT,
        bf16_t* __restrict__ C, int ldc, int ccol0, int n)
{
    __shared__ bf16_t As[64 * 136];
    __shared__ bf16_t Whi[128 * 72];
    __shared__ bf16_t Wlo[128 * 72];
    int tid = threadIdx.x;
    int wid = tid >> 6, lane = tid & 63;
    int row0 = blockIdx.x * 64;
    int m0 = wid * 16;
    int q8 = (lane >> 4) * 8, l15 = lane & 15;

    int c8t = (tid & 15) * 8;
    float sM[8], sR[8];
    #pragma unroll
    for (int j = 0; j < 8; ++j){
        float m = st[c8t + j] / n;
        float var = st[128 + c8t + j] / n - m * m;
        sM[j] = m; sR[j] = rsqrtf(var + 1e-5f);
    }

    for (int i = tid; i < 64 * 16; i += 256){
        int r = i >> 4, c8 = (i & 15) * 8;
        int gr = row0 + r;
        float v[8];
        if (gr < n){
            float sc = scale ? scale[(size_t)gr * 2 + sch] : 1.f;
            if (INBF){
                const bf16_t* Ab = (const bf16_t*)Av;
                ushort4 qa = *(const ushort4*)&Ab[(size_t)gr * 128 + c8];
                ushort4 qb = *(const ushort4*)&Ab[(size_t)gr * 128 + c8 + 4];
                v[0]=b2f(qa.x); v[1]=b2f(qa.y); v[2]=b2f(qa.z); v[3]=b2f(qa.w);
                v[4]=b2f(qb.x); v[5]=b2f(qb.y); v[6]=b2f(qb.z); v[7]=b2f(qb.w);
            } else {
                const float* Af = (const float*)Av;
                float4 fa = *(const float4*)&Af[(size_t)gr * 128 + c8];
                float4 fb = *(const float4*)&Af[(size_t)gr * 128 + c8 + 4];
                v[0]=fa.x; v[1]=fa.y; v[2]=fa.z; v[3]=fa.w;
                v[4]=fb.x; v[5]=fb.y; v[6]=fb.z; v[7]=fb.w;
            }
            #pragma unroll
            for (int j = 0; j < 8; ++j)
                v[j] = (v[j] * sc - sM[j]) * sR[j] + 1e-4f;
        } else {
            #pragma unroll
            for (int j = 0; j < 8; ++j) v[j] = 0.f;
        }
        #pragma unroll
        for (int j = 0; j < 8; ++j) As[r * 136 + c8 + j] = f2b(v[j]);
    }

    f32x4 acc[8];
    #pragma unroll
    for (int t = 0; t < 8; ++t) acc[t] = (f32x4){0.f, 0.f, 0.f, 0.f};

    for (int kc = 0; kc < 128; kc += 64){
        __syncthreads();
        for (int i = tid; i < 128 * 8; i += 256){
            int nrow = i >> 3, k8 = (i & 7) * 8;
            *(uint4*)&Whi[nrow * 72 + k8] = *(const uint4*)&WhiT[(size_t)nrow * 128 + kc + k8];
            *(uint4*)&Wlo[nrow * 72 + k8] = *(const uint4*)&WloT[(size_t)nrow * 128 + kc + k8];
        }
        __syncthreads();
        #pragma unroll
        for (int kbl = 0; kbl < 2; ++kbl){
            bf16x8 a = *(const bf16x8*)&As[(m0 + l15) * 136 + kc + kbl * 32 + q8];
            #pragma unroll
            for (int nt = 0; nt < 8; ++nt){
                bf16x8 bh = *(const bf16x8*)&Whi[(nt * 16 + l15) * 72 + kbl * 32 + q8];
                acc[nt] = __builtin_amdgcn_mfma_f32_16x16x32_bf16(a, bh, acc[nt], 0, 0, 0);
                bf16x8 bl = *(const bf16x8*)&Wlo[(nt * 16 + l15) * 72 + kbl * 32 + q8];
                acc[nt] = __builtin_amdgcn_mfma_f32_16x16x32_bf16(a, bl, acc[nt], 0, 0, 0);
            }
        }
    }

    __syncthreads();
    #pragma unroll
    for (int nt = 0; nt < 8; ++nt){
        #pragma unroll
        for (int r = 0; r < 4; ++r){
            float v = acc[nt][r];
            if (ACT == 1) v = fmaxf(v, 0.f);
            As[(m0 + (lane >> 4) * 4 + r) * 136 + nt * 16 + l15] = f2b(v);
        }
    }
    __syncthreads();
    for (int i = tid; i < 64 * 16; i += 256){
        int r = i >> 4, c8 = (i & 15) * 8;
        int gr = row0 + r;
        if (gr < n)
            *(uint4*)&C[(size_t)gr * ldc + ccol0 + c8] = *(const uint4*)&As[r * 136 + c8];
    }
}

// dual branch GEMM: blockIdx.y = branch (0:xc, 1:xo); input bf16, no act
__global__ __launch_bounds__(256, 3) void k_gemm2(const bf16_t* __restrict__ Ab,
        const float* __restrict__ natt, const float* __restrict__ stBase,
        const bf16_t* __restrict__ whiT6, const bf16_t* __restrict__ wloT6,
        bf16_t* __restrict__ C, int n)
{
    __shared__ bf16_t As[64 * 136];
    __shared__ bf16_t Whi[128 * 72];
    __shared__ bf16_t Wlo[128 * 72];
    int brn = blockIdx.y;
    const float* st = stBase + brn * 256;
    const bf16_t* WhiT = whiT6 + (size_t)(4 + brn) * 16384;
    const bf16_t* WloT = wloT6 + (size_t)(4 + brn) * 16384;
    int ccol0 = brn * 128;
    const int ldc = 256;

    int tid = threadIdx.x;
    int wid = tid >> 6, lane = tid & 63;
    int row0 = blockIdx.x * 64;
    int m0 = wid * 16;
    int q8 = (lane >> 4) * 8, l15 = lane & 15;

    int c8t = (tid & 15) * 8;
    float sM[8], sR[8];
    #pragma unroll
    for (int j = 0; j < 8; ++j){
        float m = st[c8t + j] / n;
        float var = st[128 + c8t + j] / n - m * m;
        sM[j] = m; sR[j] = rsqrtf(var + 1e-5f);
    }

    for (int i = tid; i < 64 * 16; i += 256){
        int r = i >> 4, c8 = (i & 15) * 8;
        int gr = row0 + r;
        float v[8];
        if (gr < n){
            float sc = natt[(size_t)gr * 2 + brn];
            ushort4 qa = *(const ushort4*)&Ab[(size_t)gr * 128 + c8];
            ushort4 qb = *(const ushort4*)&Ab[(size_t)gr * 128 + c8 + 4];
            v[0]=b2f(qa.x); v[1]=b2f(qa.y); v[2]=b2f(qa.z); v[3]=b2f(qa.w);
            v[4]=b2f(qb.x); v[5]=b2f(qb.y); v[6]=b2f(qb.z); v[7]=b2f(qb.w);
            #pragma unroll
            for (int j = 0; j < 8; ++j)
                v[j] = (v[j] * sc - sM[j]) * sR[j] + 1e-4f;
        } else {
            #pragma unroll
            for (int j = 0; j < 8; ++j) v[j] = 0.f;
        }
        #pragma unroll
        for (int j = 0; j < 8; ++j) As[r * 136 + c8 + j] = f2b(v[j]);
    }

    f32x4 acc[8];
    #pragma unroll
    for (int t = 0; t < 8; ++t) acc[t] = (f32x4){0.f, 0.f, 0.f, 0.f};

    for (int kc = 0; kc < 128; kc += 64){
        __syncthreads();
        for (int i = tid; i < 128 * 8; i += 256){
            int nrow = i >> 3, k8 = (i & 7) * 8;
            *(uint4*)&Whi[nrow * 72 + k8] = *(const uint4*)&WhiT[(size_t)nrow * 128 + kc + k8];
            *(uint4*)&Wlo[nrow * 72 + k8] = *(const uint4*)&WloT[(size_t)nrow * 128 + kc + k8];
        }
        __syncthreads();
        #pragma unroll
        for (int kbl = 0; kbl < 2; ++kbl){
            bf16x8 a = *(const bf16x8*)&As[(m0 + l15) * 136 + kc + kbl * 32 + q8];
            #pragma unroll
            for (int nt = 0; nt < 8; ++nt){
                bf16x8 bh = *(const bf16x8*)&Whi[(nt * 16 + l15) * 72 + kbl * 32 + q8];
                acc[nt] = __builtin_amdgcn_mfma_f32_16x16x32_bf16(a, bh, acc[nt], 0, 0, 0);
                bf16x8 bl = *(const bf16x8*)&Wlo[(nt * 16 + l15) * 72 + kbl * 32 + q8];
                acc[nt] = __builtin_amdgcn_mfma_f32_16x16x32_bf16(a, bl, acc[nt], 0, 0, 0);
            }
        }
    }

    __syncthreads();
    #pragma unroll
    for (int nt = 0; nt < 8; ++nt){
        #pragma unroll
        for (int r = 0; r < 4; ++r){
            As[(m0 + (lane >> 4) * 4 + r) * 136 + nt * 16 + l15] = f2b(acc[nt][r]);
        }
    }
    __syncthreads();
    for (int i = tid; i < 64 * 16; i += 256){
        int r = i >> 4, c8 = (i & 15) * 8;
        int gr = row0 + r;
        if (gr < n)
            *(uint4*)&C[(size_t)gr * ldc + ccol0 + c8] = *(const uint4*)&As[r * 136 + c8];
    }
}

// ---------- CSR scan ----------
__global__ __launch_bounds__(1024) void k_scanA(const int* __restrict__ cnt,
        int* __restrict__ ptr, int* __restrict__ bsum, int n){
    __shared__ int wsum[16];
    int t = threadIdx.x, lane = t & 63, wid = t >> 6;
    int i = blockIdx.x * 1024 + t;
    int v = (i < n) ? cnt[i] : 0;
    int s = v;
    for (int off = 1; off < 64; off <<= 1){
        int u = __shfl_up(s, off);
        if (lane >= off) s += u;
    }
    if (lane == 63) wsum[wid] = s;
    __syncthreads();
    if (wid == 0 && lane < 16){
        int ws = wsum[lane];
        for (int off = 1; off < 16; off <<= 1){
            int u = __shfl_up(ws, off);
            if (lane >= off) ws += u;
        }
        wsum[lane] = ws;
    }
    __syncthreads();
    int woff = wid ? wsum[wid - 1] : 0;
    if (i < n) ptr[i] = woff + s - v;
    if (t == 1023) bsum[blockIdx.x] = woff + s;
}
__global__ void k_scanB(int* __restrict__ bsum, int* __restrict__ ptrN, int nb){
    int lane = threadIdx.x;       // 64 threads
    int carry = 0;
    for (int base = 0; base < nb; base += 64){
        int i = base + lane;
        int v = (i < nb) ? bsum[i] : 0;
        int s = v;
        for (int off = 1; off < 64; off <<= 1){
            int u = __shfl_up(s, off);
            if (lane >= off) s += u;
        }
        if (i < nb) bsum[i] = carry + s - v;
        carry += __shfl(s, 63);
    }
    if (lane == 0) *ptrN = carry;
}
__global__ __launch_bounds__(1024) void k_scanC(int* __restrict__ ptr,
        const int* __restrict__ bsum, int* __restrict__ fill, int n){
    int i = blockIdx.x * 1024 + threadIdx.x;
    if (i < n){
        int p = ptr[i] + bsum[blockIdx.x];
        ptr[i] = p; fill[i] = p;
    }
}
// fill CSR + wU = rsqrt(degU[src]+1) in one pass
__global__ void k_fill(const int* __restrict__ src, const int* __restrict__ dst,
                       int* __restrict__ fill, int* __restrict__ srcC,
                       int* __restrict__ dstC, const float* __restrict__ degU,
                       float* __restrict__ wU, int e){
    int i = blockIdx.x * 256 + threadIdx.x;
    if (i < e){
        int s = src[i];
        int d = dst[i];
        int slot = atomicAdd(&fill[d], 1);
        srcC[slot] = s;
        dstC[slot] = d;
        wU[slot] = rsqrtf(degU[s] + 1.0f);
    }
}

// ---------- conv propagate: readlane index broadcast; optional fused prep ----------
template<int PREP>
__global__ __launch_bounds__(256) void k_gather0(const int* __restrict__ ptr,
        const int* __restrict__ srcC, const float* __restrict__ wE,
        const float* __restrict__ degU, const bf16_t* __restrict__ t,
        const float* __restrict__ bias, bf16_t* __restrict__ outB,
        const float* __restrict__ eW, const float* __restrict__ naW,
        float4* __restrict__ epre, float* __restrict__ ntT, int n)
{
    int node = blockIdx.x * 4 + (threadIdx.x >> 6);
    if (node >= n) return;
    int lane = threadIdx.x & 63;
    const uint32* T = (const uint32*)t;
    float dd = rsqrtf(degU[node] + 1.0f);
    uint32 sv = T[(size_t)node * 64 + lane];
    float a0 = 0.f, a1 = 0.f;
    int k = ptr[node], end = ptr[node + 1];
    while (k < end){
        int cnt = min(end - k, 64);
        int kl = k + min(lane, cnt - 1);
        int   myI = srcC[kl];
        float myW = wE[kl];
        int j = 0;
        for (; j + 8 <= cnt; j += 8){
            int s0 = rl(myI, j),     s1 = rl(myI, j + 1), s2 = rl(myI, j + 2), s3 = rl(myI, j + 3);
            int s4 = rl(myI, j + 4), s5 = rl(myI, j + 5), s6 = rl(myI, j + 6), s7 = rl(myI, j + 7);
            float w0 = rlf(myW, j),     w1 = rlf(myW, j + 1), w2 = rlf(myW, j + 2), w3 = rlf(myW, j + 3);
            float w4 = rlf(myW, j + 4), w5 = rlf(myW, j + 5), w6 = rlf(myW, j + 6), w7 = rlf(myW, j + 7);
            uint32 v0 = T[(size_t)s0 * 64 + lane];
            uint32 v1 = T[(size_t)s1 * 64 + lane];
            uint32 v2 = T[(size_t)s2 * 64 + lane];
            uint32 v3 = T[(size_t)s3 * 64 + lane];
            uint32 v4 = T[(size_t)s4 * 64 + lane];
            uint32 v5 = T[(size_t)s5 * 64 + lane];
            uint32 v6 = T[(size_t)s6 * 64 + lane];
            uint32 v7 = T[(size_t)s7 * 64 + lane];
            a0 += w0 * lo16(v0) + w1 * lo16(v1) + w2 * lo16(v2) + w3 * lo16(v3);
            a1 += w0 * hi16(v0) + w1 * hi16(v1) + w2 * hi16(v2) + w3 * hi16(v3);
            a0 += w4 * lo16(v4) + w5 * lo16(v5) + w6 * lo16(v6) + w7 * lo16(v7);
            a1 += w4 * hi16(v4) + w5 * hi16(v5) + w6 * hi16(v6) + w7 * hi16(v7);
        }
        for (; j < cnt; ++j){
            int s = rl(myI, j);
            float w = rlf(myW, j);
            uint32 v = T[(size_t)s * 64 + lane];
            a0 += w * lo16(v); a1 += w * hi16(v);
        }
        k += cnt;
    }
    a0 = fmaxf(dd * (a0 + dd * lo16(sv)) + bias[2 * lane],     0.f);
    a1 = fmaxf(dd * (a1 + dd * hi16(sv)) + bias[2 * lane + 1], 0.f);
    ((uint32*)outB)[(size_t)node * 64 + lane] = pack2(a0, a1);
    if (PREP){
        // lane holds feats (2*lane, 2*lane+1) = (a0, a1).
        // eW row f at float offset 2f; dst half rows 128+f at 256+2f (NOT 512 - R12 bug).
        float s0 = a0 * eW[4 * lane]           + a1 * eW[4 * lane + 2];
        float s1 = a0 * eW[4 * lane + 1]       + a1 * eW[4 * lane + 3];
        float d0 = a0 * eW[256 + 4 * lane]     + a1 * eW[256 + 4 * lane + 2];
        float d1 = a0 * eW[256 + 4 * lane + 1] + a1 * eW[256 + 4 * lane + 3];
        float n0 = a0 * naW[4 * lane]          + a1 * naW[4 * lane + 2];
        float n1 = a0 * naW[4 * lane + 1]      + a1 * naW[4 * lane + 3];
        for (int off = 32; off; off >>= 1){
            s0 += __shfl_xor(s0, off); s1 += __shfl_xor(s1, off);
            d0 += __shfl_xor(d0, off); d1 += __shfl_xor(d1, off);
            n0 += __shfl_xor(n0, off); n1 += __shfl_xor(n1, off);
        }
        if (lane == 0){
            epre[node] = make_float4(s0, s1, d0, d1);
            ntT[2 * node] = n0; ntT[2 * node + 1] = n1;
        }
    }
}

// ---------- branch propagate, branch-split + readlane broadcast ----------
__global__ __launch_bounds__(256) void k_gatherP2(const int* __restrict__ ptr,
        const int* __restrict__ srcC, const float* __restrict__ w0E,
        const float* __restrict__ w1E, const float* __restrict__ degC0,
        const float* __restrict__ degC1, const bf16_t* __restrict__ t,
        const float* __restrict__ biasC, const float* __restrict__ biasO,
        const int* __restrict__ batch, float* __restrict__ pool0,
        float* __restrict__ pool1, int n, int span)
{
    int br   = blockIdx.x & 1;
    int wave = (blockIdx.x >> 1) * 4 + (threadIdx.x >> 6);
    int lane = threadIdx.x & 63;
    int nbeg = wave * span;
    if (nbeg >= n) return;
    int nend = min(n, nbeg + span);
    const float* wE   = br ? w1E : w0E;
    const float* deg  = br ? degC1 : degC0;
    const float* bias = br ? biasO : biasC;
    float* pool       = br ? pool1 : pool0;
    float b0 = bias[2 * lane], b1 = bias[2 * lane + 1];
    const uint32* T = (const uint32*)t;       // B0c row = 128 uint32
    int rowoff = (br ? 64 : 0) + lane;
    int curG = -1;
    float p0 = 0.f, p1 = 0.f;
    for (int node = nbeg; node < nend; ++node){
        float dd = rsqrtf(deg[node] + 1.0f);
        uint32 sv = T[(size_t)node * 128 + rowoff];
        float a0 = 0.f, a1 = 0.f;
        int k = ptr[node], end = ptr[node + 1];
        while (k < end){
            int cnt = min(end - k, 64);
            int kl = k + min(lane, cnt - 1);
            int   myI = srcC[kl];
            float myW = wE[kl];
            int j = 0;
            for (; j + 8 <= cnt; j += 8){
                int s0 = rl(myI, j),     s1 = rl(myI, j + 1), s2 = rl(myI, j + 2), s3 = rl(myI, j + 3);
                int s4 = rl(myI, j + 4), s5 = rl(myI, j + 5), s6 = rl(myI, j + 6), s7 = rl(myI, j + 7);
                float w0 = rlf(myW, j),     w1 = rlf(myW, j + 1), w2 = rlf(myW, j + 2), w3 = rlf(myW, j + 3);
                float w4 = rlf(myW, j + 4), w5 = rlf(myW, j + 5), w6 = rlf(myW, j + 6), w7 = rlf(myW, j + 7);
                uint32 v0 = T[(size_t)s0 * 128 + rowoff];
                uint32 v1 = T[(size_t)s1 * 128 + rowoff];
                uint32 v2 = T[(size_t)s2 * 128 + rowoff];
                uint32 v3 = T[(size_t)s3 * 128 + rowoff];
                uint32 v4 = T[(size_t)s4 * 128 + rowoff];
                uint32 v5 = T[(size_t)s5 * 128 + rowoff];
                uint32 v6 = T[(size_t)s6 * 128 + rowoff];
                uint32 v7 = T[(size_t)s7 * 128 + rowoff];
                a0 += w0 * lo16(v0) + w1 * lo16(v1) + w2 * lo16(v2) + w3 * lo16(v3);
                a1 += w0 * hi16(v0) + w1 * hi16(v1) + w2 * hi16(v2) + w3 * hi16(v3);
                a0 += w4 * lo16(v4) + w5 * lo16(v5) + w6 * lo16(v6) + w7 * lo16(v7);
                a1 += w4 * hi16(v4) + w5 * hi16(v5) + w6 * hi16(v6) + w7 * hi16(v7);
            }
            for (; j < cnt; ++j){
                int s = rl(myI, j);
                float w = rlf(myW, j);
                uint32 v = T[(size_t)s * 128 + rowoff];
                a0 += w * lo16(v); a1 += w * hi16(v);
            }
            k += cnt;
        }
        a0 = dd * (a0 + dd * lo16(sv)) + b0;
        a1 = dd * (a1 + dd * hi16(sv)) + b1;
        a0 = a0 > 0.f ? a0 : expm1f(a0);
        a1 = a1 > 0.f ? a1 : expm1f(a1);
        int g = batch[node];
        if (g != curG){
            if (curG >= 0){
                float* p = pool + (size_t)curG * 128 + 2 * lane;
                atomicAdd(&p[0], p0); atomicAdd(&p[1], p1);
            }
            curG = g; p0 = a0; p1 = a1;
        } else {
            p0 += a0; p1 += a1;
        }
    }
    if (curG >= 0){
        float* p = pool + (size_t)curG * 128 + 2 * lane;
        atomicAdd(&p[0], p0); atomicAdd(&p[1], p1);
    }
}

// ---------- attention: natt (gridN blocks) | eatt2 (gridE blocks), independent ----------
__global__ void k_eattnatt(const int* __restrict__ srcC, const int* __restrict__ dstC,
        const float4* __restrict__ epre, const float* __restrict__ eb,
        float* __restrict__ wB0, float* __restrict__ wB1,
        float* __restrict__ d0, float* __restrict__ d1,
        const int* __restrict__ ptr, const float* __restrict__ wU,
        const float* __restrict__ degU, const float* __restrict__ ntT,
        const float* __restrict__ nab, float* __restrict__ natt,
        int e, int n, int gridN)
{
    int bx = blockIdx.x;
    if (bx < gridN){
        int i = bx * 256 + threadIdx.x;
        if (i >= n) return;
        float dd = rsqrtf(degU[i] + 1.0f);
        float z0 = 0.f, z1 = 0.f;
        int end = ptr[i + 1];
        for (int k = ptr[i]; k < end; ++k){
            int s = srcC[k];
            float w = wU[k];
            z0 += w * ntT[2 * s]; z1 += w * ntT[2 * s + 1];
        }
        z0 = dd * (z0 + dd * ntT[2 * i])     + nab[0];
        z1 = dd * (z1 + dd * ntT[2 * i + 1]) + nab[1];
        float m = fmaxf(z0, z1);
        float e0 = expf(z0 - m), e1 = expf(z1 - m);
        float inv = 1.f / (e0 + e1);
        natt[2 * i] = e0 * inv; natt[2 * i + 1] = e1 * inv;
    } else {
        int i = (bx - gridN) * 256 + threadIdx.x;
        if (i >= e) return;
        int s = srcC[i];
        float4 ps = epre[s], pd = epre[dstC[i]];
        float l0 = ps.x + pd.z + eb[0], l1 = ps.y + pd.w + eb[1];
        float m = fmaxf(l0, l1);
        float e0 = expf(l0 - m), e1 = expf(l1 - m);
        float inv = 1.f / (e0 + e1);
        e0 *= inv; e1 *= inv;
        wB0[i] = e0; wB1[i] = e1;
        atomicAdd(&d0[s], e0); atomicAdd(&d1[s], e1);
    }
}

// ---------- stats2 (256 blocks) | wB (gridE blocks), independent ----------
__global__ void k_stats2wB(const bf16_t* __restrict__ a, const float* __restrict__ natt,
        float* __restrict__ st, int n,
        const int* __restrict__ srcC, const float* __restrict__ degC0,
        const float* __restrict__ degC1, float* __restrict__ w0,
        float* __restrict__ w1, int e)
{
    int bx = blockIdx.x, tid = threadIdx.x;
    if (bx < 256){
        int feat = tid & 127;
        int row = bx * 2 + (tid >> 7);
        float s0 = 0.f, q0 = 0.f, s1 = 0.f, q1 = 0.f;
        for (; row < n; row += 512){
            float v = b2f(a[(size_t)row * 128 + feat]);
            float2 w = *(const float2*)&natt[(size_t)row * 2];
            float v0 = v * w.x, v1 = v * w.y;
            s0 += v0; q0 += v0 * v0; s1 += v1; q1 += v1 * v1;
        }
        atomicAdd(&st[feat], s0);       atomicAdd(&st[128 + feat], q0);
        atomicAdd(&st[256 + feat], s1); atomicAdd(&st[384 + feat], q1);
    } else {
        int i = (bx - 256) * 256 + tid;
        if (i < e){
            int s = srcC[i];
            w0[i] *= rsqrtf(degC0[s] + 1.0f);
            w1[i] *= rsqrtf(degC1[s] + 1.0f);
        }
    }
}

// ---------- heads (G=512, fp32), 3 heads fused per stage ----------
__global__ __launch_bounds__(1024) void k_gstats3(const float* __restrict__ xcp,
        const float* __restrict__ xop, float* __restrict__ mrsH, int n){
    __shared__ float red[2][1024];
    int head = blockIdx.x;
    const float* a = (head == 1) ? xop : xcp;
    const float* b = (head == 0) ? xcp : xop;
    int f = (head == 2) ? 256 : 128;
    float* mrs = mrsH + head * 512;
    int col = threadIdx.x & (f - 1);
    int rpb = 1024 / f;
    int rw  = threadIdx.x / f;
    float s = 0.f, sq = 0.f;
    for (int r = rw; r < n; r += rpb){
        float v = (col < 128) ? a[(size_t)r * 128 + col] : b[(size_t)r * 128 + col - 128];
        s += v; sq += v * v;
    }
    red[0][threadIdx.x] = s; red[1][threadIdx.x] = sq;
    __syncthreads();
    if (threadIdx.x < (unsigned)f){
        float ts = 0.f, tq = 0.f;
        for (int w = 0; w < rpb; ++w){ ts += red[0][w * f + col]; tq += red[1][w * f + col]; }
        float m = ts / n, var = tq / n - m * m;
        mrs[col] = m; mrs[f + col] = rsqrtf(var + 1e-5f);
    }
}
__global__ __launch_bounds__(128) void k_hgemm3(const float* __restrict__ xcp,
        const float* __restrict__ xop, const float* __restrict__ mrsH,
        const float* __restrict__ cW1, const float* __restrict__ cb1,
        const float* __restrict__ oW1, const float* __restrict__ ob1,
        const float* __restrict__ coW1, const float* __restrict__ cob1,
        float* __restrict__ gt3)
{
    __shared__ float as[256];
    int head = blockIdx.y, row = blockIdx.x, tid = threadIdx.x;
    const float* a  = (head == 1) ? xop : xcp;
    const float* b2 = (head == 0) ? xcp : xop;
    int fin = (head == 2) ? 256 : 128;
    const float* mrs = mrsH + head * 512;
    const float* W  = (head == 0) ? cW1 : (head == 1) ? oW1 : coW1;
    const float* bb = (head == 0) ? cb1 : (head == 1) ? ob1 : cob1;
    float* o = gt3 + (size_t)head * 512 * 128;
    for (int i = tid; i < fin; i += 128){
        float v = (i < 128) ? a[(size_t)row * 128 + i] : b2[(size_t)row * 128 + i - 128];
        as[i] = (v - mrs[i]) * mrs[fin + i] + 1e-4f;
    }
    __syncthreads();
    float s = 0.f;
    for (int k = 0; k < fin; ++k) s += as[k] * W[k * 128 + tid];
    s += bb[tid];
    if (head < 2) s = fmaxf(s, 0.f);
    else { s = s > 0.f ? s : expm1f(s); s = s > 0.f ? s : expm1f(s); }
    o[(size_t)row * 128 + tid] = s;
}
__global__ __launch_bounds__(1024) void k_gstats3b(const float* __restrict__ gt3,
        float* __restrict__ mrsH2, int n){
    __shared__ float red[2][1024];
    int head = blockIdx.x;
    const float* a = gt3 + (size_t)head * 512 * 128;
    float* mrs = mrsH2 + head * 256;
    int col = threadIdx.x & 127;
    int rw  = threadIdx.x >> 7;    // 8 rows/block-pass
    float s = 0.f, sq = 0.f;
    for (int r = rw; r < n; r += 8){
        float v = a[(size_t)r * 128 + col];
        s += v; sq += v * v;
    }
    red[0][threadIdx.x] = s; red[1][threadIdx.x] = sq;
    __syncthreads();
    if (threadIdx.x < 128u){
        float ts = 0.f, tq = 0.f;
        for (int w = 0; w < 8; ++w){ ts += red[0][w * 128 + col]; tq += red[1][w * 128 + col]; }
        float m = ts / n, var = tq / n - m * m;
        mrs[col] = m; mrs[128 + col] = rsqrtf(var + 1e-5f);
    }
}
__global__ __launch_bounds__(256) void k_hfinal3(const float* __restrict__ gt3,
        const float* __restrict__ mrsH2,
        const float* __restrict__ cW2, const float* __restrict__ cb2,
        const float* __restrict__ oW2, const float* __restrict__ ob2,
        const float* __restrict__ coW2, const float* __restrict__ cob2,
        float* __restrict__ out, int nrows)
{
    int head = blockIdx.y;
    int row = blockIdx.x * 4 + (threadIdx.x >> 6);
    if (row >= nrows) return;
    int lane = threadIdx.x & 63;
    const float* a   = gt3 + (size_t)head * 512 * 128;
    const float* mrs = mrsH2 + head * 256;
    const float* W = (head == 0) ? cW2 : (head == 1) ? oW2 : coW2;
    const float* b = (head == 0) ? cb2 : (head == 1) ? ob2 : cob2;
    float* o = out + (size_t)head * nrows * 10;
    float v0 = (a[(size_t)row * 128 + lane]      - mrs[lane])      * mrs[128 + lane]      + 1e-4f;
    float v1 = (a[(size_t)row * 128 + 64 + lane] - mrs[64 + lane]) * mrs[128 + 64 + lane] + 1e-4f;
    float logit[10];
    #pragma unroll
    for (int c = 0; c < 10; ++c){
        float p = v0 * W[lane * 10 + c] + v1 * W[(lane + 64) * 10 + c];
        for (int off = 32; off; off >>= 1) p += __shfl_xor(p, off);
        logit[c] = p + b[c];
    }
    float m = logit[0];
    #pragma unroll
    for (int c = 1; c < 10; ++c) m = fmaxf(m, logit[c]);
    float s = 0.f;
    #pragma unroll
    for (int c = 0; c < 10; ++c) s += expf(logit[c] - m);
    float lse = logf(s);
    if (lane < 10) o[row * 10 + lane] = logit[lane] - m - lse;
}

extern "C" void kernel_launch(void* const* d_in, const int* in_sizes, int n_in,
                              void* d_out, int out_size, void* d_ws, size_t ws_size,
                              hipStream_t stream)
{
    const int N = in_sizes[0] / 128;
    const int E = in_sizes[24];
    const int G = 512;
    const float* x    = (const float*)d_in[0];
    const float* Wf   = (const float*)d_in[1];
    const float* cWs  = (const float*)d_in[2];
    const float* cbs  = (const float*)d_in[3];
    const float* eW   = (const float*)d_in[4];
    const float* ebv  = (const float*)d_in[5];
    const float* naW  = (const float*)d_in[6];
    const float* nab  = (const float*)d_in[7];
    const float* xcW  = (const float*)d_in[8];
    const float* xcb  = (const float*)d_in[9];
    const float* xoW  = (const float*)d_in[10];
    const float* xob  = (const float*)d_in[11];
    const float* cW1  = (const float*)d_in[12];
    const float* cb1  = (const float*)d_in[13];
    const float* cW2  = (const float*)d_in[14];
    const float* cb2  = (const float*)d_in[15];
    const float* oW1  = (const float*)d_in[16];
    const float* ob1  = (const float*)d_in[17];
    const float* oW2  = (const float*)d_in[18];
    const float* ob2  = (const float*)d_in[19];
    const float* coW1 = (const float*)d_in[20];
    const float* cob1 = (const float*)d_in[21];
    const float* coW2 = (const float*)d_in[22];
    const float* cob2 = (const float*)d_in[23];
    const int* esrc  = (const int*)d_in[24];
    const int* edst  = (const int*)d_in[25];
    const int* batch = (const int*)d_in[26];
    float* out = (float*)d_out;

    size_t NH = (size_t)N * 128;
    bf16_t* B1  = (bf16_t*)d_ws;            // N*128
    bf16_t* B0  = B1 + NH;                  // N*128
    bf16_t* B0c = B0 + NH;                  // N*256 ([xc|xo])
    float* fbase = (float*)(B0c + 2 * NH);
    float* epreF = fbase;                   // 4N
    float* ntT   = epreF + 4 * (size_t)N;
    float* natt  = ntT + 2 * (size_t)N;
    float* mrsH  = natt + 2 * (size_t)N;    // 1536 (3 heads x 512)
    float* mrsH2 = mrsH + 1536;             // 768  (3 heads x 256)
    float* wU    = mrsH2 + 768;             // E (CSR order)
    float* wB0   = wU + E;                  // E
    float* wB1   = wB0 + E;                 // E
    float* gt3   = wB1 + E;                 // 3*G*128
    // zero zone (single memset)
    float* zz    = gt3 + (size_t)3 * G * 128;
    float* degU  = zz;                      // N
    float* degC0 = degU + N;                // N
    float* degC1 = degC0 + N;               // N
    float* stZ   = degC1 + N;               // 1536
    float* xcp   = stZ + 1536;              // G*128
    float* xop   = xcp + (size_t)G * 128;   // G*128
    int*   cntI  = (int*)(xop + (size_t)G * 128);   // N (zeroed: part of zz span)
    size_t zzBytes = ((size_t)(4 * N) + 1536 + 2 * (size_t)G * 128) * 4;
    int* ptrI   = cntI + N;                 // N+1
    int* fillI  = ptrI + N + 1;             // N
    int* srcC   = fillI + N;                // E
    int* dstC   = srcC + E;                 // E
    int* bsum   = dstC + E;                 // up to 64
    bf16_t* whiT = (bf16_t*)((((size_t)(bsum + 64)) + 15) & ~(size_t)15);  // 6*16384
    bf16_t* wloT = whiT + 6 * 16384;                                       // 6*16384
    float4* epre = (float4*)epreF;

    int gridE = (E + 255) / 256;
    int gridN = (N + 255) / 256;
    int gridW = (N + 3) / 4;
    int gridG = (N + 63) / 64;
    int nb    = (N + 1023) / 1024;
    int span  = (N + 16383) / 16384;
    int gridP = (N + span * 4 - 1) / (span * 4);

    hipMemsetAsync(zz, 0, zzBytes, stream);

    // ---- prologue: wsplit | hist2 | statsF ----
    k_prologue<<<96 + gridE + 256, 256, 0, stream>>>(Wf, cWs, xcW, xoW, whiT, wloT,
            esrc, edst, cntI, degU, E, x, stZ, N, gridE);

    // ---- CSR scan + fill (wU fused) ----
    k_scanA<<<nb, 1024, 0, stream>>>(cntI, ptrI, bsum, N);
    k_scanB<<<1, 64, 0, stream>>>(bsum, ptrI + N, nb);
    k_scanC<<<nb, 1024, 0, stream>>>(ptrI, bsum, fillI, N);
    k_fill<<<gridE, 256, 0, stream>>>(esrc, edst, fillI, srcC, dstC, degU, wU, E);

    // ---- h = relu(BN(x) @ W_feat) -> B1 (bf16) ----
    k_gemm<1, 0><<<gridG, 256, 0, stream>>>(x, nullptr, 0, stZ, whiT, wloT, B1, 128, 0, N);

    // ---- 3 x [BN -> GCNConv -> relu], prep fused into last gather ----
    for (int i = 0; i < 3; ++i){
        float* st = stZ + 256 * (i + 1);
        k_statsB<<<256, 256, 0, stream>>>(B1, st, N);
        k_gemm<0, 1><<<gridG, 256, 0, stream>>>(B1, nullptr, 0, st,
                whiT + (size_t)(i + 1) * 16384, wloT + (size_t)(i + 1) * 16384,
                B0, 128, 0, N);
        if (i < 2)
            k_gather0<0><<<gridW, 256, 0, stream>>>(ptrI, srcC, wU, degU, B0,
                    cbs + i * 128, B1, eW, naW, epre, ntT, N);
        else
            k_gather0<1><<<gridW, 256, 0, stream>>>(ptrI, srcC, wU, degU, B0,
                    cbs + i * 128, B1, eW, naW, epre, ntT, N);
    }

    // ---- attention: natt | eatt2 merged ----
    k_eattnatt<<<gridN + gridE, 256, 0, stream>>>(srcC, dstC, epre, ebv, wB0, wB1,
            degC0, degC1, ptrI, wU, degU, ntT, nab, natt, E, N, gridN);

    // ---- branch stats | branch weights merged ----
    k_stats2wB<<<256 + gridE, 256, 0, stream>>>(B1, natt, stZ + 1024, N,
            srcC, degC0, degC1, wB0, wB1, E);

    // ---- dual branch GEMM into B0c, then ONE branch-split gather ----
    k_gemm2<<<dim3(gridG, 2), 256, 0, stream>>>(B1, natt, stZ + 1024, whiT, wloT, B0c, N);
    k_gatherP2<<<2 * gridP, 256, 0, stream>>>(ptrI, srcC, wB0, wB1, degC0, degC1, B0c,
                                              xcb, xob, batch, xcp, xop, N, span);

    // ---- heads: 3 heads fused per stage ----
    k_gstats3<<<3, 1024, 0, stream>>>(xcp, xop, mrsH, G);
    k_hgemm3<<<dim3(G, 3), 128, 0, stream>>>(xcp, xop, mrsH, cW1, cb1, oW1, ob1,
                                             coW1, cob1, gt3);
    k_gstats3b<<<3, 1024, 0, stream>>>(gt3, mrsH2, G);
    k_hfinal3<<<dim3((G + 3) / 4, 3), 256, 0, stream>>>(gt3, mrsH2, cW2, cb2, oW2, ob2,
                                                        coW2, cob2, out, G);
}

// Round 7
// 574.783 us; speedup vs baseline: 1.7406x; 1.2543x over previous
//
#include <hip/hip_runtime.h>

// CausalGCN forward on MI355X. fp32 in/out; internal N x 128 tensors bf16.
// R14: random device atomics execute at L3 (~24/cy wall; prologue WRITE_SIZE
//      25.8MB = 800K x 32B partial lines). Cuts: rank-trick CSR fill (fill now
//      atomic-free), d1 derived from e0+e1=1 (eatt2 one atomic not two),
//      stats kernels vectorized (uint4/float4 + LDS slice reduce).

typedef unsigned short bf16_t;
typedef unsigned int   uint32;
typedef __attribute__((ext_vector_type(8))) short   bf16x8;
typedef __attribute__((ext_vector_type(4))) float   f32x4;

__device__ __forceinline__ float b2f(bf16_t v){ return __uint_as_float(((uint32)v) << 16); }
__device__ __forceinline__ bf16_t f2b(float f){
    uint32 u = __float_as_uint(f);
    return (bf16_t)((u + 0x7fffu + ((u >> 16) & 1u)) >> 16);   // RNE
}
__device__ __forceinline__ uint32 pack2(float lo, float hi){
    return (uint32)f2b(lo) | ((uint32)f2b(hi) << 16);
}
__device__ __forceinline__ float lo16(uint32 u){ return __uint_as_float(u << 16); }
__device__ __forceinline__ float hi16(uint32 u){ return __uint_as_float(u & 0xffff0000u); }
__device__ __forceinline__ int   rl (int v, int l){ return __builtin_amdgcn_readlane(v, l); }
__device__ __forceinline__ float rlf(float v, int l){
    return __int_as_float(__builtin_amdgcn_readlane(__float_as_int(v), l));
}

// ---------- prologue: wsplit (96 blocks) | hist2+rank (gridE) | statsF (256) ----------
__global__ void k_prologue(const float* __restrict__ Wf, const float* __restrict__ cWs,
        const float* __restrict__ xcW, const float* __restrict__ xoW,
        bf16_t* __restrict__ whiT, bf16_t* __restrict__ wloT,
        const int* __restrict__ esrc, const int* __restrict__ edst,
        int* __restrict__ cnt, float* __restrict__ degU, int* __restrict__ rankE, int e,
        const float* __restrict__ x, float* __restrict__ st, int n, int gridE)
{
    __shared__ float red[2][8][128];
    int bx = blockIdx.x, tid = threadIdx.x;
    if (bx < 96){
        // W pre-split: fp32 [k][n] -> bf16 hi/lo transposed [n][k], 6 matrices
        int mat = bx >> 4, sub = bx & 15;
        const float* src = (mat == 0) ? Wf : (mat <= 3) ? cWs + (size_t)(mat - 1) * 16384
                          : (mat == 4) ? xcW : xoW;
        int i = (sub * 256 + tid) * 4;
        int nrow = i >> 7, k0 = i & 127;
        size_t off = (size_t)mat * 16384 + (size_t)nrow * 128 + k0;
        #pragma unroll
        for (int j = 0; j < 4; ++j){
            float w = src[(size_t)(k0 + j) * 128 + nrow];
            bf16_t h = f2b(w);
            whiT[off + j] = h;
            wloT[off + j] = f2b(w - b2f(h));
        }
    } else if (bx < 96 + gridE){
        int i = (bx - 96) * 256 + tid;
        if (i < e){
            int r = atomicAdd(&cnt[edst[i]], 1);   // returns within-bin rank
            rankE[i] = r;
            atomicAdd(&degU[esrc[i]], 1.0f);
        }
    } else {
        int bb = bx - 96 - gridE;
        int f4 = (tid & 31) * 4, slice = tid >> 5;
        float s[4] = {0,0,0,0}, q[4] = {0,0,0,0};
        for (int row = bb * 8 + slice; row < n; row += 2048){
            float4 v = *(const float4*)&x[(size_t)row * 128 + f4];
            s[0]+=v.x; q[0]+=v.x*v.x; s[1]+=v.y; q[1]+=v.y*v.y;
            s[2]+=v.z; q[2]+=v.z*v.z; s[3]+=v.w; q[3]+=v.w*v.w;
        }
        #pragma unroll
        for (int j = 0; j < 4; ++j){ red[0][slice][f4+j]=s[j]; red[1][slice][f4+j]=q[j]; }
        __syncthreads();
        if (tid < 128){
            float ts=0.f, tq=0.f;
            #pragma unroll
            for (int w = 0; w < 8; ++w){ ts += red[0][w][tid]; tq += red[1][w][tid]; }
            atomicAdd(&st[tid], ts); atomicAdd(&st[128+tid], tq);
        }
    }
}

// ---------- BN stats: uint4 loads, LDS slice reduce ----------
__global__ __launch_bounds__(256) void k_statsB(const bf16_t* __restrict__ a,
        float* __restrict__ st, int n){
    __shared__ float red[2][16][128];
    int tid = threadIdx.x;
    int c8 = (tid & 15) * 8, slice = tid >> 4;
    float s[8] = {0,0,0,0,0,0,0,0}, q[8] = {0,0,0,0,0,0,0,0};
    for (int row = blockIdx.x * 16 + slice; row < n; row += 4096){
        uint4 v = *(const uint4*)&a[(size_t)row * 128 + c8];
        const bf16_t* pv = (const bf16_t*)&v;
        #pragma unroll
        for (int j = 0; j < 8; ++j){ float f = b2f(pv[j]); s[j] += f; q[j] += f * f; }
    }
    #pragma unroll
    for (int j = 0; j < 8; ++j){ red[0][slice][c8+j]=s[j]; red[1][slice][c8+j]=q[j]; }
    __syncthreads();
    if (tid < 128){
        float ts=0.f, tq=0.f;
        #pragma unroll
        for (int w = 0; w < 16; ++w){ ts += red[0][w][tid]; tq += red[1][w][tid]; }
        atomicAdd(&st[tid], ts); atomicAdd(&st[128+tid], tq);
    }
}

// ---------- MFMA GEMM: C[n, ccol0..+128 of ldc] = act( BN(scale*A) @ W ) ----------
template<int ACT, int INBF>  // ACT: 1=relu ; INBF: input bf16?
__global__ __launch_bounds__(256, 3) void k_gemm(const void* __restrict__ Av,
        const float* __restrict__ scale, int sch,
        const float* __restrict__ st, const bf16_t* __restrict__ WhiT,
        const bf16_t* __restrict__ WloT,
        bf16_t* __restrict__ C, int ldc, int ccol0, int n)
{
    __shared__ bf16_t As[64 * 136];
    __shared__ bf16_t Whi[128 * 72];
    __shared__ bf16_t Wlo[128 * 72];
    int tid = threadIdx.x;
    int wid = tid >> 6, lane = tid & 63;
    int row0 = blockIdx.x * 64;
    int m0 = wid * 16;
    int q8 = (lane >> 4) * 8, l15 = lane & 15;

    int c8t = (tid & 15) * 8;
    float sM[8], sR[8];
    #pragma unroll
    for (int j = 0; j < 8; ++j){
        float m = st[c8t + j] / n;
        float var = st[128 + c8t + j] / n - m * m;
        sM[j] = m; sR[j] = rsqrtf(var + 1e-5f);
    }

    for (int i = tid; i < 64 * 16; i += 256){
        int r = i >> 4, c8 = (i & 15) * 8;
        int gr = row0 + r;
        float v[8];
        if (gr < n){
            float sc = scale ? scale[(size_t)gr * 2 + sch] : 1.f;
            if (INBF){
                const bf16_t* Ab = (const bf16_t*)Av;
                ushort4 qa = *(const ushort4*)&Ab[(size_t)gr * 128 + c8];
                ushort4 qb = *(const ushort4*)&Ab[(size_t)gr * 128 + c8 + 4];
                v[0]=b2f(qa.x); v[1]=b2f(qa.y); v[2]=b2f(qa.z); v[3]=b2f(qa.w);
                v[4]=b2f(qb.x); v[5]=b2f(qb.y); v[6]=b2f(qb.z); v[7]=b2f(qb.w);
            } else {
                const float* Af = (const float*)Av;
                float4 fa = *(const float4*)&Af[(size_t)gr * 128 + c8];
                float4 fb = *(const float4*)&Af[(size_t)gr * 128 + c8 + 4];
                v[0]=fa.x; v[1]=fa.y; v[2]=fa.z; v[3]=fa.w;
                v[4]=fb.x; v[5]=fb.y; v[6]=fb.z; v[7]=fb.w;
            }
            #pragma unroll
            for (int j = 0; j < 8; ++j)
                v[j] = (v[j] * sc - sM[j]) * sR[j] + 1e-4f;
        } else {
            #pragma unroll
            for (int j = 0; j < 8; ++j) v[j] = 0.f;
        }
        #pragma unroll
        for (int j = 0; j < 8; ++j) As[r * 136 + c8 + j] = f2b(v[j]);
    }

    f32x4 acc[8];
    #pragma unroll
    for (int t = 0; t < 8; ++t) acc[t] = (f32x4){0.f, 0.f, 0.f, 0.f};

    for (int kc = 0; kc < 128; kc += 64){
        __syncthreads();
        for (int i = tid; i < 128 * 8; i += 256){
            int nrow = i >> 3, k8 = (i & 7) * 8;
            *(uint4*)&Whi[nrow * 72 + k8] = *(const uint4*)&WhiT[(size_t)nrow * 128 + kc + k8];
            *(uint4*)&Wlo[nrow * 72 + k8] = *(const uint4*)&WloT[(size_t)nrow * 128 + kc + k8];
        }
        __syncthreads();
        #pragma unroll
        for (int kbl = 0; kbl < 2; ++kbl){
            bf16x8 a = *(const bf16x8*)&As[(m0 + l15) * 136 + kc + kbl * 32 + q8];
            #pragma unroll
            for (int nt = 0; nt < 8; ++nt){
                bf16x8 bh = *(const bf16x8*)&Whi[(nt * 16 + l15) * 72 + kbl * 32 + q8];
                acc[nt] = __builtin_amdgcn_mfma_f32_16x16x32_bf16(a, bh, acc[nt], 0, 0, 0);
                bf16x8 bl = *(const bf16x8*)&Wlo[(nt * 16 + l15) * 72 + kbl * 32 + q8];
                acc[nt] = __builtin_amdgcn_mfma_f32_16x16x32_bf16(a, bl, acc[nt], 0, 0, 0);
            }
        }
    }

    __syncthreads();
    #pragma unroll
    for (int nt = 0; nt < 8; ++nt){
        #pragma unroll
        for (int r = 0; r < 4; ++r){
            float v = acc[nt][r];
            if (ACT == 1) v = fmaxf(v, 0.f);
            As[(m0 + (lane >> 4) * 4 + r) * 136 + nt * 16 + l15] = f2b(v);
        }
    }
    __syncthreads();
    for (int i = tid; i < 64 * 16; i += 256){
        int r = i >> 4, c8 = (i & 15) * 8;
        int gr = row0 + r;
        if (gr < n)
            *(uint4*)&C[(size_t)gr * ldc + ccol0 + c8] = *(const uint4*)&As[r * 136 + c8];
    }
}

// dual branch GEMM: blockIdx.y = branch (0:xc, 1:xo); input bf16, no act
__global__ __launch_bounds__(256, 3) void k_gemm2(const bf16_t* __restrict__ Ab,
        const float* __restrict__ natt, const float* __restrict__ stBase,
        const bf16_t* __restrict__ whiT6, const bf16_t* __restrict__ wloT6,
        bf16_t* __restrict__ C, int n)
{
    __shared__ bf16_t As[64 * 136];
    __shared__ bf16_t Whi[128 * 72];
    __shared__ bf16_t Wlo[128 * 72];
    int brn = blockIdx.y;
    const float* st = stBase + brn * 256;
    const bf16_t* WhiT = whiT6 + (size_t)(4 + brn) * 16384;
    const bf16_t* WloT = wloT6 + (size_t)(4 + brn) * 16384;
    int ccol0 = brn * 128;
    const int ldc = 256;

    int tid = threadIdx.x;
    int wid = tid >> 6, lane = tid & 63;
    int row0 = blockIdx.x * 64;
    int m0 = wid * 16;
    int q8 = (lane >> 4) * 8, l15 = lane & 15;

    int c8t = (tid & 15) * 8;
    float sM[8], sR[8];
    #pragma unroll
    for (int j = 0; j < 8; ++j){
        float m = st[c8t + j] / n;
        float var = st[128 + c8t + j] / n - m * m;
        sM[j] = m; sR[j] = rsqrtf(var + 1e-5f);
    }

    for (int i = tid; i < 64 * 16; i += 256){
        int r = i >> 4, c8 = (i & 15) * 8;
        int gr = row0 + r;
        float v[8];
        if (gr < n){
            float sc = natt[(size_t)gr * 2 + brn];
            ushort4 qa = *(const ushort4*)&Ab[(size_t)gr * 128 + c8];
            ushort4 qb = *(const ushort4*)&Ab[(size_t)gr * 128 + c8 + 4];
            v[0]=b2f(qa.x); v[1]=b2f(qa.y); v[2]=b2f(qa.z); v[3]=b2f(qa.w);
            v[4]=b2f(qb.x); v[5]=b2f(qb.y); v[6]=b2f(qb.z); v[7]=b2f(qb.w);
            #pragma unroll
            for (int j = 0; j < 8; ++j)
                v[j] = (v[j] * sc - sM[j]) * sR[j] + 1e-4f;
        } else {
            #pragma unroll
            for (int j = 0; j < 8; ++j) v[j] = 0.f;
        }
        #pragma unroll
        for (int j = 0; j < 8; ++j) As[r * 136 + c8 + j] = f2b(v[j]);
    }

    f32x4 acc[8];
    #pragma unroll
    for (int t = 0; t < 8; ++t) acc[t] = (f32x4){0.f, 0.f, 0.f, 0.f};

    for (int kc = 0; kc < 128; kc += 64){
        __syncthreads();
        for (int i = tid; i < 128 * 8; i += 256){
            int nrow = i >> 3, k8 = (i & 7) * 8;
            *(uint4*)&Whi[nrow * 72 + k8] = *(const uint4*)&WhiT[(size_t)nrow * 128 + kc + k8];
            *(uint4*)&Wlo[nrow * 72 + k8] = *(const uint4*)&WloT[(size_t)nrow * 128 + kc + k8];
        }
        __syncthreads();
        #pragma unroll
        for (int kbl = 0; kbl < 2; ++kbl){
            bf16x8 a = *(const bf16x8*)&As[(m0 + l15) * 136 + kc + kbl * 32 + q8];
            #pragma unroll
            for (int nt = 0; nt < 8; ++nt){
                bf16x8 bh = *(const bf16x8*)&Whi[(nt * 16 + l15) * 72 + kbl * 32 + q8];
                acc[nt] = __builtin_amdgcn_mfma_f32_16x16x32_bf16(a, bh, acc[nt], 0, 0, 0);
                bf16x8 bl = *(const bf16x8*)&Wlo[(nt * 16 + l15) * 72 + kbl * 32 + q8];
                acc[nt] = __builtin_amdgcn_mfma_f32_16x16x32_bf16(a, bl, acc[nt], 0, 0, 0);
            }
        }
    }

    __syncthreads();
    #pragma unroll
    for (int nt = 0; nt < 8; ++nt){
        #pragma unroll
        for (int r = 0; r < 4; ++r){
            As[(m0 + (lane >> 4) * 4 + r) * 136 + nt * 16 + l15] = f2b(acc[nt][r]);
        }
    }
    __syncthreads();
    for (int i = tid; i < 64 * 16; i += 256){
        int r = i >> 4, c8 = (i & 15) * 8;
        int gr = row0 + r;
        if (gr < n)
            *(uint4*)&C[(size_t)gr * ldc + ccol0 + c8] = *(const uint4*)&As[r * 136 + c8];
    }
}

// ---------- CSR scan ----------
__global__ __launch_bounds__(1024) void k_scanA(const int* __restrict__ cnt,
        int* __restrict__ ptr, int* __restrict__ bsum, int n){
    __shared__ int wsum[16];
    int t = threadIdx.x, lane = t & 63, wid = t >> 6;
    int i = blockIdx.x * 1024 + t;
    int v = (i < n) ? cnt[i] : 0;
    int s = v;
    for (int off = 1; off < 64; off <<= 1){
        int u = __shfl_up(s, off);
        if (lane >= off) s += u;
    }
    if (lane == 63) wsum[wid] = s;
    __syncthreads();
    if (wid == 0 && lane < 16){
        int ws = wsum[lane];
        for (int off = 1; off < 16; off <<= 1){
            int u = __shfl_up(ws, off);
            if (lane >= off) ws += u;
        }
        wsum[lane] = ws;
    }
    __syncthreads();
    int woff = wid ? wsum[wid - 1] : 0;
    if (i < n) ptr[i] = woff + s - v;
    if (t == 1023) bsum[blockIdx.x] = woff + s;
}
__global__ void k_scanB(int* __restrict__ bsum, int* __restrict__ ptrN, int nb){
    int lane = threadIdx.x;       // 64 threads
    int carry = 0;
    for (int base = 0; base < nb; base += 64){
        int i = base + lane;
        int v = (i < nb) ? bsum[i] : 0;
        int s = v;
        for (int off = 1; off < 64; off <<= 1){
            int u = __shfl_up(s, off);
            if (lane >= off) s += u;
        }
        if (i < nb) bsum[i] = carry + s - v;
        carry += __shfl(s, 63);
    }
    if (lane == 0) *ptrN = carry;
}
__global__ __launch_bounds__(1024) void k_scanC(int* __restrict__ ptr,
        const int* __restrict__ bsum, int n){
    int i = blockIdx.x * 1024 + threadIdx.x;
    if (i < n) ptr[i] += bsum[blockIdx.x];
}
// atomic-free CSR fill: slot = ptr[dst] + rank (rank from prologue's histogram)
__global__ void k_fill(const int* __restrict__ src, const int* __restrict__ dst,
                       const int* __restrict__ rankE, const int* __restrict__ ptr,
                       int* __restrict__ srcC, int* __restrict__ dstC,
                       const float* __restrict__ degU, float* __restrict__ wU, int e){
    int i = blockIdx.x * 256 + threadIdx.x;
    if (i < e){
        int s = src[i];
        int d = dst[i];
        int slot = ptr[d] + rankE[i];
        srcC[slot] = s;
        dstC[slot] = d;
        wU[slot] = rsqrtf(degU[s] + 1.0f);
    }
}

// ---------- conv propagate: readlane index broadcast; optional fused prep ----------
template<int PREP>
__global__ __launch_bounds__(256) void k_gather0(const int* __restrict__ ptr,
        const int* __restrict__ srcC, const float* __restrict__ wE,
        const float* __restrict__ degU, const bf16_t* __restrict__ t,
        const float* __restrict__ bias, bf16_t* __restrict__ outB,
        const float* __restrict__ eW, const float* __restrict__ naW,
        float4* __restrict__ epre, float* __restrict__ ntT, int n)
{
    int node = blockIdx.x * 4 + (threadIdx.x >> 6);
    if (node >= n) return;
    int lane = threadIdx.x & 63;
    const uint32* T = (const uint32*)t;
    float dd = rsqrtf(degU[node] + 1.0f);
    uint32 sv = T[(size_t)node * 64 + lane];
    float a0 = 0.f, a1 = 0.f;
    int k = ptr[node], end = ptr[node + 1];
    while (k < end){
        int cnt = min(end - k, 64);
        int kl = k + min(lane, cnt - 1);
        int   myI = srcC[kl];
        float myW = wE[kl];
        int j = 0;
        for (; j + 8 <= cnt; j += 8){
            int s0 = rl(myI, j),     s1 = rl(myI, j + 1), s2 = rl(myI, j + 2), s3 = rl(myI, j + 3);
            int s4 = rl(myI, j + 4), s5 = rl(myI, j + 5), s6 = rl(myI, j + 6), s7 = rl(myI, j + 7);
            float w0 = rlf(myW, j),     w1 = rlf(myW, j + 1), w2 = rlf(myW, j + 2), w3 = rlf(myW, j + 3);
            float w4 = rlf(myW, j + 4), w5 = rlf(myW, j + 5), w6 = rlf(myW, j + 6), w7 = rlf(myW, j + 7);
            uint32 v0 = T[(size_t)s0 * 64 + lane];
            uint32 v1 = T[(size_t)s1 * 64 + lane];
            uint32 v2 = T[(size_t)s2 * 64 + lane];
            uint32 v3 = T[(size_t)s3 * 64 + lane];
            uint32 v4 = T[(size_t)s4 * 64 + lane];
            uint32 v5 = T[(size_t)s5 * 64 + lane];
            uint32 v6 = T[(size_t)s6 * 64 + lane];
            uint32 v7 = T[(size_t)s7 * 64 + lane];
            a0 += w0 * lo16(v0) + w1 * lo16(v1) + w2 * lo16(v2) + w3 * lo16(v3);
            a1 += w0 * hi16(v0) + w1 * hi16(v1) + w2 * hi16(v2) + w3 * hi16(v3);
            a0 += w4 * lo16(v4) + w5 * lo16(v5) + w6 * lo16(v6) + w7 * lo16(v7);
            a1 += w4 * hi16(v4) + w5 * hi16(v5) + w6 * hi16(v6) + w7 * hi16(v7);
        }
        for (; j < cnt; ++j){
            int s = rl(myI, j);
            float w = rlf(myW, j);
            uint32 v = T[(size_t)s * 64 + lane];
            a0 += w * lo16(v); a1 += w * hi16(v);
        }
        k += cnt;
    }
    a0 = fmaxf(dd * (a0 + dd * lo16(sv)) + bias[2 * lane],     0.f);
    a1 = fmaxf(dd * (a1 + dd * hi16(sv)) + bias[2 * lane + 1], 0.f);
    ((uint32*)outB)[(size_t)node * 64 + lane] = pack2(a0, a1);
    if (PREP){
        // lane holds feats (2*lane, 2*lane+1) = (a0, a1).
        // eW row f at float offset 2f; dst-half rows 128+f at 256+2f.
        float s0 = a0 * eW[4 * lane]           + a1 * eW[4 * lane + 2];
        float s1 = a0 * eW[4 * lane + 1]       + a1 * eW[4 * lane + 3];
        float d0 = a0 * eW[256 + 4 * lane]     + a1 * eW[256 + 4 * lane + 2];
        float d1 = a0 * eW[256 + 4 * lane + 1] + a1 * eW[256 + 4 * lane + 3];
        float n0 = a0 * naW[4 * lane]          + a1 * naW[4 * lane + 2];
        float n1 = a0 * naW[4 * lane + 1]      + a1 * naW[4 * lane + 3];
        for (int off = 32; off; off >>= 1){
            s0 += __shfl_xor(s0, off); s1 += __shfl_xor(s1, off);
            d0 += __shfl_xor(d0, off); d1 += __shfl_xor(d1, off);
            n0 += __shfl_xor(n0, off); n1 += __shfl_xor(n1, off);
        }
        if (lane == 0){
            epre[node] = make_float4(s0, s1, d0, d1);
            ntT[2 * node] = n0; ntT[2 * node + 1] = n1;
        }
    }
}

// ---------- branch propagate; degC1 derived as degU - degC0 ----------
__global__ __launch_bounds__(256) void k_gatherP2(const int* __restrict__ ptr,
        const int* __restrict__ srcC, const float* __restrict__ w0E,
        const float* __restrict__ w1E, const float* __restrict__ degC0,
        const float* __restrict__ degU, const bf16_t* __restrict__ t,
        const float* __restrict__ biasC, const float* __restrict__ biasO,
        const int* __restrict__ batch, float* __restrict__ pool0,
        float* __restrict__ pool1, int n, int span)
{
    int br   = blockIdx.x & 1;
    int wave = (blockIdx.x >> 1) * 4 + (threadIdx.x >> 6);
    int lane = threadIdx.x & 63;
    int nbeg = wave * span;
    if (nbeg >= n) return;
    int nend = min(n, nbeg + span);
    const float* wE   = br ? w1E : w0E;
    const float* bias = br ? biasO : biasC;
    float* pool       = br ? pool1 : pool0;
    float b0 = bias[2 * lane], b1 = bias[2 * lane + 1];
    const uint32* T = (const uint32*)t;       // B0c row = 128 uint32
    int rowoff = (br ? 64 : 0) + lane;
    int curG = -1;
    float p0 = 0.f, p1 = 0.f;
    for (int node = nbeg; node < nend; ++node){
        float d0v = degC0[node];
        float dv  = br ? (degU[node] - d0v) : d0v;
        float dd  = rsqrtf(dv + 1.0f);
        uint32 sv = T[(size_t)node * 128 + rowoff];
        float a0 = 0.f, a1 = 0.f;
        int k = ptr[node], end = ptr[node + 1];
        while (k < end){
            int cnt = min(end - k, 64);
            int kl = k + min(lane, cnt - 1);
            int   myI = srcC[kl];
            float myW = wE[kl];
            int j = 0;
            for (; j + 8 <= cnt; j += 8){
                int s0 = rl(myI, j),     s1 = rl(myI, j + 1), s2 = rl(myI, j + 2), s3 = rl(myI, j + 3);
                int s4 = rl(myI, j + 4), s5 = rl(myI, j + 5), s6 = rl(myI, j + 6), s7 = rl(myI, j + 7);
                float w0 = rlf(myW, j),     w1 = rlf(myW, j + 1), w2 = rlf(myW, j + 2), w3 = rlf(myW, j + 3);
                float w4 = rlf(myW, j + 4), w5 = rlf(myW, j + 5), w6 = rlf(myW, j + 6), w7 = rlf(myW, j + 7);
                uint32 v0 = T[(size_t)s0 * 128 + rowoff];
                uint32 v1 = T[(size_t)s1 * 128 + rowoff];
                uint32 v2 = T[(size_t)s2 * 128 + rowoff];
                uint32 v3 = T[(size_t)s3 * 128 + rowoff];
                uint32 v4 = T[(size_t)s4 * 128 + rowoff];
                uint32 v5 = T[(size_t)s5 * 128 + rowoff];
                uint32 v6 = T[(size_t)s6 * 128 + rowoff];
                uint32 v7 = T[(size_t)s7 * 128 + rowoff];
                a0 += w0 * lo16(v0) + w1 * lo16(v1) + w2 * lo16(v2) + w3 * lo16(v3);
                a1 += w0 * hi16(v0) + w1 * hi16(v1) + w2 * hi16(v2) + w3 * hi16(v3);
                a0 += w4 * lo16(v4) + w5 * lo16(v5) + w6 * lo16(v6) + w7 * lo16(v7);
                a1 += w4 * hi16(v4) + w5 * hi16(v5) + w6 * hi16(v6) + w7 * hi16(v7);
            }
            for (; j < cnt; ++j){
                int s = rl(myI, j);
                float w = rlf(myW, j);
                uint32 v = T[(size_t)s * 128 + rowoff];
                a0 += w * lo16(v); a1 += w * hi16(v);
            }
            k += cnt;
        }
        a0 = dd * (a0 + dd * lo16(sv)) + b0;
        a1 = dd * (a1 + dd * hi16(sv)) + b1;
        a0 = a0 > 0.f ? a0 : expm1f(a0);
        a1 = a1 > 0.f ? a1 : expm1f(a1);
        int g = batch[node];
        if (g != curG){
            if (curG >= 0){
                float* p = pool + (size_t)curG * 128 + 2 * lane;
                atomicAdd(&p[0], p0); atomicAdd(&p[1], p1);
            }
            curG = g; p0 = a0; p1 = a1;
        } else {
            p0 += a0; p1 += a1;
        }
    }
    if (curG >= 0){
        float* p = pool + (size_t)curG * 128 + 2 * lane;
        atomicAdd(&p[0], p0); atomicAdd(&p[1], p1);
    }
}

// ---------- attention: natt (gridN blocks) | eatt2 (gridE blocks); d0 only ----------
__global__ void k_eattnatt(const int* __restrict__ srcC, const int* __restrict__ dstC,
        const float4* __restrict__ epre, const float* __restrict__ eb,
        float* __restrict__ wB0, float* __restrict__ wB1,
        float* __restrict__ d0,
        const int* __restrict__ ptr, const float* __restrict__ wU,
        const float* __restrict__ degU, const float* __restrict__ ntT,
        const float* __restrict__ nab, float* __restrict__ natt,
        int e, int n, int gridN)
{
    int bx = blockIdx.x;
    if (bx < gridN){
        int i = bx * 256 + threadIdx.x;
        if (i >= n) return;
        float dd = rsqrtf(degU[i] + 1.0f);
        float z0 = 0.f, z1 = 0.f;
        int end = ptr[i + 1];
        for (int k = ptr[i]; k < end; ++k){
            int s = srcC[k];
            float w = wU[k];
            z0 += w * ntT[2 * s]; z1 += w * ntT[2 * s + 1];
        }
        z0 = dd * (z0 + dd * ntT[2 * i])     + nab[0];
        z1 = dd * (z1 + dd * ntT[2 * i + 1]) + nab[1];
        float m = fmaxf(z0, z1);
        float e0 = expf(z0 - m), e1 = expf(z1 - m);
        float inv = 1.f / (e0 + e1);
        natt[2 * i] = e0 * inv; natt[2 * i + 1] = e1 * inv;
    } else {
        int i = (bx - gridN) * 256 + threadIdx.x;
        if (i >= e) return;
        int s = srcC[i];
        float4 ps = epre[s], pd = epre[dstC[i]];
        float l0 = ps.x + pd.z + eb[0], l1 = ps.y + pd.w + eb[1];
        float m = fmaxf(l0, l1);
        float e0 = expf(l0 - m), e1 = expf(l1 - m);
        float inv = 1.f / (e0 + e1);
        e0 *= inv; e1 *= inv;
        wB0[i] = e0; wB1[i] = e1;
        atomicAdd(&d0[s], e0);      // d1 derived: degC1 = degU - degC0
    }
}

// ---------- stats2 (256 blocks, vectorized) | wB (gridE blocks) ----------
__global__ void k_stats2wB(const bf16_t* __restrict__ a, const float* __restrict__ natt,
        float* __restrict__ st, int n,
        const int* __restrict__ srcC, const float* __restrict__ degC0,
        const float* __restrict__ degU, float* __restrict__ w0,
        float* __restrict__ w1, int e)
{
    __shared__ float red[2][16][128];
    int bx = blockIdx.x, tid = threadIdx.x;
    if (bx < 256){
        int c8 = (tid & 15) * 8, slice = tid >> 4;
        float s0[8]={0,0,0,0,0,0,0,0}, q0[8]={0,0,0,0,0,0,0,0};
        float s1[8]={0,0,0,0,0,0,0,0}, q1[8]={0,0,0,0,0,0,0,0};
        for (int row = bx * 16 + slice; row < n; row += 4096){
            uint4 v = *(const uint4*)&a[(size_t)row * 128 + c8];
            const bf16_t* pv = (const bf16_t*)&v;
            float2 w = *(const float2*)&natt[(size_t)row * 2];
            #pragma unroll
            for (int j = 0; j < 8; ++j){
                float f = b2f(pv[j]);
                float f0 = f * w.x, f1 = f * w.y;
                s0[j] += f0; q0[j] += f0 * f0;
                s1[j] += f1; q1[j] += f1 * f1;
            }
        }
        #pragma unroll
        for (int j = 0; j < 8; ++j){ red[0][slice][c8+j]=s0[j]; red[1][slice][c8+j]=q0[j]; }
        __syncthreads();
        if (tid < 128){
            float ts=0.f, tq=0.f;
            #pragma unroll
            for (int w = 0; w < 16; ++w){ ts += red[0][w][tid]; tq += red[1][w][tid]; }
            atomicAdd(&st[tid], ts); atomicAdd(&st[128+tid], tq);
        }
        __syncthreads();
        #pragma unroll
        for (int j = 0; j < 8; ++j){ red[0][slice][c8+j]=s1[j]; red[1][slice][c8+j]=q1[j]; }
        __syncthreads();
        if (tid < 128){
            float ts=0.f, tq=0.f;
            #pragma unroll
            for (int w = 0; w < 16; ++w){ ts += red[0][w][tid]; tq += red[1][w][tid]; }
            atomicAdd(&st[256+tid], ts); atomicAdd(&st[384+tid], tq);
        }
    } else {
        int i = (bx - 256) * 256 + tid;
        if (i < e){
            int s = srcC[i];
            float d0v = degC0[s];
            w0[i] *= rsqrtf(d0v + 1.0f);
            w1[i] *= rsqrtf(degU[s] - d0v + 1.0f);
        }
    }
}

// ---------- heads (G=512, fp32), 3 heads fused per stage ----------
__global__ __launch_bounds__(1024) void k_gstats3(const float* __restrict__ xcp,
        const float* __restrict__ xop, float* __restrict__ mrsH, int n){
    __shared__ float red[2][1024];
    int head = blockIdx.x;
    const float* a = (head == 1) ? xop : xcp;
    const float* b = (head == 0) ? xcp : xop;
    int f = (head == 2) ? 256 : 128;
    float* mrs = mrsH + head * 512;
    int col = threadIdx.x & (f - 1);
    int rpb = 1024 / f;
    int rw  = threadIdx.x / f;
    float s = 0.f, sq = 0.f;
    for (int r = rw; r < n; r += rpb){
        float v = (col < 128) ? a[(size_t)r * 128 + col] : b[(size_t)r * 128 + col - 128];
        s += v; sq += v * v;
    }
    red[0][threadIdx.x] = s; red[1][threadIdx.x] = sq;
    __syncthreads();
    if (threadIdx.x < (unsigned)f){
        float ts = 0.f, tq = 0.f;
        for (int w = 0; w < rpb; ++w){ ts += red[0][w * f + col]; tq += red[1][w * f + col]; }
        float m = ts / n, var = tq / n - m * m;
        mrs[col] = m; mrs[f + col] = rsqrtf(var + 1e-5f);
    }
}
__global__ __launch_bounds__(128) void k_hgemm3(const float* __restrict__ xcp,
        const float* __restrict__ xop, const float* __restrict__ mrsH,
        const float* __restrict__ cW1, const float* __restrict__ cb1,
        const float* __restrict__ oW1, const float* __restrict__ ob1,
        const float* __restrict__ coW1, const float* __restrict__ cob1,
        float* __restrict__ gt3)
{
    __shared__ float as[256];
    int head = blockIdx.y, row = blockIdx.x, tid = threadIdx.x;
    const float* a  = (head == 1) ? xop : xcp;
    const float* b2 = (head == 0) ? xcp : xop;
    int fin = (head == 2) ? 256 : 128;
    const float* mrs = mrsH + head * 512;
    const float* W  = (head == 0) ? cW1 : (head == 1) ? oW1 : coW1;
    const float* bb = (head == 0) ? cb1 : (head == 1) ? ob1 : cob1;
    float* o = gt3 + (size_t)head * 512 * 128;
    for (int i = tid; i < fin; i += 128){
        float v = (i < 128) ? a[(size_t)row * 128 + i] : b2[(size_t)row * 128 + i - 128];
        as[i] = (v - mrs[i]) * mrs[fin + i] + 1e-4f;
    }
    __syncthreads();
    float s = 0.f;
    for (int k = 0; k < fin; ++k) s += as[k] * W[k * 128 + tid];
    s += bb[tid];
    if (head < 2) s = fmaxf(s, 0.f);
    else { s = s > 0.f ? s : expm1f(s); s = s > 0.f ? s : expm1f(s); }
    o[(size_t)row * 128 + tid] = s;
}
__global__ __launch_bounds__(1024) void k_gstats3b(const float* __restrict__ gt3,
        float* __restrict__ mrsH2, int n){
    __shared__ float red[2][1024];
    int head = blockIdx.x;
    const float* a = gt3 + (size_t)head * 512 * 128;
    float* mrs = mrsH2 + head * 256;
    int col = threadIdx.x & 127;
    int rw  = threadIdx.x >> 7;    // 8 rows/block-pass
    float s = 0.f, sq = 0.f;
    for (int r = rw; r < n; r += 8){
        float v = a[(size_t)r * 128 + col];
        s += v; sq += v * v;
    }
    red[0][threadIdx.x] = s; red[1][threadIdx.x] = sq;
    __syncthreads();
    if (threadIdx.x < 128u){
        float ts = 0.f, tq = 0.f;
        for (int w = 0; w < 8; ++w){ ts += red[0][w * 128 + col]; tq += red[1][w * 128 + col]; }
        float m = ts / n, var = tq / n - m * m;
        mrs[col] = m; mrs[128 + col] = rsqrtf(var + 1e-5f);
    }
}
__global__ __launch_bounds__(256) void k_hfinal3(const float* __restrict__ gt3,
        const float* __restrict__ mrsH2,
        const float* __restrict__ cW2, const float* __restrict__ cb2,
        const float* __restrict__ oW2, const float* __restrict__ ob2,
        const float* __restrict__ coW2, const float* __restrict__ cob2,
        float* __restrict__ out, int nrows)
{
    int head = blockIdx.y;
    int row = blockIdx.x * 4 + (threadIdx.x >> 6);
    if (row >= nrows) return;
    int lane = threadIdx.x & 63;
    const float* a   = gt3 + (size_t)head * 512 * 128;
    const float* mrs = mrsH2 + head * 256;
    const float* W = (head == 0) ? cW2 : (head == 1) ? oW2 : coW2;
    const float* b = (head == 0) ? cb2 : (head == 1) ? ob2 : cob2;
    float* o = out + (size_t)head * nrows * 10;
    float v0 = (a[(size_t)row * 128 + lane]      - mrs[lane])      * mrs[128 + lane]      + 1e-4f;
    float v1 = (a[(size_t)row * 128 + 64 + lane] - mrs[64 + lane]) * mrs[128 + 64 + lane] + 1e-4f;
    float logit[10];
    #pragma unroll
    for (int c = 0; c < 10; ++c){
        float p = v0 * W[lane * 10 + c] + v1 * W[(lane + 64) * 10 + c];
        for (int off = 32; off; off >>= 1) p += __shfl_xor(p, off);
        logit[c] = p + b[c];
    }
    float m = logit[0];
    #pragma unroll
    for (int c = 1; c < 10; ++c) m = fmaxf(m, logit[c]);
    float s = 0.f;
    #pragma unroll
    for (int c = 0; c < 10; ++c) s += expf(logit[c] - m);
    float lse = logf(s);
    if (lane < 10) o[row * 10 + lane] = logit[lane] - m - lse;
}

extern "C" void kernel_launch(void* const* d_in, const int* in_sizes, int n_in,
                              void* d_out, int out_size, void* d_ws, size_t ws_size,
                              hipStream_t stream)
{
    const int N = in_sizes[0] / 128;
    const int E = in_sizes[24];
    const int G = 512;
    const float* x    = (const float*)d_in[0];
    const float* Wf   = (const float*)d_in[1];
    const float* cWs  = (const float*)d_in[2];
    const float* cbs  = (const float*)d_in[3];
    const float* eW   = (const float*)d_in[4];
    const float* ebv  = (const float*)d_in[5];
    const float* naW  = (const float*)d_in[6];
    const float* nab  = (const float*)d_in[7];
    const float* xcW  = (const float*)d_in[8];
    const float* xcb  = (const float*)d_in[9];
    const float* xoW  = (const float*)d_in[10];
    const float* xob  = (const float*)d_in[11];
    const float* cW1  = (const float*)d_in[12];
    const float* cb1  = (const float*)d_in[13];
    const float* cW2  = (const float*)d_in[14];
    const float* cb2  = (const float*)d_in[15];
    const float* oW1  = (const float*)d_in[16];
    const float* ob1  = (const float*)d_in[17];
    const float* oW2  = (const float*)d_in[18];
    const float* ob2  = (const float*)d_in[19];
    const float* coW1 = (const float*)d_in[20];
    const float* cob1 = (const float*)d_in[21];
    const float* coW2 = (const float*)d_in[22];
    const float* cob2 = (const float*)d_in[23];
    const int* esrc  = (const int*)d_in[24];
    const int* edst  = (const int*)d_in[25];
    const int* batch = (const int*)d_in[26];
    float* out = (float*)d_out;

    size_t NH = (size_t)N * 128;
    bf16_t* B1  = (bf16_t*)d_ws;            // N*128
    bf16_t* B0  = B1 + NH;                  // N*128
    bf16_t* B0c = B0 + NH;                  // N*256 ([xc|xo])
    float* fbase = (float*)(B0c + 2 * NH);
    float* epreF = fbase;                   // 4N
    float* ntT   = epreF + 4 * (size_t)N;
    float* natt  = ntT + 2 * (size_t)N;
    float* mrsH  = natt + 2 * (size_t)N;    // 1536 (3 heads x 512)
    float* mrsH2 = mrsH + 1536;             // 768  (3 heads x 256)
    float* wU    = mrsH2 + 768;             // E (CSR order)
    float* wB0   = wU + E;                  // E
    float* wB1   = wB0 + E;                 // E
    float* gt3   = wB1 + E;                 // 3*G*128
    // zero zone (single memset)
    float* zz    = gt3 + (size_t)3 * G * 128;
    float* degU  = zz;                      // N
    float* degC0 = degU + N;                // N
    float* degC1 = degC0 + N;               // N (unused; kept for layout stability)
    float* stZ   = degC1 + N;               // 1536
    float* xcp   = stZ + 1536;              // G*128
    float* xop   = xcp + (size_t)G * 128;   // G*128
    int*   cntI  = (int*)(xop + (size_t)G * 128);   // N (zeroed: part of zz span)
    size_t zzBytes = ((size_t)(4 * N) + 1536 + 2 * (size_t)G * 128) * 4;
    int* ptrI   = cntI + N;                 // N+1
    int* srcC   = ptrI + N + 1;             // E
    int* dstC   = srcC + E;                 // E
    int* bsum   = dstC + E;                 // up to 64
    int* rankE  = bsum + 64;                // E
    bf16_t* whiT = (bf16_t*)((((size_t)(rankE + E)) + 15) & ~(size_t)15);  // 6*16384
    bf16_t* wloT = whiT + 6 * 16384;                                       // 6*16384
    float4* epre = (float4*)epreF;

    int gridE = (E + 255) / 256;
    int gridN = (N + 255) / 256;
    int gridW = (N + 3) / 4;
    int gridG = (N + 63) / 64;
    int nb    = (N + 1023) / 1024;
    int span  = (N + 16383) / 16384;
    int gridP = (N + span * 4 - 1) / (span * 4);

    hipMemsetAsync(zz, 0, zzBytes, stream);

    // ---- prologue: wsplit | hist2+rank | statsF ----
    k_prologue<<<96 + gridE + 256, 256, 0, stream>>>(Wf, cWs, xcW, xoW, whiT, wloT,
            esrc, edst, cntI, degU, rankE, E, x, stZ, N, gridE);

    // ---- CSR scan + atomic-free fill ----
    k_scanA<<<nb, 1024, 0, stream>>>(cntI, ptrI, bsum, N);
    k_scanB<<<1, 64, 0, stream>>>(bsum, ptrI + N, nb);
    k_scanC<<<nb, 1024, 0, stream>>>(ptrI, bsum, N);
    k_fill<<<gridE, 256, 0, stream>>>(esrc, edst, rankE, ptrI, srcC, dstC, degU, wU, E);

    // ---- h = relu(BN(x) @ W_feat) -> B1 (bf16) ----
    k_gemm<1, 0><<<gridG, 256, 0, stream>>>(x, nullptr, 0, stZ, whiT, wloT, B1, 128, 0, N);

    // ---- 3 x [BN -> GCNConv -> relu], prep fused into last gather ----
    for (int i = 0; i < 3; ++i){
        float* st = stZ + 256 * (i + 1);
        k_statsB<<<256, 256, 0, stream>>>(B1, st, N);
        k_gemm<0, 1><<<gridG, 256, 0, stream>>>(B1, nullptr, 0, st,
                whiT + (size_t)(i + 1) * 16384, wloT + (size_t)(i + 1) * 16384,
                B0, 128, 0, N);
        if (i < 2)
            k_gather0<0><<<gridW, 256, 0, stream>>>(ptrI, srcC, wU, degU, B0,
                    cbs + i * 128, B1, eW, naW, epre, ntT, N);
        else
            k_gather0<1><<<gridW, 256, 0, stream>>>(ptrI, srcC, wU, degU, B0,
                    cbs + i * 128, B1, eW, naW, epre, ntT, N);
    }

    // ---- attention: natt | eatt2 merged (d0 only) ----
    k_eattnatt<<<gridN + gridE, 256, 0, stream>>>(srcC, dstC, epre, ebv, wB0, wB1,
            degC0, ptrI, wU, degU, ntT, nab, natt, E, N, gridN);

    // ---- branch stats (vectorized) | branch weights merged ----
    k_stats2wB<<<256 + gridE, 256, 0, stream>>>(B1, natt, stZ + 1024, N,
            srcC, degC0, degU, wB0, wB1, E);

    // ---- dual branch GEMM into B0c, then ONE branch-split gather ----
    k_gemm2<<<dim3(gridG, 2), 256, 0, stream>>>(B1, natt, stZ + 1024, whiT, wloT, B0c, N);
    k_gatherP2<<<2 * gridP, 256, 0, stream>>>(ptrI, srcC, wB0, wB1, degC0, degU, B0c,
                                              xcb, xob, batch, xcp, xop, N, span);

    // ---- heads: 3 heads fused per stage ----
    k_gstats3<<<3, 1024, 0, stream>>>(xcp, xop, mrsH, G);
    k_hgemm3<<<dim3(G, 3), 128, 0, stream>>>(xcp, xop, mrsH, cW1, cb1, oW1, ob1,
                                             coW1, cob1, gt3);
    k_gstats3b<<<3, 1024, 0, stream>>>(gt3, mrsH2, G);
    k_hfinal3<<<dim3((G + 3) / 4, 3), 256, 0, stream>>>(gt3, mrsH2, cW2, cb2, oW2, ob2,
                                                        coW2, cob2, out, G);
}

// Round 8
// 558.392 us; speedup vs baseline: 1.7916x; 1.0294x over previous
//
#include <hip/hip_runtime.h>

// CausalGCN forward on MI355X. fp32 in/out; internal N x 128 tensors bf16.
// R15: zero bulk global atomics. LDS-chunked histogram (64 edge-chunks x 2 bin
//      halves x {dst,src}; packed uint16 counts, LDS-atomic rank), joint 2N scan
//      -> dst-CSR + src-CSR, atomic-free fill, degC0 recomputed over src-CSR in
//      eattnatt (d0 atomic gone), degU from src histogram.

typedef unsigned short bf16_t;
typedef unsigned int   uint32;
typedef __attribute__((ext_vector_type(8))) short   bf16x8;
typedef __attribute__((ext_vector_type(4))) float   f32x4;

#define CHNK 64

__device__ __forceinline__ float b2f(bf16_t v){ return __uint_as_float(((uint32)v) << 16); }
__device__ __forceinline__ bf16_t f2b(float f){
    uint32 u = __float_as_uint(f);
    return (bf16_t)((u + 0x7fffu + ((u >> 16) & 1u)) >> 16);   // RNE
}
__device__ __forceinline__ uint32 pack2(float lo, float hi){
    return (uint32)f2b(lo) | ((uint32)f2b(hi) << 16);
}
__device__ __forceinline__ float lo16(uint32 u){ return __uint_as_float(u << 16); }
__device__ __forceinline__ float hi16(uint32 u){ return __uint_as_float(u & 0xffff0000u); }
__device__ __forceinline__ int   rl (int v, int l){ return __builtin_amdgcn_readlane(v, l); }
__device__ __forceinline__ float rlf(float v, int l){
    return __int_as_float(__builtin_amdgcn_readlane(__float_as_int(v), l));
}

// ---------- prologue: hist (256 blocks) | wsplit (96) | statsF (256) ----------
// hist: block (side, chunk, half) counts its bin-half into LDS packed-uint16,
// LDS-atomic return = local rank. 50KB LDS (N <= 50176).
__global__ void k_prologue(const float* __restrict__ Wf, const float* __restrict__ cWs,
        const float* __restrict__ xcW, const float* __restrict__ xoW,
        bf16_t* __restrict__ whiT, bf16_t* __restrict__ wloT,
        const int* __restrict__ esrc, const int* __restrict__ edst,
        uint32* __restrict__ cntD16, uint32* __restrict__ cntS16,
        int* __restrict__ rankE, int* __restrict__ rankS, int e,
        const float* __restrict__ x, float* __restrict__ st, int n, int WD)
{
    __shared__ uint32 h[12544];     // 50,176 B
    int bx = blockIdx.x, tid = threadIdx.x;
    if (bx < 256){
        int side = bx >> 7;          // 0: dst hist, 1: src hist
        int sub = bx & 127;
        int c = sub >> 1, hh = sub & 1;
        int Nh = ((n + 3) / 4) * 2;  // even split point
        int lo = hh ? Nh : 0;
        int hi = hh ? n : Nh;
        int w0 = lo >> 1;
        int nw = (hi - lo + 1) >> 1;
        for (int j = tid; j < nw; j += 256) h[j] = 0;
        __syncthreads();
        int EC = (e + CHNK - 1) / CHNK;
        int beg = c * EC, endE = min(e, beg + EC);
        const int* keys = side ? esrc : edst;
        int* rank = side ? rankS : rankE;
        for (int i = beg + tid; i < endE; i += 256){
            int d = keys[i];
            if (d >= lo && d < hi){
                int w = (d >> 1) - w0;
                int sh = (d & 1) * 16;
                uint32 old = atomicAdd(&h[w], 1u << sh);
                rank[i] = (int)((old >> sh) & 0xffffu);
            }
        }
        __syncthreads();
        uint32* table = side ? cntS16 : cntD16;
        for (int j = tid; j < nw; j += 256)
            table[(size_t)c * WD + w0 + j] = h[j];
    } else if (bx < 352){
        // W pre-split: fp32 [k][n] -> bf16 hi/lo transposed [n][k], 6 matrices
        int ms = bx - 256;
        int mat = ms >> 4, sub = ms & 15;
        const float* src = (mat == 0) ? Wf : (mat <= 3) ? cWs + (size_t)(mat - 1) * 16384
                          : (mat == 4) ? xcW : xoW;
        int i = (sub * 256 + tid) * 4;
        int nrow = i >> 7, k0 = i & 127;
        size_t off = (size_t)mat * 16384 + (size_t)nrow * 128 + k0;
        #pragma unroll
        for (int j = 0; j < 4; ++j){
            float w = src[(size_t)(k0 + j) * 128 + nrow];
            bf16_t hb = f2b(w);
            whiT[off + j] = hb;
            wloT[off + j] = f2b(w - b2f(hb));
        }
    } else {
        int bb = bx - 352;
        float* red = (float*)h;      // overlay: [2][8][128]
        int f4 = (tid & 31) * 4, slice = tid >> 5;
        float s[4] = {0,0,0,0}, q[4] = {0,0,0,0};
        for (int row = bb * 8 + slice; row < n; row += 2048){
            float4 v = *(const float4*)&x[(size_t)row * 128 + f4];
            s[0]+=v.x; q[0]+=v.x*v.x; s[1]+=v.y; q[1]+=v.y*v.y;
            s[2]+=v.z; q[2]+=v.z*v.z; s[3]+=v.w; q[3]+=v.w*v.w;
        }
        #pragma unroll
        for (int j = 0; j < 4; ++j){
            red[slice * 128 + f4 + j] = s[j];
            red[1024 + slice * 128 + f4 + j] = q[j];
        }
        __syncthreads();
        if (tid < 128){
            float ts=0.f, tq=0.f;
            #pragma unroll
            for (int w = 0; w < 8; ++w){ ts += red[w*128+tid]; tq += red[1024+w*128+tid]; }
            atomicAdd(&st[tid], ts); atomicAdd(&st[128+tid], tq);
        }
    }
}

// ---------- chunk-offset scan: per-bin exclusive prefix over chunks, totals out ----------
__global__ void k_chunkscan(uint32* __restrict__ cntD16, uint32* __restrict__ cntS16,
        int* __restrict__ cntI, float* __restrict__ degUf, int WD, int n)
{
    int g = blockIdx.x * 256 + threadIdx.x;
    if (g >= 2 * WD) return;
    int side = (g >= WD);
    int w = side ? g - WD : g;
    uint32* tab = side ? cntS16 : cntD16;
    uint32 r0 = 0, r1 = 0;
    for (int c = 0; c < CHNK; ++c){
        size_t idx = (size_t)c * WD + w;
        uint32 v = tab[idx];
        tab[idx] = r0 | (r1 << 16);
        r0 += v & 0xffffu; r1 += v >> 16;
    }
    int b0 = 2 * w, b1 = 2 * w + 1;
    if (!side){
        if (b0 < n) cntI[b0] = (int)r0;
        if (b1 < n) cntI[b1] = (int)r1;
    } else {
        if (b0 < n){ cntI[n + b0] = (int)r0; degUf[b0] = (float)r0; }
        if (b1 < n){ cntI[n + b1] = (int)r1; degUf[b1] = (float)r1; }
    }
}

// ---------- BN stats: uint4 loads, LDS slice reduce ----------
__global__ __launch_bounds__(256) void k_statsB(const bf16_t* __restrict__ a,
        float* __restrict__ st, int n){
    __shared__ float red[2][16][128];
    int tid = threadIdx.x;
    int c8 = (tid & 15) * 8, slice = tid >> 4;
    float s[8] = {0,0,0,0,0,0,0,0}, q[8] = {0,0,0,0,0,0,0,0};
    for (int row = blockIdx.x * 16 + slice; row < n; row += 4096){
        uint4 v = *(const uint4*)&a[(size_t)row * 128 + c8];
        const bf16_t* pv = (const bf16_t*)&v;
        #pragma unroll
        for (int j = 0; j < 8; ++j){ float f = b2f(pv[j]); s[j] += f; q[j] += f * f; }
    }
    #pragma unroll
    for (int j = 0; j < 8; ++j){ red[0][slice][c8+j]=s[j]; red[1][slice][c8+j]=q[j]; }
    __syncthreads();
    if (tid < 128){
        float ts=0.f, tq=0.f;
        #pragma unroll
        for (int w = 0; w < 16; ++w){ ts += red[0][w][tid]; tq += red[1][w][tid]; }
        atomicAdd(&st[tid], ts); atomicAdd(&st[128+tid], tq);
    }
}

// ---------- MFMA GEMM: C[n, ccol0..+128 of ldc] = act( BN(scale*A) @ W ) ----------
template<int ACT, int INBF>  // ACT: 1=relu ; INBF: input bf16?
__global__ __launch_bounds__(256, 3) void k_gemm(const void* __restrict__ Av,
        const float* __restrict__ scale, int sch,
        const float* __restrict__ st, const bf16_t* __restrict__ WhiT,
        const bf16_t* __restrict__ WloT,
        bf16_t* __restrict__ C, int ldc, int ccol0, int n)
{
    __shared__ bf16_t As[64 * 136];
    __shared__ bf16_t Whi[128 * 72];
    __shared__ bf16_t Wlo[128 * 72];
    int tid = threadIdx.x;
    int wid = tid >> 6, lane = tid & 63;
    int row0 = blockIdx.x * 64;
    int m0 = wid * 16;
    int q8 = (lane >> 4) * 8, l15 = lane & 15;

    int c8t = (tid & 15) * 8;
    float sM[8], sR[8];
    #pragma unroll
    for (int j = 0; j < 8; ++j){
        float m = st[c8t + j] / n;
        float var = st[128 + c8t + j] / n - m * m;
        sM[j] = m; sR[j] = rsqrtf(var + 1e-5f);
    }

    for (int i = tid; i < 64 * 16; i += 256){
        int r = i >> 4, c8 = (i & 15) * 8;
        int gr = row0 + r;
        float v[8];
        if (gr < n){
            float sc = scale ? scale[(size_t)gr * 2 + sch] : 1.f;
            if (INBF){
                const bf16_t* Ab = (const bf16_t*)Av;
                ushort4 qa = *(const ushort4*)&Ab[(size_t)gr * 128 + c8];
                ushort4 qb = *(const ushort4*)&Ab[(size_t)gr * 128 + c8 + 4];
                v[0]=b2f(qa.x); v[1]=b2f(qa.y); v[2]=b2f(qa.z); v[3]=b2f(qa.w);
                v[4]=b2f(qb.x); v[5]=b2f(qb.y); v[6]=b2f(qb.z); v[7]=b2f(qb.w);
            } else {
                const float* Af = (const float*)Av;
                float4 fa = *(const float4*)&Af[(size_t)gr * 128 + c8];
                float4 fb = *(const float4*)&Af[(size_t)gr * 128 + c8 + 4];
                v[0]=fa.x; v[1]=fa.y; v[2]=fa.z; v[3]=fa.w;
                v[4]=fb.x; v[5]=fb.y; v[6]=fb.z; v[7]=fb.w;
            }
            #pragma unroll
            for (int j = 0; j < 8; ++j)
                v[j] = (v[j] * sc - sM[j]) * sR[j] + 1e-4f;
        } else {
            #pragma unroll
            for (int j = 0; j < 8; ++j) v[j] = 0.f;
        }
        #pragma unroll
        for (int j = 0; j < 8; ++j) As[r * 136 + c8 + j] = f2b(v[j]);
    }

    f32x4 acc[8];
    #pragma unroll
    for (int t = 0; t < 8; ++t) acc[t] = (f32x4){0.f, 0.f, 0.f, 0.f};

    for (int kc = 0; kc < 128; kc += 64){
        __syncthreads();
        for (int i = tid; i < 128 * 8; i += 256){
            int nrow = i >> 3, k8 = (i & 7) * 8;
            *(uint4*)&Whi[nrow * 72 + k8] = *(const uint4*)&WhiT[(size_t)nrow * 128 + kc + k8];
            *(uint4*)&Wlo[nrow * 72 + k8] = *(const uint4*)&WloT[(size_t)nrow * 128 + kc + k8];
        }
        __syncthreads();
        #pragma unroll
        for (int kbl = 0; kbl < 2; ++kbl){
            bf16x8 a = *(const bf16x8*)&As[(m0 + l15) * 136 + kc + kbl * 32 + q8];
            #pragma unroll
            for (int nt = 0; nt < 8; ++nt){
                bf16x8 bh = *(const bf16x8*)&Whi[(nt * 16 + l15) * 72 + kbl * 32 + q8];
                acc[nt] = __builtin_amdgcn_mfma_f32_16x16x32_bf16(a, bh, acc[nt], 0, 0, 0);
                bf16x8 bl = *(const bf16x8*)&Wlo[(nt * 16 + l15) * 72 + kbl * 32 + q8];
                acc[nt] = __builtin_amdgcn_mfma_f32_16x16x32_bf16(a, bl, acc[nt], 0, 0, 0);
            }
        }
    }

    __syncthreads();
    #pragma unroll
    for (int nt = 0; nt < 8; ++nt){
        #pragma unroll
        for (int r = 0; r < 4; ++r){
            float v = acc[nt][r];
            if (ACT == 1) v = fmaxf(v, 0.f);
            As[(m0 + (lane >> 4) * 4 + r) * 136 + nt * 16 + l15] = f2b(v);
        }
    }
    __syncthreads();
    for (int i = tid; i < 64 * 16; i += 256){
        int r = i >> 4, c8 = (i & 15) * 8;
        int gr = row0 + r;
        if (gr < n)
            *(uint4*)&C[(size_t)gr * ldc + ccol0 + c8] = *(const uint4*)&As[r * 136 + c8];
    }
}

// dual branch GEMM: blockIdx.y = branch (0:xc, 1:xo); input bf16, no act
__global__ __launch_bounds__(256, 3) void k_gemm2(const bf16_t* __restrict__ Ab,
        const float* __restrict__ natt, const float* __restrict__ stBase,
        const bf16_t* __restrict__ whiT6, const bf16_t* __restrict__ wloT6,
        bf16_t* __restrict__ C, int n)
{
    __shared__ bf16_t As[64 * 136];
    __shared__ bf16_t Whi[128 * 72];
    __shared__ bf16_t Wlo[128 * 72];
    int brn = blockIdx.y;
    const float* st = stBase + brn * 256;
    const bf16_t* WhiT = whiT6 + (size_t)(4 + brn) * 16384;
    const bf16_t* WloT = wloT6 + (size_t)(4 + brn) * 16384;
    int ccol0 = brn * 128;
    const int ldc = 256;

    int tid = threadIdx.x;
    int wid = tid >> 6, lane = tid & 63;
    int row0 = blockIdx.x * 64;
    int m0 = wid * 16;
    int q8 = (lane >> 4) * 8, l15 = lane & 15;

    int c8t = (tid & 15) * 8;
    float sM[8], sR[8];
    #pragma unroll
    for (int j = 0; j < 8; ++j){
        float m = st[c8t + j] / n;
        float var = st[128 + c8t + j] / n - m * m;
        sM[j] = m; sR[j] = rsqrtf(var + 1e-5f);
    }

    for (int i = tid; i < 64 * 16; i += 256){
        int r = i >> 4, c8 = (i & 15) * 8;
        int gr = row0 + r;
        float v[8];
        if (gr < n){
            float sc = natt[(size_t)gr * 2 + brn];
            ushort4 qa = *(const ushort4*)&Ab[(size_t)gr * 128 + c8];
            ushort4 qb = *(const ushort4*)&Ab[(size_t)gr * 128 + c8 + 4];
            v[0]=b2f(qa.x); v[1]=b2f(qa.y); v[2]=b2f(qa.z); v[3]=b2f(qa.w);
            v[4]=b2f(qb.x); v[5]=b2f(qb.y); v[6]=b2f(qb.z); v[7]=b2f(qb.w);
            #pragma unroll
            for (int j = 0; j < 8; ++j)
                v[j] = (v[j] * sc - sM[j]) * sR[j] + 1e-4f;
        } else {
            #pragma unroll
            for (int j = 0; j < 8; ++j) v[j] = 0.f;
        }
        #pragma unroll
        for (int j = 0; j < 8; ++j) As[r * 136 + c8 + j] = f2b(v[j]);
    }

    f32x4 acc[8];
    #pragma unroll
    for (int t = 0; t < 8; ++t) acc[t] = (f32x4){0.f, 0.f, 0.f, 0.f};

    for (int kc = 0; kc < 128; kc += 64){
        __syncthreads();
        for (int i = tid; i < 128 * 8; i += 256){
            int nrow = i >> 3, k8 = (i & 7) * 8;
            *(uint4*)&Whi[nrow * 72 + k8] = *(const uint4*)&WhiT[(size_t)nrow * 128 + kc + k8];
            *(uint4*)&Wlo[nrow * 72 + k8] = *(const uint4*)&WloT[(size_t)nrow * 128 + kc + k8];
        }
        __syncthreads();
        #pragma unroll
        for (int kbl = 0; kbl < 2; ++kbl){
            bf16x8 a = *(const bf16x8*)&As[(m0 + l15) * 136 + kc + kbl * 32 + q8];
            #pragma unroll
            for (int nt = 0; nt < 8; ++nt){
                bf16x8 bh = *(const bf16x8*)&Whi[(nt * 16 + l15) * 72 + kbl * 32 + q8];
                acc[nt] = __builtin_amdgcn_mfma_f32_16x16x32_bf16(a, bh, acc[nt], 0, 0, 0);
                bf16x8 bl = *(const bf16x8*)&Wlo[(nt * 16 + l15) * 72 + kbl * 32 + q8];
                acc[nt] = __builtin_amdgcn_mfma_f32_16x16x32_bf16(a, bl, acc[nt], 0, 0, 0);
            }
        }
    }

    __syncthreads();
    #pragma unroll
    for (int nt = 0; nt < 8; ++nt){
        #pragma unroll
        for (int r = 0; r < 4; ++r){
            As[(m0 + (lane >> 4) * 4 + r) * 136 + nt * 16 + l15] = f2b(acc[nt][r]);
        }
    }
    __syncthreads();
    for (int i = tid; i < 64 * 16; i += 256){
        int r = i >> 4, c8 = (i & 15) * 8;
        int gr = row0 + r;
        if (gr < n)
            *(uint4*)&C[(size_t)gr * ldc + ccol0 + c8] = *(const uint4*)&As[r * 136 + c8];
    }
}

// ---------- CSR scan (joint: dst counts then src counts, 2N) ----------
__global__ __launch_bounds__(1024) void k_scanA(const int* __restrict__ cnt,
        int* __restrict__ ptr, int* __restrict__ bsum, int n){
    __shared__ int wsum[16];
    int t = threadIdx.x, lane = t & 63, wid = t >> 6;
    int i = blockIdx.x * 1024 + t;
    int v = (i < n) ? cnt[i] : 0;
    int s = v;
    for (int off = 1; off < 64; off <<= 1){
        int u = __shfl_up(s, off);
        if (lane >= off) s += u;
    }
    if (lane == 63) wsum[wid] = s;
    __syncthreads();
    if (wid == 0 && lane < 16){
        int ws = wsum[lane];
        for (int off = 1; off < 16; off <<= 1){
            int u = __shfl_up(ws, off);
            if (lane >= off) ws += u;
        }
        wsum[lane] = ws;
    }
    __syncthreads();
    int woff = wid ? wsum[wid - 1] : 0;
    if (i < n) ptr[i] = woff + s - v;
    if (t == 1023) bsum[blockIdx.x] = woff + s;
}
__global__ void k_scanB(int* __restrict__ bsum, int* __restrict__ ptrN, int nb){
    int lane = threadIdx.x;       // 64 threads
    int carry = 0;
    for (int base = 0; base < nb; base += 64){
        int i = base + lane;
        int v = (i < nb) ? bsum[i] : 0;
        int s = v;
        for (int off = 1; off < 64; off <<= 1){
            int u = __shfl_up(s, off);
            if (lane >= off) s += u;
        }
        if (i < nb) bsum[i] = carry + s - v;
        carry += __shfl(s, 63);
    }
    if (lane == 0) *ptrN = carry;
}
__global__ __launch_bounds__(1024) void k_scanC(int* __restrict__ ptr,
        const int* __restrict__ bsum, int n){
    int i = blockIdx.x * 1024 + threadIdx.x;
    if (i < n) ptr[i] += bsum[blockIdx.x];
}
// atomic-free CSR fill: slot = ptr + chunkOff + localRank (both CSRs)
__global__ void k_fill(const int* __restrict__ esrc, const int* __restrict__ edst,
        const int* __restrict__ rankE, const int* __restrict__ rankS,
        const uint32* __restrict__ cntD16, const uint32* __restrict__ cntS16,
        const int* __restrict__ ptr, const float* __restrict__ degUf,
        int* __restrict__ srcC, int* __restrict__ dstC, int* __restrict__ dstS,
        float* __restrict__ wU, int e, int n, int WD, int EC)
{
    int i = blockIdx.x * 256 + threadIdx.x;
    if (i >= e) return;
    int s = esrc[i], d = edst[i];
    int c = i / EC;
    uint32 pw = cntD16[(size_t)c * WD + (d >> 1)];
    int offD = (d & 1) ? (int)(pw >> 16) : (int)(pw & 0xffffu);
    int dslot = ptr[d] + offD + rankE[i];
    uint32 sw = cntS16[(size_t)c * WD + (s >> 1)];
    int offS = (s & 1) ? (int)(sw >> 16) : (int)(sw & 0xffffu);
    int sslot = (ptr[n + s] - e) + offS + rankS[i];
    srcC[dslot] = s;
    dstC[dslot] = d;
    wU[dslot] = rsqrtf(degUf[s] + 1.0f);
    dstS[sslot] = d;
}

// ---------- conv propagate: readlane index broadcast; optional fused prep ----------
template<int PREP>
__global__ __launch_bounds__(256) void k_gather0(const int* __restrict__ ptr,
        const int* __restrict__ srcC, const float* __restrict__ wE,
        const float* __restrict__ degU, const bf16_t* __restrict__ t,
        const float* __restrict__ bias, bf16_t* __restrict__ outB,
        const float* __restrict__ eW, const float* __restrict__ naW,
        float4* __restrict__ epre, float* __restrict__ ntT, int n)
{
    int node = blockIdx.x * 4 + (threadIdx.x >> 6);
    if (node >= n) return;
    int lane = threadIdx.x & 63;
    const uint32* T = (const uint32*)t;
    float dd = rsqrtf(degU[node] + 1.0f);
    uint32 sv = T[(size_t)node * 64 + lane];
    float a0 = 0.f, a1 = 0.f;
    int k = ptr[node], end = ptr[node + 1];
    while (k < end){
        int cnt = min(end - k, 64);
        int kl = k + min(lane, cnt - 1);
        int   myI = srcC[kl];
        float myW = wE[kl];
        int j = 0;
        for (; j + 8 <= cnt; j += 8){
            int s0 = rl(myI, j),     s1 = rl(myI, j + 1), s2 = rl(myI, j + 2), s3 = rl(myI, j + 3);
            int s4 = rl(myI, j + 4), s5 = rl(myI, j + 5), s6 = rl(myI, j + 6), s7 = rl(myI, j + 7);
            float w0 = rlf(myW, j),     w1 = rlf(myW, j + 1), w2 = rlf(myW, j + 2), w3 = rlf(myW, j + 3);
            float w4 = rlf(myW, j + 4), w5 = rlf(myW, j + 5), w6 = rlf(myW, j + 6), w7 = rlf(myW, j + 7);
            uint32 v0 = T[(size_t)s0 * 64 + lane];
            uint32 v1 = T[(size_t)s1 * 64 + lane];
            uint32 v2 = T[(size_t)s2 * 64 + lane];
            uint32 v3 = T[(size_t)s3 * 64 + lane];
            uint32 v4 = T[(size_t)s4 * 64 + lane];
            uint32 v5 = T[(size_t)s5 * 64 + lane];
            uint32 v6 = T[(size_t)s6 * 64 + lane];
            uint32 v7 = T[(size_t)s7 * 64 + lane];
            a0 += w0 * lo16(v0) + w1 * lo16(v1) + w2 * lo16(v2) + w3 * lo16(v3);
            a1 += w0 * hi16(v0) + w1 * hi16(v1) + w2 * hi16(v2) + w3 * hi16(v3);
            a0 += w4 * lo16(v4) + w5 * lo16(v5) + w6 * lo16(v6) + w7 * lo16(v7);
            a1 += w4 * hi16(v4) + w5 * hi16(v5) + w6 * hi16(v6) + w7 * hi16(v7);
        }
        for (; j < cnt; ++j){
            int s = rl(myI, j);
            float w = rlf(myW, j);
            uint32 v = T[(size_t)s * 64 + lane];
            a0 += w * lo16(v); a1 += w * hi16(v);
        }
        k += cnt;
    }
    a0 = fmaxf(dd * (a0 + dd * lo16(sv)) + bias[2 * lane],     0.f);
    a1 = fmaxf(dd * (a1 + dd * hi16(sv)) + bias[2 * lane + 1], 0.f);
    ((uint32*)outB)[(size_t)node * 64 + lane] = pack2(a0, a1);
    if (PREP){
        // lane holds feats (2*lane, 2*lane+1) = (a0, a1).
        // eW row f at float offset 2f; dst-half rows 128+f at 256+2f.
        float s0 = a0 * eW[4 * lane]           + a1 * eW[4 * lane + 2];
        float s1 = a0 * eW[4 * lane + 1]       + a1 * eW[4 * lane + 3];
        float d0 = a0 * eW[256 + 4 * lane]     + a1 * eW[256 + 4 * lane + 2];
        float d1 = a0 * eW[256 + 4 * lane + 1] + a1 * eW[256 + 4 * lane + 3];
        float n0 = a0 * naW[4 * lane]          + a1 * naW[4 * lane + 2];
        float n1 = a0 * naW[4 * lane + 1]      + a1 * naW[4 * lane + 3];
        for (int off = 32; off; off >>= 1){
            s0 += __shfl_xor(s0, off); s1 += __shfl_xor(s1, off);
            d0 += __shfl_xor(d0, off); d1 += __shfl_xor(d1, off);
            n0 += __shfl_xor(n0, off); n1 += __shfl_xor(n1, off);
        }
        if (lane == 0){
            epre[node] = make_float4(s0, s1, d0, d1);
            ntT[2 * node] = n0; ntT[2 * node + 1] = n1;
        }
    }
}

// ---------- branch propagate; degC1 derived as degU - degC0 ----------
__global__ __launch_bounds__(256) void k_gatherP2(const int* __restrict__ ptr,
        const int* __restrict__ srcC, const float* __restrict__ w0E,
        const float* __restrict__ w1E, const float* __restrict__ degC0,
        const float* __restrict__ degU, const bf16_t* __restrict__ t,
        const float* __restrict__ biasC, const float* __restrict__ biasO,
        const int* __restrict__ batch, float* __restrict__ pool0,
        float* __restrict__ pool1, int n, int span)
{
    int br   = blockIdx.x & 1;
    int wave = (blockIdx.x >> 1) * 4 + (threadIdx.x >> 6);
    int lane = threadIdx.x & 63;
    int nbeg = wave * span;
    if (nbeg >= n) return;
    int nend = min(n, nbeg + span);
    const float* wE   = br ? w1E : w0E;
    const float* bias = br ? biasO : biasC;
    float* pool       = br ? pool1 : pool0;
    float b0 = bias[2 * lane], b1 = bias[2 * lane + 1];
    const uint32* T = (const uint32*)t;       // B0c row = 128 uint32
    int rowoff = (br ? 64 : 0) + lane;
    int curG = -1;
    float p0 = 0.f, p1 = 0.f;
    for (int node = nbeg; node < nend; ++node){
        float d0v = degC0[node];
        float dv  = br ? (degU[node] - d0v) : d0v;
        float dd  = rsqrtf(dv + 1.0f);
        uint32 sv = T[(size_t)node * 128 + rowoff];
        float a0 = 0.f, a1 = 0.f;
        int k = ptr[node], end = ptr[node + 1];
        while (k < end){
            int cnt = min(end - k, 64);
            int kl = k + min(lane, cnt - 1);
            int   myI = srcC[kl];
            float myW = wE[kl];
            int j = 0;
            for (; j + 8 <= cnt; j += 8){
                int s0 = rl(myI, j),     s1 = rl(myI, j + 1), s2 = rl(myI, j + 2), s3 = rl(myI, j + 3);
                int s4 = rl(myI, j + 4), s5 = rl(myI, j + 5), s6 = rl(myI, j + 6), s7 = rl(myI, j + 7);
                float w0 = rlf(myW, j),     w1 = rlf(myW, j + 1), w2 = rlf(myW, j + 2), w3 = rlf(myW, j + 3);
                float w4 = rlf(myW, j + 4), w5 = rlf(myW, j + 5), w6 = rlf(myW, j + 6), w7 = rlf(myW, j + 7);
                uint32 v0 = T[(size_t)s0 * 128 + rowoff];
                uint32 v1 = T[(size_t)s1 * 128 + rowoff];
                uint32 v2 = T[(size_t)s2 * 128 + rowoff];
                uint32 v3 = T[(size_t)s3 * 128 + rowoff];
                uint32 v4 = T[(size_t)s4 * 128 + rowoff];
                uint32 v5 = T[(size_t)s5 * 128 + rowoff];
                uint32 v6 = T[(size_t)s6 * 128 + rowoff];
                uint32 v7 = T[(size_t)s7 * 128 + rowoff];
                a0 += w0 * lo16(v0) + w1 * lo16(v1) + w2 * lo16(v2) + w3 * lo16(v3);
                a1 += w0 * hi16(v0) + w1 * hi16(v1) + w2 * hi16(v2) + w3 * hi16(v3);
                a0 += w4 * lo16(v4) + w5 * lo16(v5) + w6 * lo16(v6) + w7 * lo16(v7);
                a1 += w4 * hi16(v4) + w5 * hi16(v5) + w6 * hi16(v6) + w7 * hi16(v7);
            }
            for (; j < cnt; ++j){
                int s = rl(myI, j);
                float w = rlf(myW, j);
                uint32 v = T[(size_t)s * 128 + rowoff];
                a0 += w * lo16(v); a1 += w * hi16(v);
            }
            k += cnt;
        }
        a0 = dd * (a0 + dd * lo16(sv)) + b0;
        a1 = dd * (a1 + dd * hi16(sv)) + b1;
        a0 = a0 > 0.f ? a0 : expm1f(a0);
        a1 = a1 > 0.f ? a1 : expm1f(a1);
        int g = batch[node];
        if (g != curG){
            if (curG >= 0){
                float* p = pool + (size_t)curG * 128 + 2 * lane;
                atomicAdd(&p[0], p0); atomicAdd(&p[1], p1);
            }
            curG = g; p0 = a0; p1 = a1;
        } else {
            p0 += a0; p1 += a1;
        }
    }
    if (curG >= 0){
        float* p = pool + (size_t)curG * 128 + 2 * lane;
        atomicAdd(&p[0], p0); atomicAdd(&p[1], p1);
    }
}

// ---------- attention: natt | eatt (no atomic) | degC0 (src-CSR recompute) ----------
__global__ void k_eattnatt(const int* __restrict__ srcC, const int* __restrict__ dstC,
        const int* __restrict__ dstS,
        const float4* __restrict__ epre, const float* __restrict__ eb,
        float* __restrict__ wB0, float* __restrict__ wB1,
        float* __restrict__ degC0,
        const int* __restrict__ ptr, const float* __restrict__ wU,
        const float* __restrict__ degU, const float* __restrict__ ntT,
        const float* __restrict__ nab, float* __restrict__ natt,
        int e, int n, int gridN, int gridE)
{
    int bx = blockIdx.x;
    if (bx < gridN){
        int i = bx * 256 + threadIdx.x;
        if (i >= n) return;
        float dd = rsqrtf(degU[i] + 1.0f);
        float z0 = 0.f, z1 = 0.f;
        int end = ptr[i + 1];
        for (int k = ptr[i]; k < end; ++k){
            int s = srcC[k];
            float w = wU[k];
            z0 += w * ntT[2 * s]; z1 += w * ntT[2 * s + 1];
        }
        z0 = dd * (z0 + dd * ntT[2 * i])     + nab[0];
        z1 = dd * (z1 + dd * ntT[2 * i + 1]) + nab[1];
        float m = fmaxf(z0, z1);
        float e0 = expf(z0 - m), e1 = expf(z1 - m);
        float inv = 1.f / (e0 + e1);
        natt[2 * i] = e0 * inv; natt[2 * i + 1] = e1 * inv;
    } else if (bx < gridN + gridE){
        int i = (bx - gridN) * 256 + threadIdx.x;
        if (i >= e) return;
        int s = srcC[i];
        float4 ps = epre[s], pd = epre[dstC[i]];
        float l0 = ps.x + pd.z + eb[0], l1 = ps.y + pd.w + eb[1];
        float m = fmaxf(l0, l1);
        float e0 = expf(l0 - m), e1 = expf(l1 - m);
        float inv = 1.f / (e0 + e1);
        wB0[i] = e0 * inv; wB1[i] = e1 * inv;
    } else {
        int s = (bx - gridN - gridE) * 256 + threadIdx.x;
        if (s >= n) return;
        float4 ps = epre[s];
        float eb0 = eb[0], eb1 = eb[1];
        int beg = ptr[n + s] - e, endk = ptr[n + s + 1] - e;
        float sum = 0.f;
        for (int k = beg; k < endk; ++k){
            int d = dstS[k];
            float4 pd = epre[d];
            float l0 = ps.x + pd.z + eb0, l1 = ps.y + pd.w + eb1;
            float m = fmaxf(l0, l1);
            float e0 = expf(l0 - m), e1v = expf(l1 - m);
            sum += e0 / (e0 + e1v);
        }
        degC0[s] = sum;
    }
}

// ---------- stats2 (256 blocks, vectorized) | wB (gridE blocks) ----------
__global__ void k_stats2wB(const bf16_t* __restrict__ a, const float* __restrict__ natt,
        float* __restrict__ st, int n,
        const int* __restrict__ srcC, const float* __restrict__ degC0,
        const float* __restrict__ degU, float* __restrict__ w0,
        float* __restrict__ w1, int e)
{
    __shared__ float red[2][16][128];
    int bx = blockIdx.x, tid = threadIdx.x;
    if (bx < 256){
        int c8 = (tid & 15) * 8, slice = tid >> 4;
        float s0[8]={0,0,0,0,0,0,0,0}, q0[8]={0,0,0,0,0,0,0,0};
        float s1[8]={0,0,0,0,0,0,0,0}, q1[8]={0,0,0,0,0,0,0,0};
        for (int row = bx * 16 + slice; row < n; row += 4096){
            uint4 v = *(const uint4*)&a[(size_t)row * 128 + c8];
            const bf16_t* pv = (const bf16_t*)&v;
            float2 w = *(const float2*)&natt[(size_t)row * 2];
            #pragma unroll
            for (int j = 0; j < 8; ++j){
                float f = b2f(pv[j]);
                float f0 = f * w.x, f1 = f * w.y;
                s0[j] += f0; q0[j] += f0 * f0;
                s1[j] += f1; q1[j] += f1 * f1;
            }
        }
        #pragma unroll
        for (int j = 0; j < 8; ++j){ red[0][slice][c8+j]=s0[j]; red[1][slice][c8+j]=q0[j]; }
        __syncthreads();
        if (tid < 128){
            float ts=0.f, tq=0.f;
            #pragma unroll
            for (int w = 0; w < 16; ++w){ ts += red[0][w][tid]; tq += red[1][w][tid]; }
            atomicAdd(&st[tid], ts); atomicAdd(&st[128+tid], tq);
        }
        __syncthreads();
        #pragma unroll
        for (int j = 0; j < 8; ++j){ red[0][slice][c8+j]=s1[j]; red[1][slice][c8+j]=q1[j]; }
        __syncthreads();
        if (tid < 128){
            float ts=0.f, tq=0.f;
            #pragma unroll
            for (int w = 0; w < 16; ++w){ ts += red[0][w][tid]; tq += red[1][w][tid]; }
            atomicAdd(&st[256+tid], ts); atomicAdd(&st[384+tid], tq);
        }
    } else {
        int i = (bx - 256) * 256 + tid;
        if (i < e){
            int s = srcC[i];
            float d0v = degC0[s];
            w0[i] *= rsqrtf(d0v + 1.0f);
            w1[i] *= rsqrtf(degU[s] - d0v + 1.0f);
        }
    }
}

// ---------- heads (G=512, fp32), 3 heads fused per stage ----------
__global__ __launch_bounds__(1024) void k_gstats3(const float* __restrict__ xcp,
        const float* __restrict__ xop, float* __restrict__ mrsH, int n){
    __shared__ float red[2][1024];
    int head = blockIdx.x;
    const float* a = (head == 1) ? xop : xcp;
    const float* b = (head == 0) ? xcp : xop;
    int f = (head == 2) ? 256 : 128;
    float* mrs = mrsH + head * 512;
    int col = threadIdx.x & (f - 1);
    int rpb = 1024 / f;
    int rw  = threadIdx.x / f;
    float s = 0.f, sq = 0.f;
    for (int r = rw; r < n; r += rpb){
        float v = (col < 128) ? a[(size_t)r * 128 + col] : b[(size_t)r * 128 + col - 128];
        s += v; sq += v * v;
    }
    red[0][threadIdx.x] = s; red[1][threadIdx.x] = sq;
    __syncthreads();
    if (threadIdx.x < (unsigned)f){
        float ts = 0.f, tq = 0.f;
        for (int w = 0; w < rpb; ++w){ ts += red[0][w * f + col]; tq += red[1][w * f + col]; }
        float m = ts / n, var = tq / n - m * m;
        mrs[col] = m; mrs[f + col] = rsqrtf(var + 1e-5f);
    }
}
__global__ __launch_bounds__(128) void k_hgemm3(const float* __restrict__ xcp,
        const float* __restrict__ xop, const float* __restrict__ mrsH,
        const float* __restrict__ cW1, const float* __restrict__ cb1,
        const float* __restrict__ oW1, const float* __restrict__ ob1,
        const float* __restrict__ coW1, const float* __restrict__ cob1,
        float* __restrict__ gt3)
{
    __shared__ float as[256];
    int head = blockIdx.y, row = blockIdx.x, tid = threadIdx.x;
    const float* a  = (head == 1) ? xop : xcp;
    const float* b2 = (head == 0) ? xcp : xop;
    int fin = (head == 2) ? 256 : 128;
    const float* mrs = mrsH + head * 512;
    const float* W  = (head == 0) ? cW1 : (head == 1) ? oW1 : coW1;
    const float* bb = (head == 0) ? cb1 : (head == 1) ? ob1 : cob1;
    float* o = gt3 + (size_t)head * 512 * 128;
    for (int i = tid; i < fin; i += 128){
        float v = (i < 128) ? a[(size_t)row * 128 + i] : b2[(size_t)row * 128 + i - 128];
        as[i] = (v - mrs[i]) * mrs[fin + i] + 1e-4f;
    }
    __syncthreads();
    float s = 0.f;
    for (int k = 0; k < fin; ++k) s += as[k] * W[k * 128 + tid];
    s += bb[tid];
    if (head < 2) s = fmaxf(s, 0.f);
    else { s = s > 0.f ? s : expm1f(s); s = s > 0.f ? s : expm1f(s); }
    o[(size_t)row * 128 + tid] = s;
}
__global__ __launch_bounds__(1024) void k_gstats3b(const float* __restrict__ gt3,
        float* __restrict__ mrsH2, int n){
    __shared__ float red[2][1024];
    int head = blockIdx.x;
    const float* a = gt3 + (size_t)head * 512 * 128;
    float* mrs = mrsH2 + head * 256;
    int col = threadIdx.x & 127;
    int rw  = threadIdx.x >> 7;    // 8 rows/block-pass
    float s = 0.f, sq = 0.f;
    for (int r = rw; r < n; r += 8){
        float v = a[(size_t)r * 128 + col];
        s += v; sq += v * v;
    }
    red[0][threadIdx.x] = s; red[1][threadIdx.x] = sq;
    __syncthreads();
    if (threadIdx.x < 128u){
        float ts = 0.f, tq = 0.f;
        for (int w = 0; w < 8; ++w){ ts += red[0][w * 128 + col]; tq += red[1][w * 128 + col]; }
        float m = ts / n, var = tq / n - m * m;
        mrs[col] = m; mrs[128 + col] = rsqrtf(var + 1e-5f);
    }
}
__global__ __launch_bounds__(256) void k_hfinal3(const float* __restrict__ gt3,
        const float* __restrict__ mrsH2,
        const float* __restrict__ cW2, const float* __restrict__ cb2,
        const float* __restrict__ oW2, const float* __restrict__ ob2,
        const float* __restrict__ coW2, const float* __restrict__ cob2,
        float* __restrict__ out, int nrows)
{
    int head = blockIdx.y;
    int row = blockIdx.x * 4 + (threadIdx.x >> 6);
    if (row >= nrows) return;
    int lane = threadIdx.x & 63;
    const float* a   = gt3 + (size_t)head * 512 * 128;
    const float* mrs = mrsH2 + head * 256;
    const float* W = (head == 0) ? cW2 : (head == 1) ? oW2 : coW2;
    const float* b = (head == 0) ? cb2 : (head == 1) ? ob2 : cob2;
    float* o = out + (size_t)head * nrows * 10;
    float v0 = (a[(size_t)row * 128 + lane]      - mrs[lane])      * mrs[128 + lane]      + 1e-4f;
    float v1 = (a[(size_t)row * 128 + 64 + lane] - mrs[64 + lane]) * mrs[128 + 64 + lane] + 1e-4f;
    float logit[10];
    #pragma unroll
    for (int c = 0; c < 10; ++c){
        float p = v0 * W[lane * 10 + c] + v1 * W[(lane + 64) * 10 + c];
        for (int off = 32; off; off >>= 1) p += __shfl_xor(p, off);
        logit[c] = p + b[c];
    }
    float m = logit[0];
    #pragma unroll
    for (int c = 1; c < 10; ++c) m = fmaxf(m, logit[c]);
    float s = 0.f;
    #pragma unroll
    for (int c = 0; c < 10; ++c) s += expf(logit[c] - m);
    float lse = logf(s);
    if (lane < 10) o[row * 10 + lane] = logit[lane] - m - lse;
}

extern "C" void kernel_launch(void* const* d_in, const int* in_sizes, int n_in,
                              void* d_out, int out_size, void* d_ws, size_t ws_size,
                              hipStream_t stream)
{
    const int N = in_sizes[0] / 128;
    const int E = in_sizes[24];
    const int G = 512;
    const float* x    = (const float*)d_in[0];
    const float* Wf   = (const float*)d_in[1];
    const float* cWs  = (const float*)d_in[2];
    const float* cbs  = (const float*)d_in[3];
    const float* eW   = (const float*)d_in[4];
    const float* ebv  = (const float*)d_in[5];
    const float* naW  = (const float*)d_in[6];
    const float* nab  = (const float*)d_in[7];
    const float* xcW  = (const float*)d_in[8];
    const float* xcb  = (const float*)d_in[9];
    const float* xoW  = (const float*)d_in[10];
    const float* xob  = (const float*)d_in[11];
    const float* cW1  = (const float*)d_in[12];
    const float* cb1  = (const float*)d_in[13];
    const float* cW2  = (const float*)d_in[14];
    const float* cb2  = (const float*)d_in[15];
    const float* oW1  = (const float*)d_in[16];
    const float* ob1  = (const float*)d_in[17];
    const float* oW2  = (const float*)d_in[18];
    const float* ob2  = (const float*)d_in[19];
    const float* coW1 = (const float*)d_in[20];
    const float* cob1 = (const float*)d_in[21];
    const float* coW2 = (const float*)d_in[22];
    const float* cob2 = (const float*)d_in[23];
    const int* esrc  = (const int*)d_in[24];
    const int* edst  = (const int*)d_in[25];
    const int* batch = (const int*)d_in[26];
    float* out = (float*)d_out;

    const int WD = (N + 1) / 2;              // packed words per histogram row
    const int EC = (E + CHNK - 1) / CHNK;    // edges per chunk

    size_t NH = (size_t)N * 128;
    bf16_t* B1  = (bf16_t*)d_ws;            // N*128
    bf16_t* B0  = B1 + NH;                  // N*128
    bf16_t* B0c = B0 + NH;                  // N*256 ([xc|xo])
    float* fbase = (float*)(B0c + 2 * NH);
    float* epreF = fbase;                   // 4N
    float* ntT   = epreF + 4 * (size_t)N;
    float* natt  = ntT + 2 * (size_t)N;
    float* mrsH  = natt + 2 * (size_t)N;    // 1536 (3 heads x 512)
    float* mrsH2 = mrsH + 1536;             // 768  (3 heads x 256)
    float* wU    = mrsH2 + 768;             // E (CSR order)
    float* wB0   = wU + E;                  // E
    float* wB1   = wB0 + E;                 // E
    float* gt3   = wB1 + E;                 // 3*G*128
    float* degU  = gt3 + (size_t)3 * G * 128; // N (float out-degree, from src hist)
    float* degC0 = degU + N;                // N (written by eattnatt)
    // zero zone: stZ + pools
    float* stZ   = degC0 + N;               // 1536
    float* xcp   = stZ + 1536;              // G*128
    float* xop   = xcp + (size_t)G * 128;   // G*128
    size_t zzBytes = (1536 + 2 * (size_t)G * 128) * 4;
    int* cntI   = (int*)(xop + (size_t)G * 128);   // 2N (totals, from chunkscan)
    int* ptrI   = cntI + 2 * N;             // 2N+1 (joint scan)
    int* srcC   = ptrI + 2 * N + 1;         // E
    int* dstC   = srcC + E;                 // E
    int* dstS   = dstC + E;                 // E (dst node per src-CSR slot)
    int* rankE  = dstS + E;                 // E (local dst rank)
    int* rankS  = rankE + E;                // E (local src rank)
    int* bsum   = rankS + E;                // up to 128
    uint32* cntD16 = (uint32*)(bsum + 128); // CHNK*WD
    uint32* cntS16 = cntD16 + (size_t)CHNK * WD;
    bf16_t* whiT = (bf16_t*)((((size_t)(cntS16 + (size_t)CHNK * WD)) + 15) & ~(size_t)15);
    bf16_t* wloT = whiT + 6 * 16384;
    float4* epre = (float4*)epreF;

    int gridE = (E + 255) / 256;
    int gridN = (N + 255) / 256;
    int gridW = (N + 3) / 4;
    int gridG = (N + 63) / 64;
    int n2    = 2 * N;
    int nb2   = (n2 + 1023) / 1024;
    int gridCS = (2 * WD + 255) / 256;
    int span  = (N + 16383) / 16384;
    int gridP = (N + span * 4 - 1) / (span * 4);

    hipMemsetAsync(stZ, 0, zzBytes, stream);

    // ---- prologue: hist(256) | wsplit(96) | statsF(256) ----
    k_prologue<<<608, 256, 0, stream>>>(Wf, cWs, xcW, xoW, whiT, wloT,
            esrc, edst, cntD16, cntS16, rankE, rankS, E, x, stZ, N, WD);

    // ---- chunk-offset scan + totals, then joint 2N ptr scan, atomic-free fill ----
    k_chunkscan<<<gridCS, 256, 0, stream>>>(cntD16, cntS16, cntI, degU, WD, N);
    k_scanA<<<nb2, 1024, 0, stream>>>(cntI, ptrI, bsum, n2);
    k_scanB<<<1, 64, 0, stream>>>(bsum, ptrI + n2, nb2);
    k_scanC<<<nb2, 1024, 0, stream>>>(ptrI, bsum, n2);
    k_fill<<<gridE, 256, 0, stream>>>(esrc, edst, rankE, rankS, cntD16, cntS16,
            ptrI, degU, srcC, dstC, dstS, wU, E, N, WD, EC);

    // ---- h = relu(BN(x) @ W_feat) -> B1 (bf16) ----
    k_gemm<1, 0><<<gridG, 256, 0, stream>>>(x, nullptr, 0, stZ, whiT, wloT, B1, 128, 0, N);

    // ---- 3 x [BN -> GCNConv -> relu], prep fused into last gather ----
    for (int i = 0; i < 3; ++i){
        float* st = stZ + 256 * (i + 1);
        k_statsB<<<256, 256, 0, stream>>>(B1, st, N);
        k_gemm<0, 1><<<gridG, 256, 0, stream>>>(B1, nullptr, 0, st,
                whiT + (size_t)(i + 1) * 16384, wloT + (size_t)(i + 1) * 16384,
                B0, 128, 0, N);
        if (i < 2)
            k_gather0<0><<<gridW, 256, 0, stream>>>(ptrI, srcC, wU, degU, B0,
                    cbs + i * 128, B1, eW, naW, epre, ntT, N);
        else
            k_gather0<1><<<gridW, 256, 0, stream>>>(ptrI, srcC, wU, degU, B0,
                    cbs + i * 128, B1, eW, naW, epre, ntT, N);
    }

    // ---- attention: natt | eatt | degC0 merged (no atomics) ----
    k_eattnatt<<<gridN + gridE + gridN, 256, 0, stream>>>(srcC, dstC, dstS, epre, ebv,
            wB0, wB1, degC0, ptrI, wU, degU, ntT, nab, natt, E, N, gridN, gridE);

    // ---- branch stats (vectorized) | branch weights merged ----
    k_stats2wB<<<256 + gridE, 256, 0, stream>>>(B1, natt, stZ + 1024, N,
            srcC, degC0, degU, wB0, wB1, E);

    // ---- dual branch GEMM into B0c, then ONE branch-split gather ----
    k_gemm2<<<dim3(gridG, 2), 256, 0, stream>>>(B1, natt, stZ + 1024, whiT, wloT, B0c, N);
    k_gatherP2<<<2 * gridP, 256, 0, stream>>>(ptrI, srcC, wB0, wB1, degC0, degU, B0c,
                                              xcb, xob, batch, xcp, xop, N, span);

    // ---- heads: 3 heads fused per stage ----
    k_gstats3<<<3, 1024, 0, stream>>>(xcp, xop, mrsH, G);
    k_hgemm3<<<dim3(G, 3), 128, 0, stream>>>(xcp, xop, mrsH, cW1, cb1, oW1, ob1,
                                             coW1, cob1, gt3);
    k_gstats3b<<<3, 1024, 0, stream>>>(gt3, mrsH2, G);
    k_hfinal3<<<dim3((G + 3) / 4, 3), 256, 0, stream>>>(gt3, mrsH2, cW2, cb2, oW2, ob2,
                                                        coW2, cob2, out, G);
}

// Round 9
// 549.218 us; speedup vs baseline: 1.8216x; 1.0167x over previous
//
#include <hip/hip_runtime.h>

// CausalGCN forward on MI355X. fp32 in/out; internal N x 128 tensors bf16.
// R16 = R15 + persistent-wave grid-stride gathers: launch exactly 8192 waves
//       (2048 blocks, 8/CU -> 32 waves/CU resident for the whole kernel);
//       each wave strides over span-chunks (gatherP2) / nodes (gather0).
//       Theory: 62% time-avg occupancy was multi-round drain, not a cap.

typedef unsigned short bf16_t;
typedef unsigned int   uint32;
typedef __attribute__((ext_vector_type(8))) short   bf16x8;
typedef __attribute__((ext_vector_type(4))) float   f32x4;

#define CHNK 64

__device__ __forceinline__ float b2f(bf16_t v){ return __uint_as_float(((uint32)v) << 16); }
__device__ __forceinline__ bf16_t f2b(float f){
    uint32 u = __float_as_uint(f);
    return (bf16_t)((u + 0x7fffu + ((u >> 16) & 1u)) >> 16);   // RNE
}
__device__ __forceinline__ uint32 pack2(float lo, float hi){
    return (uint32)f2b(lo) | ((uint32)f2b(hi) << 16);
}
__device__ __forceinline__ float lo16(uint32 u){ return __uint_as_float(u << 16); }
__device__ __forceinline__ float hi16(uint32 u){ return __uint_as_float(u & 0xffff0000u); }
__device__ __forceinline__ int   rl (int v, int l){ return __builtin_amdgcn_readlane(v, l); }
__device__ __forceinline__ float rlf(float v, int l){
    return __int_as_float(__builtin_amdgcn_readlane(__float_as_int(v), l));
}

// ---------- prologue: hist (256 blocks) | wsplit (96) | statsF (256) ----------
// hist: block (side, chunk, half) counts its bin-half into LDS packed-uint16,
// LDS-atomic return = local rank. 50KB LDS (N <= 50176).
__global__ void k_prologue(const float* __restrict__ Wf, const float* __restrict__ cWs,
        const float* __restrict__ xcW, const float* __restrict__ xoW,
        bf16_t* __restrict__ whiT, bf16_t* __restrict__ wloT,
        const int* __restrict__ esrc, const int* __restrict__ edst,
        uint32* __restrict__ cntD16, uint32* __restrict__ cntS16,
        int* __restrict__ rankE, int* __restrict__ rankS, int e,
        const float* __restrict__ x, float* __restrict__ st, int n, int WD)
{
    __shared__ uint32 h[12544];     // 50,176 B
    int bx = blockIdx.x, tid = threadIdx.x;
    if (bx < 256){
        int side = bx >> 7;          // 0: dst hist, 1: src hist
        int sub = bx & 127;
        int c = sub >> 1, hh = sub & 1;
        int Nh = ((n + 3) / 4) * 2;  // even split point
        int lo = hh ? Nh : 0;
        int hi = hh ? n : Nh;
        int w0 = lo >> 1;
        int nw = (hi - lo + 1) >> 1;
        for (int j = tid; j < nw; j += 256) h[j] = 0;
        __syncthreads();
        int EC = (e + CHNK - 1) / CHNK;
        int beg = c * EC, endE = min(e, beg + EC);
        const int* keys = side ? esrc : edst;
        int* rank = side ? rankS : rankE;
        for (int i = beg + tid; i < endE; i += 256){
            int d = keys[i];
            if (d >= lo && d < hi){
                int w = (d >> 1) - w0;
                int sh = (d & 1) * 16;
                uint32 old = atomicAdd(&h[w], 1u << sh);
                rank[i] = (int)((old >> sh) & 0xffffu);
            }
        }
        __syncthreads();
        uint32* table = side ? cntS16 : cntD16;
        for (int j = tid; j < nw; j += 256)
            table[(size_t)c * WD + w0 + j] = h[j];
    } else if (bx < 352){
        // W pre-split: fp32 [k][n] -> bf16 hi/lo transposed [n][k], 6 matrices
        int ms = bx - 256;
        int mat = ms >> 4, sub = ms & 15;
        const float* src = (mat == 0) ? Wf : (mat <= 3) ? cWs + (size_t)(mat - 1) * 16384
                          : (mat == 4) ? xcW : xoW;
        int i = (sub * 256 + tid) * 4;
        int nrow = i >> 7, k0 = i & 127;
        size_t off = (size_t)mat * 16384 + (size_t)nrow * 128 + k0;
        #pragma unroll
        for (int j = 0; j < 4; ++j){
            float w = src[(size_t)(k0 + j) * 128 + nrow];
            bf16_t hb = f2b(w);
            whiT[off + j] = hb;
            wloT[off + j] = f2b(w - b2f(hb));
        }
    } else {
        int bb = bx - 352;
        float* red = (float*)h;      // overlay: [2][8][128]
        int f4 = (tid & 31) * 4, slice = tid >> 5;
        float s[4] = {0,0,0,0}, q[4] = {0,0,0,0};
        for (int row = bb * 8 + slice; row < n; row += 2048){
            float4 v = *(const float4*)&x[(size_t)row * 128 + f4];
            s[0]+=v.x; q[0]+=v.x*v.x; s[1]+=v.y; q[1]+=v.y*v.y;
            s[2]+=v.z; q[2]+=v.z*v.z; s[3]+=v.w; q[3]+=v.w*v.w;
        }
        #pragma unroll
        for (int j = 0; j < 4; ++j){
            red[slice * 128 + f4 + j] = s[j];
            red[1024 + slice * 128 + f4 + j] = q[j];
        }
        __syncthreads();
        if (tid < 128){
            float ts=0.f, tq=0.f;
            #pragma unroll
            for (int w = 0; w < 8; ++w){ ts += red[w*128+tid]; tq += red[1024+w*128+tid]; }
            atomicAdd(&st[tid], ts); atomicAdd(&st[128+tid], tq);
        }
    }
}

// ---------- chunk-offset scan: per-bin exclusive prefix over chunks, totals out ----------
__global__ void k_chunkscan(uint32* __restrict__ cntD16, uint32* __restrict__ cntS16,
        int* __restrict__ cntI, float* __restrict__ degUf, int WD, int n)
{
    int g = blockIdx.x * 256 + threadIdx.x;
    if (g >= 2 * WD) return;
    int side = (g >= WD);
    int w = side ? g - WD : g;
    uint32* tab = side ? cntS16 : cntD16;
    uint32 r0 = 0, r1 = 0;
    for (int c = 0; c < CHNK; ++c){
        size_t idx = (size_t)c * WD + w;
        uint32 v = tab[idx];
        tab[idx] = r0 | (r1 << 16);
        r0 += v & 0xffffu; r1 += v >> 16;
    }
    int b0 = 2 * w, b1 = 2 * w + 1;
    if (!side){
        if (b0 < n) cntI[b0] = (int)r0;
        if (b1 < n) cntI[b1] = (int)r1;
    } else {
        if (b0 < n){ cntI[n + b0] = (int)r0; degUf[b0] = (float)r0; }
        if (b1 < n){ cntI[n + b1] = (int)r1; degUf[b1] = (float)r1; }
    }
}

// ---------- BN stats: uint4 loads, LDS slice reduce ----------
__global__ __launch_bounds__(256) void k_statsB(const bf16_t* __restrict__ a,
        float* __restrict__ st, int n){
    __shared__ float red[2][16][128];
    int tid = threadIdx.x;
    int c8 = (tid & 15) * 8, slice = tid >> 4;
    float s[8] = {0,0,0,0,0,0,0,0}, q[8] = {0,0,0,0,0,0,0,0};
    for (int row = blockIdx.x * 16 + slice; row < n; row += 4096){
        uint4 v = *(const uint4*)&a[(size_t)row * 128 + c8];
        const bf16_t* pv = (const bf16_t*)&v;
        #pragma unroll
        for (int j = 0; j < 8; ++j){ float f = b2f(pv[j]); s[j] += f; q[j] += f * f; }
    }
    #pragma unroll
    for (int j = 0; j < 8; ++j){ red[0][slice][c8+j]=s[j]; red[1][slice][c8+j]=q[j]; }
    __syncthreads();
    if (tid < 128){
        float ts=0.f, tq=0.f;
        #pragma unroll
        for (int w = 0; w < 16; ++w){ ts += red[0][w][tid]; tq += red[1][w][tid]; }
        atomicAdd(&st[tid], ts); atomicAdd(&st[128+tid], tq);
    }
}

// ---------- MFMA GEMM: C[n, ccol0..+128 of ldc] = act( BN(scale*A) @ W ) ----------
template<int ACT, int INBF>  // ACT: 1=relu ; INBF: input bf16?
__global__ __launch_bounds__(256, 3) void k_gemm(const void* __restrict__ Av,
        const float* __restrict__ scale, int sch,
        const float* __restrict__ st, const bf16_t* __restrict__ WhiT,
        const bf16_t* __restrict__ WloT,
        bf16_t* __restrict__ C, int ldc, int ccol0, int n)
{
    __shared__ bf16_t As[64 * 136];
    __shared__ bf16_t Whi[128 * 72];
    __shared__ bf16_t Wlo[128 * 72];
    int tid = threadIdx.x;
    int wid = tid >> 6, lane = tid & 63;
    int row0 = blockIdx.x * 64;
    int m0 = wid * 16;
    int q8 = (lane >> 4) * 8, l15 = lane & 15;

    int c8t = (tid & 15) * 8;
    float sM[8], sR[8];
    #pragma unroll
    for (int j = 0; j < 8; ++j){
        float m = st[c8t + j] / n;
        float var = st[128 + c8t + j] / n - m * m;
        sM[j] = m; sR[j] = rsqrtf(var + 1e-5f);
    }

    for (int i = tid; i < 64 * 16; i += 256){
        int r = i >> 4, c8 = (i & 15) * 8;
        int gr = row0 + r;
        float v[8];
        if (gr < n){
            float sc = scale ? scale[(size_t)gr * 2 + sch] : 1.f;
            if (INBF){
                const bf16_t* Ab = (const bf16_t*)Av;
                ushort4 qa = *(const ushort4*)&Ab[(size_t)gr * 128 + c8];
                ushort4 qb = *(const ushort4*)&Ab[(size_t)gr * 128 + c8 + 4];
                v[0]=b2f(qa.x); v[1]=b2f(qa.y); v[2]=b2f(qa.z); v[3]=b2f(qa.w);
                v[4]=b2f(qb.x); v[5]=b2f(qb.y); v[6]=b2f(qb.z); v[7]=b2f(qb.w);
            } else {
                const float* Af = (const float*)Av;
                float4 fa = *(const float4*)&Af[(size_t)gr * 128 + c8];
                float4 fb = *(const float4*)&Af[(size_t)gr * 128 + c8 + 4];
                v[0]=fa.x; v[1]=fa.y; v[2]=fa.z; v[3]=fa.w;
                v[4]=fb.x; v[5]=fb.y; v[6]=fb.z; v[7]=fb.w;
            }
            #pragma unroll
            for (int j = 0; j < 8; ++j)
                v[j] = (v[j] * sc - sM[j]) * sR[j] + 1e-4f;
        } else {
            #pragma unroll
            for (int j = 0; j < 8; ++j) v[j] = 0.f;
        }
        #pragma unroll
        for (int j = 0; j < 8; ++j) As[r * 136 + c8 + j] = f2b(v[j]);
    }

    f32x4 acc[8];
    #pragma unroll
    for (int t = 0; t < 8; ++t) acc[t] = (f32x4){0.f, 0.f, 0.f, 0.f};

    for (int kc = 0; kc < 128; kc += 64){
        __syncthreads();
        for (int i = tid; i < 128 * 8; i += 256){
            int nrow = i >> 3, k8 = (i & 7) * 8;
            *(uint4*)&Whi[nrow * 72 + k8] = *(const uint4*)&WhiT[(size_t)nrow * 128 + kc + k8];
            *(uint4*)&Wlo[nrow * 72 + k8] = *(const uint4*)&WloT[(size_t)nrow * 128 + kc + k8];
        }
        __syncthreads();
        #pragma unroll
        for (int kbl = 0; kbl < 2; ++kbl){
            bf16x8 a = *(const bf16x8*)&As[(m0 + l15) * 136 + kc + kbl * 32 + q8];
            #pragma unroll
            for (int nt = 0; nt < 8; ++nt){
                bf16x8 bh = *(const bf16x8*)&Whi[(nt * 16 + l15) * 72 + kbl * 32 + q8];
                acc[nt] = __builtin_amdgcn_mfma_f32_16x16x32_bf16(a, bh, acc[nt], 0, 0, 0);
                bf16x8 bl = *(const bf16x8*)&Wlo[(nt * 16 + l15) * 72 + kbl * 32 + q8];
                acc[nt] = __builtin_amdgcn_mfma_f32_16x16x32_bf16(a, bl, acc[nt], 0, 0, 0);
            }
        }
    }

    __syncthreads();
    #pragma unroll
    for (int nt = 0; nt < 8; ++nt){
        #pragma unroll
        for (int r = 0; r < 4; ++r){
            float v = acc[nt][r];
            if (ACT == 1) v = fmaxf(v, 0.f);
            As[(m0 + (lane >> 4) * 4 + r) * 136 + nt * 16 + l15] = f2b(v);
        }
    }
    __syncthreads();
    for (int i = tid; i < 64 * 16; i += 256){
        int r = i >> 4, c8 = (i & 15) * 8;
        int gr = row0 + r;
        if (gr < n)
            *(uint4*)&C[(size_t)gr * ldc + ccol0 + c8] = *(const uint4*)&As[r * 136 + c8];
    }
}

// dual branch GEMM: blockIdx.y = branch (0:xc, 1:xo); input bf16, no act
__global__ __launch_bounds__(256, 3) void k_gemm2(const bf16_t* __restrict__ Ab,
        const float* __restrict__ natt, const float* __restrict__ stBase,
        const bf16_t* __restrict__ whiT6, const bf16_t* __restrict__ wloT6,
        bf16_t* __restrict__ C, int n)
{
    __shared__ bf16_t As[64 * 136];
    __shared__ bf16_t Whi[128 * 72];
    __shared__ bf16_t Wlo[128 * 72];
    int brn = blockIdx.y;
    const float* st = stBase + brn * 256;
    const bf16_t* WhiT = whiT6 + (size_t)(4 + brn) * 16384;
    const bf16_t* WloT = wloT6 + (size_t)(4 + brn) * 16384;
    int ccol0 = brn * 128;
    const int ldc = 256;

    int tid = threadIdx.x;
    int wid = tid >> 6, lane = tid & 63;
    int row0 = blockIdx.x * 64;
    int m0 = wid * 16;
    int q8 = (lane >> 4) * 8, l15 = lane & 15;

    int c8t = (tid & 15) * 8;
    float sM[8], sR[8];
    #pragma unroll
    for (int j = 0; j < 8; ++j){
        float m = st[c8t + j] / n;
        float var = st[128 + c8t + j] / n - m * m;
        sM[j] = m; sR[j] = rsqrtf(var + 1e-5f);
    }

    for (int i = tid; i < 64 * 16; i += 256){
        int r = i >> 4, c8 = (i & 15) * 8;
        int gr = row0 + r;
        float v[8];
        if (gr < n){
            float sc = natt[(size_t)gr * 2 + brn];
            ushort4 qa = *(const ushort4*)&Ab[(size_t)gr * 128 + c8];
            ushort4 qb = *(const ushort4*)&Ab[(size_t)gr * 128 + c8 + 4];
            v[0]=b2f(qa.x); v[1]=b2f(qa.y); v[2]=b2f(qa.z); v[3]=b2f(qa.w);
            v[4]=b2f(qb.x); v[5]=b2f(qb.y); v[6]=b2f(qb.z); v[7]=b2f(qb.w);
            #pragma unroll
            for (int j = 0; j < 8; ++j)
                v[j] = (v[j] * sc - sM[j]) * sR[j] + 1e-4f;
        } else {
            #pragma unroll
            for (int j = 0; j < 8; ++j) v[j] = 0.f;
        }
        #pragma unroll
        for (int j = 0; j < 8; ++j) As[r * 136 + c8 + j] = f2b(v[j]);
    }

    f32x4 acc[8];
    #pragma unroll
    for (int t = 0; t < 8; ++t) acc[t] = (f32x4){0.f, 0.f, 0.f, 0.f};

    for (int kc = 0; kc < 128; kc += 64){
        __syncthreads();
        for (int i = tid; i < 128 * 8; i += 256){
            int nrow = i >> 3, k8 = (i & 7) * 8;
            *(uint4*)&Whi[nrow * 72 + k8] = *(const uint4*)&WhiT[(size_t)nrow * 128 + kc + k8];
            *(uint4*)&Wlo[nrow * 72 + k8] = *(const uint4*)&WloT[(size_t)nrow * 128 + kc + k8];
        }
        __syncthreads();
        #pragma unroll
        for (int kbl = 0; kbl < 2; ++kbl){
            bf16x8 a = *(const bf16x8*)&As[(m0 + l15) * 136 + kc + kbl * 32 + q8];
            #pragma unroll
            for (int nt = 0; nt < 8; ++nt){
                bf16x8 bh = *(const bf16x8*)&Whi[(nt * 16 + l15) * 72 + kbl * 32 + q8];
                acc[nt] = __builtin_amdgcn_mfma_f32_16x16x32_bf16(a, bh, acc[nt], 0, 0, 0);
                bf16x8 bl = *(const bf16x8*)&Wlo[(nt * 16 + l15) * 72 + kbl * 32 + q8];
                acc[nt] = __builtin_amdgcn_mfma_f32_16x16x32_bf16(a, bl, acc[nt], 0, 0, 0);
            }
        }
    }

    __syncthreads();
    #pragma unroll
    for (int nt = 0; nt < 8; ++nt){
        #pragma unroll
        for (int r = 0; r < 4; ++r){
            As[(m0 + (lane >> 4) * 4 + r) * 136 + nt * 16 + l15] = f2b(acc[nt][r]);
        }
    }
    __syncthreads();
    for (int i = tid; i < 64 * 16; i += 256){
        int r = i >> 4, c8 = (i & 15) * 8;
        int gr = row0 + r;
        if (gr < n)
            *(uint4*)&C[(size_t)gr * ldc + ccol0 + c8] = *(const uint4*)&As[r * 136 + c8];
    }
}

// ---------- CSR scan (joint: dst counts then src counts, 2N) ----------
__global__ __launch_bounds__(1024) void k_scanA(const int* __restrict__ cnt,
        int* __restrict__ ptr, int* __restrict__ bsum, int n){
    __shared__ int wsum[16];
    int t = threadIdx.x, lane = t & 63, wid = t >> 6;
    int i = blockIdx.x * 1024 + t;
    int v = (i < n) ? cnt[i] : 0;
    int s = v;
    for (int off = 1; off < 64; off <<= 1){
        int u = __shfl_up(s, off);
        if (lane >= off) s += u;
    }
    if (lane == 63) wsum[wid] = s;
    __syncthreads();
    if (wid == 0 && lane < 16){
        int ws = wsum[lane];
        for (int off = 1; off < 16; off <<= 1){
            int u = __shfl_up(ws, off);
            if (lane >= off) ws += u;
        }
        wsum[lane] = ws;
    }
    __syncthreads();
    int woff = wid ? wsum[wid - 1] : 0;
    if (i < n) ptr[i] = woff + s - v;
    if (t == 1023) bsum[blockIdx.x] = woff + s;
}
__global__ void k_scanB(int* __restrict__ bsum, int* __restrict__ ptrN, int nb){
    int lane = threadIdx.x;       // 64 threads
    int carry = 0;
    for (int base = 0; base < nb; base += 64){
        int i = base + lane;
        int v = (i < nb) ? bsum[i] : 0;
        int s = v;
        for (int off = 1; off < 64; off <<= 1){
            int u = __shfl_up(s, off);
            if (lane >= off) s += u;
        }
        if (i < nb) bsum[i] = carry + s - v;
        carry += __shfl(s, 63);
    }
    if (lane == 0) *ptrN = carry;
}
__global__ __launch_bounds__(1024) void k_scanC(int* __restrict__ ptr,
        const int* __restrict__ bsum, int n){
    int i = blockIdx.x * 1024 + threadIdx.x;
    if (i < n) ptr[i] += bsum[blockIdx.x];
}
// atomic-free CSR fill: slot = ptr + chunkOff + localRank (both CSRs)
__global__ void k_fill(const int* __restrict__ esrc, const int* __restrict__ edst,
        const int* __restrict__ rankE, const int* __restrict__ rankS,
        const uint32* __restrict__ cntD16, const uint32* __restrict__ cntS16,
        const int* __restrict__ ptr, const float* __restrict__ degUf,
        int* __restrict__ srcC, int* __restrict__ dstC, int* __restrict__ dstS,
        float* __restrict__ wU, int e, int n, int WD, int EC)
{
    int i = blockIdx.x * 256 + threadIdx.x;
    if (i >= e) return;
    int s = esrc[i], d = edst[i];
    int c = i / EC;
    uint32 pw = cntD16[(size_t)c * WD + (d >> 1)];
    int offD = (d & 1) ? (int)(pw >> 16) : (int)(pw & 0xffffu);
    int dslot = ptr[d] + offD + rankE[i];
    uint32 sw = cntS16[(size_t)c * WD + (s >> 1)];
    int offS = (s & 1) ? (int)(sw >> 16) : (int)(sw & 0xffffu);
    int sslot = (ptr[n + s] - e) + offS + rankS[i];
    srcC[dslot] = s;
    dstC[dslot] = d;
    wU[dslot] = rsqrtf(degUf[s] + 1.0f);
    dstS[sslot] = d;
}

// ---------- conv propagate: persistent waves, node-strided; optional fused prep ----------
template<int PREP>
__global__ __launch_bounds__(256) void k_gather0(const int* __restrict__ ptr,
        const int* __restrict__ srcC, const float* __restrict__ wE,
        const float* __restrict__ degU, const bf16_t* __restrict__ t,
        const float* __restrict__ bias, bf16_t* __restrict__ outB,
        const float* __restrict__ eW, const float* __restrict__ naW,
        float4* __restrict__ epre, float* __restrict__ ntT, int n, int nwaves)
{
    int wid = blockIdx.x * 4 + (threadIdx.x >> 6);
    int lane = threadIdx.x & 63;
    const uint32* T = (const uint32*)t;
    float bias0 = bias[2 * lane], bias1 = bias[2 * lane + 1];
    for (int node = wid; node < n; node += nwaves){
        float dd = rsqrtf(degU[node] + 1.0f);
        uint32 sv = T[(size_t)node * 64 + lane];
        float a0 = 0.f, a1 = 0.f;
        int k = ptr[node], end = ptr[node + 1];
        while (k < end){
            int cnt = min(end - k, 64);
            int kl = k + min(lane, cnt - 1);
            int   myI = srcC[kl];
            float myW = wE[kl];
            int j = 0;
            for (; j + 8 <= cnt; j += 8){
                int s0 = rl(myI, j),     s1 = rl(myI, j + 1), s2 = rl(myI, j + 2), s3 = rl(myI, j + 3);
                int s4 = rl(myI, j + 4), s5 = rl(myI, j + 5), s6 = rl(myI, j + 6), s7 = rl(myI, j + 7);
                float w0 = rlf(myW, j),     w1 = rlf(myW, j + 1), w2 = rlf(myW, j + 2), w3 = rlf(myW, j + 3);
                float w4 = rlf(myW, j + 4), w5 = rlf(myW, j + 5), w6 = rlf(myW, j + 6), w7 = rlf(myW, j + 7);
                uint32 v0 = T[(size_t)s0 * 64 + lane];
                uint32 v1 = T[(size_t)s1 * 64 + lane];
                uint32 v2 = T[(size_t)s2 * 64 + lane];
                uint32 v3 = T[(size_t)s3 * 64 + lane];
                uint32 v4 = T[(size_t)s4 * 64 + lane];
                uint32 v5 = T[(size_t)s5 * 64 + lane];
                uint32 v6 = T[(size_t)s6 * 64 + lane];
                uint32 v7 = T[(size_t)s7 * 64 + lane];
                a0 += w0 * lo16(v0) + w1 * lo16(v1) + w2 * lo16(v2) + w3 * lo16(v3);
                a1 += w0 * hi16(v0) + w1 * hi16(v1) + w2 * hi16(v2) + w3 * hi16(v3);
                a0 += w4 * lo16(v4) + w5 * lo16(v5) + w6 * lo16(v6) + w7 * lo16(v7);
                a1 += w4 * hi16(v4) + w5 * hi16(v5) + w6 * hi16(v6) + w7 * hi16(v7);
            }
            for (; j < cnt; ++j){
                int s = rl(myI, j);
                float w = rlf(myW, j);
                uint32 v = T[(size_t)s * 64 + lane];
                a0 += w * lo16(v); a1 += w * hi16(v);
            }
            k += cnt;
        }
        a0 = fmaxf(dd * (a0 + dd * lo16(sv)) + bias0, 0.f);
        a1 = fmaxf(dd * (a1 + dd * hi16(sv)) + bias1, 0.f);
        ((uint32*)outB)[(size_t)node * 64 + lane] = pack2(a0, a1);
        if (PREP){
            // lane holds feats (2*lane, 2*lane+1) = (a0, a1).
            // eW row f at float offset 2f; dst-half rows 128+f at 256+2f.
            float s0 = a0 * eW[4 * lane]           + a1 * eW[4 * lane + 2];
            float s1 = a0 * eW[4 * lane + 1]       + a1 * eW[4 * lane + 3];
            float d0 = a0 * eW[256 + 4 * lane]     + a1 * eW[256 + 4 * lane + 2];
            float d1 = a0 * eW[256 + 4 * lane + 1] + a1 * eW[256 + 4 * lane + 3];
            float n0 = a0 * naW[4 * lane]          + a1 * naW[4 * lane + 2];
            float n1 = a0 * naW[4 * lane + 1]      + a1 * naW[4 * lane + 3];
            for (int off = 32; off; off >>= 1){
                s0 += __shfl_xor(s0, off); s1 += __shfl_xor(s1, off);
                d0 += __shfl_xor(d0, off); d1 += __shfl_xor(d1, off);
                n0 += __shfl_xor(n0, off); n1 += __shfl_xor(n1, off);
            }
            if (lane == 0){
                epre[node] = make_float4(s0, s1, d0, d1);
                ntT[2 * node] = n0; ntT[2 * node + 1] = n1;
            }
        }
    }
}

// ---------- branch propagate: persistent waves, span-strided; degC1 = degU - degC0 ----
__global__ __launch_bounds__(256) void k_gatherP2(const int* __restrict__ ptr,
        const int* __restrict__ srcC, const float* __restrict__ w0E,
        const float* __restrict__ w1E, const float* __restrict__ degC0,
        const float* __restrict__ degU, const bf16_t* __restrict__ t,
        const float* __restrict__ biasC, const float* __restrict__ biasO,
        const int* __restrict__ batch, float* __restrict__ pool0,
        float* __restrict__ pool1, int n, int span, int nwb)
{
    int br  = blockIdx.x & 1;
    int wvb = (blockIdx.x >> 1) * 4 + (threadIdx.x >> 6);   // wave idx within branch
    int lane = threadIdx.x & 63;
    const float* wE   = br ? w1E : w0E;
    const float* bias = br ? biasO : biasC;
    float* pool       = br ? pool1 : pool0;
    float b0 = bias[2 * lane], b1 = bias[2 * lane + 1];
    const uint32* T = (const uint32*)t;       // B0c row = 128 uint32
    int rowoff = (br ? 64 : 0) + lane;
    int nspans = (n + span - 1) / span;
    for (int sp = wvb; sp < nspans; sp += nwb){
        int nbeg = sp * span;
        int nend = min(n, nbeg + span);
        int curG = -1;
        float p0 = 0.f, p1 = 0.f;
        for (int node = nbeg; node < nend; ++node){
            float d0v = degC0[node];
            float dv  = br ? (degU[node] - d0v) : d0v;
            float dd  = rsqrtf(dv + 1.0f);
            uint32 sv = T[(size_t)node * 128 + rowoff];
            float a0 = 0.f, a1 = 0.f;
            int k = ptr[node], end = ptr[node + 1];
            while (k < end){
                int cnt = min(end - k, 64);
                int kl = k + min(lane, cnt - 1);
                int   myI = srcC[kl];
                float myW = wE[kl];
                int j = 0;
                for (; j + 8 <= cnt; j += 8){
                    int s0 = rl(myI, j),     s1 = rl(myI, j + 1), s2 = rl(myI, j + 2), s3 = rl(myI, j + 3);
                    int s4 = rl(myI, j + 4), s5 = rl(myI, j + 5), s6 = rl(myI, j + 6), s7 = rl(myI, j + 7);
                    float w0 = rlf(myW, j),     w1 = rlf(myW, j + 1), w2 = rlf(myW, j + 2), w3 = rlf(myW, j + 3);
                    float w4 = rlf(myW, j + 4), w5 = rlf(myW, j + 5), w6 = rlf(myW, j + 6), w7 = rlf(myW, j + 7);
                    uint32 v0 = T[(size_t)s0 * 128 + rowoff];
                    uint32 v1 = T[(size_t)s1 * 128 + rowoff];
                    uint32 v2 = T[(size_t)s2 * 128 + rowoff];
                    uint32 v3 = T[(size_t)s3 * 128 + rowoff];
                    uint32 v4 = T[(size_t)s4 * 128 + rowoff];
                    uint32 v5 = T[(size_t)s5 * 128 + rowoff];
                    uint32 v6 = T[(size_t)s6 * 128 + rowoff];
                    uint32 v7 = T[(size_t)s7 * 128 + rowoff];
                    a0 += w0 * lo16(v0) + w1 * lo16(v1) + w2 * lo16(v2) + w3 * lo16(v3);
                    a1 += w0 * hi16(v0) + w1 * hi16(v1) + w2 * hi16(v2) + w3 * hi16(v3);
                    a0 += w4 * lo16(v4) + w5 * lo16(v5) + w6 * lo16(v6) + w7 * lo16(v7);
                    a1 += w4 * hi16(v4) + w5 * hi16(v5) + w6 * hi16(v6) + w7 * hi16(v7);
                }
                for (; j < cnt; ++j){
                    int s = rl(myI, j);
                    float w = rlf(myW, j);
                    uint32 v = T[(size_t)s * 128 + rowoff];
                    a0 += w * lo16(v); a1 += w * hi16(v);
                }
                k += cnt;
            }
            a0 = dd * (a0 + dd * lo16(sv)) + b0;
            a1 = dd * (a1 + dd * hi16(sv)) + b1;
            a0 = a0 > 0.f ? a0 : expm1f(a0);
            a1 = a1 > 0.f ? a1 : expm1f(a1);
            int g = batch[node];
            if (g != curG){
                if (curG >= 0){
                    float* p = pool + (size_t)curG * 128 + 2 * lane;
                    atomicAdd(&p[0], p0); atomicAdd(&p[1], p1);
                }
                curG = g; p0 = a0; p1 = a1;
            } else {
                p0 += a0; p1 += a1;
            }
        }
        if (curG >= 0){
            float* p = pool + (size_t)curG * 128 + 2 * lane;
            atomicAdd(&p[0], p0); atomicAdd(&p[1], p1);
        }
    }
}

// ---------- attention: natt | eatt (no atomic) | degC0 (src-CSR recompute) ----------
__global__ void k_eattnatt(const int* __restrict__ srcC, const int* __restrict__ dstC,
        const int* __restrict__ dstS,
        const float4* __restrict__ epre, const float* __restrict__ eb,
        float* __restrict__ wB0, float* __restrict__ wB1,
        float* __restrict__ degC0,
        const int* __restrict__ ptr, const float* __restrict__ wU,
        const float* __restrict__ degU, const float* __restrict__ ntT,
        const float* __restrict__ nab, float* __restrict__ natt,
        int e, int n, int gridN, int gridE)
{
    int bx = blockIdx.x;
    if (bx < gridN){
        int i = bx * 256 + threadIdx.x;
        if (i >= n) return;
        float dd = rsqrtf(degU[i] + 1.0f);
        float z0 = 0.f, z1 = 0.f;
        int end = ptr[i + 1];
        for (int k = ptr[i]; k < end; ++k){
            int s = srcC[k];
            float w = wU[k];
            z0 += w * ntT[2 * s]; z1 += w * ntT[2 * s + 1];
        }
        z0 = dd * (z0 + dd * ntT[2 * i])     + nab[0];
        z1 = dd * (z1 + dd * ntT[2 * i + 1]) + nab[1];
        float m = fmaxf(z0, z1);
        float e0 = expf(z0 - m), e1 = expf(z1 - m);
        float inv = 1.f / (e0 + e1);
        natt[2 * i] = e0 * inv; natt[2 * i + 1] = e1 * inv;
    } else if (bx < gridN + gridE){
        int i = (bx - gridN) * 256 + threadIdx.x;
        if (i >= e) return;
        int s = srcC[i];
        float4 ps = epre[s], pd = epre[dstC[i]];
        float l0 = ps.x + pd.z + eb[0], l1 = ps.y + pd.w + eb[1];
        float m = fmaxf(l0, l1);
        float e0 = expf(l0 - m), e1 = expf(l1 - m);
        float inv = 1.f / (e0 + e1);
        wB0[i] = e0 * inv; wB1[i] = e1 * inv;
    } else {
        int s = (bx - gridN - gridE) * 256 + threadIdx.x;
        if (s >= n) return;
        float4 ps = epre[s];
        float eb0 = eb[0], eb1 = eb[1];
        int beg = ptr[n + s] - e, endk = ptr[n + s + 1] - e;
        float sum = 0.f;
        for (int k = beg; k < endk; ++k){
            int d = dstS[k];
            float4 pd = epre[d];
            float l0 = ps.x + pd.z + eb0, l1 = ps.y + pd.w + eb1;
            float m = fmaxf(l0, l1);
            float e0 = expf(l0 - m), e1v = expf(l1 - m);
            sum += e0 / (e0 + e1v);
        }
        degC0[s] = sum;
    }
}

// ---------- stats2 (256 blocks, vectorized) | wB (gridE blocks) ----------
__global__ void k_stats2wB(const bf16_t* __restrict__ a, const float* __restrict__ natt,
        float* __restrict__ st, int n,
        const int* __restrict__ srcC, const float* __restrict__ degC0,
        const float* __restrict__ degU, float* __restrict__ w0,
        float* __restrict__ w1, int e)
{
    __shared__ float red[2][16][128];
    int bx = blockIdx.x, tid = threadIdx.x;
    if (bx < 256){
        int c8 = (tid & 15) * 8, slice = tid >> 4;
        float s0[8]={0,0,0,0,0,0,0,0}, q0[8]={0,0,0,0,0,0,0,0};
        float s1[8]={0,0,0,0,0,0,0,0}, q1[8]={0,0,0,0,0,0,0,0};
        for (int row = bx * 16 + slice; row < n; row += 4096){
            uint4 v = *(const uint4*)&a[(size_t)row * 128 + c8];
            const bf16_t* pv = (const bf16_t*)&v;
            float2 w = *(const float2*)&natt[(size_t)row * 2];
            #pragma unroll
            for (int j = 0; j < 8; ++j){
                float f = b2f(pv[j]);
                float f0 = f * w.x, f1 = f * w.y;
                s0[j] += f0; q0[j] += f0 * f0;
                s1[j] += f1; q1[j] += f1 * f1;
            }
        }
        #pragma unroll
        for (int j = 0; j < 8; ++j){ red[0][slice][c8+j]=s0[j]; red[1][slice][c8+j]=q0[j]; }
        __syncthreads();
        if (tid < 128){
            float ts=0.f, tq=0.f;
            #pragma unroll
            for (int w = 0; w < 16; ++w){ ts += red[0][w][tid]; tq += red[1][w][tid]; }
            atomicAdd(&st[tid], ts); atomicAdd(&st[128+tid], tq);
        }
        __syncthreads();
        #pragma unroll
        for (int j = 0; j < 8; ++j){ red[0][slice][c8+j]=s1[j]; red[1][slice][c8+j]=q1[j]; }
        __syncthreads();
        if (tid < 128){
            float ts=0.f, tq=0.f;
            #pragma unroll
            for (int w = 0; w < 16; ++w){ ts += red[0][w][tid]; tq += red[1][w][tid]; }
            atomicAdd(&st[256+tid], ts); atomicAdd(&st[384+tid], tq);
        }
    } else {
        int i = (bx - 256) * 256 + tid;
        if (i < e){
            int s = srcC[i];
            float d0v = degC0[s];
            w0[i] *= rsqrtf(d0v + 1.0f);
            w1[i] *= rsqrtf(degU[s] - d0v + 1.0f);
        }
    }
}

// ---------- heads (G=512, fp32), 3 heads fused per stage ----------
__global__ __launch_bounds__(1024) void k_gstats3(const float* __restrict__ xcp,
        const float* __restrict__ xop, float* __restrict__ mrsH, int n){
    __shared__ float red[2][1024];
    int head = blockIdx.x;
    const float* a = (head == 1) ? xop : xcp;
    const float* b = (head == 0) ? xcp : xop;
    int f = (head == 2) ? 256 : 128;
    float* mrs = mrsH + head * 512;
    int col = threadIdx.x & (f - 1);
    int rpb = 1024 / f;
    int rw  = threadIdx.x / f;
    float s = 0.f, sq = 0.f;
    for (int r = rw; r < n; r += rpb){
        float v = (col < 128) ? a[(size_t)r * 128 + col] : b[(size_t)r * 128 + col - 128];
        s += v; sq += v * v;
    }
    red[0][threadIdx.x] = s; red[1][threadIdx.x] = sq;
    __syncthreads();
    if (threadIdx.x < (unsigned)f){
        float ts = 0.f, tq = 0.f;
        for (int w = 0; w < rpb; ++w){ ts += red[0][w * f + col]; tq += red[1][w * f + col]; }
        float m = ts / n, var = tq / n - m * m;
        mrs[col] = m; mrs[f + col] = rsqrtf(var + 1e-5f);
    }
}
__global__ __launch_bounds__(128) void k_hgemm3(const float* __restrict__ xcp,
        const float* __restrict__ xop, const float* __restrict__ mrsH,
        const float* __restrict__ cW1, const float* __restrict__ cb1,
        const float* __restrict__ oW1, const float* __restrict__ ob1,
        const float* __restrict__ coW1, const float* __restrict__ cob1,
        float* __restrict__ gt3)
{
    __shared__ float as[256];
    int head = blockIdx.y, row = blockIdx.x, tid = threadIdx.x;
    const float* a  = (head == 1) ? xop : xcp;
    const float* b2 = (head == 0) ? xcp : xop;
    int fin = (head == 2) ? 256 : 128;
    const float* mrs = mrsH + head * 512;
    const float* W  = (head == 0) ? cW1 : (head == 1) ? oW1 : coW1;
    const float* bb = (head == 0) ? cb1 : (head == 1) ? ob1 : cob1;
    float* o = gt3 + (size_t)head * 512 * 128;
    for (int i = tid; i < fin; i += 128){
        float v = (i < 128) ? a[(size_t)row * 128 + i] : b2[(size_t)row * 128 + i - 128];
        as[i] = (v - mrs[i]) * mrs[fin + i] + 1e-4f;
    }
    __syncthreads();
    float s = 0.f;
    for (int k = 0; k < fin; ++k) s += as[k] * W[k * 128 + tid];
    s += bb[tid];
    if (head < 2) s = fmaxf(s, 0.f);
    else { s = s > 0.f ? s : expm1f(s); s = s > 0.f ? s : expm1f(s); }
    o[(size_t)row * 128 + tid] = s;
}
__global__ __launch_bounds__(1024) void k_gstats3b(const float* __restrict__ gt3,
        float* __restrict__ mrsH2, int n){
    __shared__ float red[2][1024];
    int head = blockIdx.x;
    const float* a = gt3 + (size_t)head * 512 * 128;
    float* mrs = mrsH2 + head * 256;
    int col = threadIdx.x & 127;
    int rw  = threadIdx.x >> 7;    // 8 rows/block-pass
    float s = 0.f, sq = 0.f;
    for (int r = rw; r < n; r += 8){
        float v = a[(size_t)r * 128 + col];
        s += v; sq += v * v;
    }
    red[0][threadIdx.x] = s; red[1][threadIdx.x] = sq;
    __syncthreads();
    if (threadIdx.x < 128u){
        float ts = 0.f, tq = 0.f;
        for (int w = 0; w < 8; ++w){ ts += red[0][w * 128 + col]; tq += red[1][w * 128 + col]; }
        float m = ts / n, var = tq / n - m * m;
        mrs[col] = m; mrs[128 + col] = rsqrtf(var + 1e-5f);
    }
}
__global__ __launch_bounds__(256) void k_hfinal3(const float* __restrict__ gt3,
        const float* __restrict__ mrsH2,
        const float* __restrict__ cW2, const float* __restrict__ cb2,
        const float* __restrict__ oW2, const float* __restrict__ ob2,
        const float* __restrict__ coW2, const float* __restrict__ cob2,
        float* __restrict__ out, int nrows)
{
    int head = blockIdx.y;
    int row = blockIdx.x * 4 + (threadIdx.x >> 6);
    if (row >= nrows) return;
    int lane = threadIdx.x & 63;
    const float* a   = gt3 + (size_t)head * 512 * 128;
    const float* mrs = mrsH2 + head * 256;
    const float* W = (head == 0) ? cW2 : (head == 1) ? oW2 : coW2;
    const float* b = (head == 0) ? cb2 : (head == 1) ? ob2 : cob2;
    float* o = out + (size_t)head * nrows * 10;
    float v0 = (a[(size_t)row * 128 + lane]      - mrs[lane])      * mrs[128 + lane]      + 1e-4f;
    float v1 = (a[(size_t)row * 128 + 64 + lane] - mrs[64 + lane]) * mrs[128 + 64 + lane] + 1e-4f;
    float logit[10];
    #pragma unroll
    for (int c = 0; c < 10; ++c){
        float p = v0 * W[lane * 10 + c] + v1 * W[(lane + 64) * 10 + c];
        for (int off = 32; off; off >>= 1) p += __shfl_xor(p, off);
        logit[c] = p + b[c];
    }
    float m = logit[0];
    #pragma unroll
    for (int c = 1; c < 10; ++c) m = fmaxf(m, logit[c]);
    float s = 0.f;
    #pragma unroll
    for (int c = 0; c < 10; ++c) s += expf(logit[c] - m);
    float lse = logf(s);
    if (lane < 10) o[row * 10 + lane] = logit[lane] - m - lse;
}

extern "C" void kernel_launch(void* const* d_in, const int* in_sizes, int n_in,
                              void* d_out, int out_size, void* d_ws, size_t ws_size,
                              hipStream_t stream)
{
    const int N = in_sizes[0] / 128;
    const int E = in_sizes[24];
    const int G = 512;
    const float* x    = (const float*)d_in[0];
    const float* Wf   = (const float*)d_in[1];
    const float* cWs  = (const float*)d_in[2];
    const float* cbs  = (const float*)d_in[3];
    const float* eW   = (const float*)d_in[4];
    const float* ebv  = (const float*)d_in[5];
    const float* naW  = (const float*)d_in[6];
    const float* nab  = (const float*)d_in[7];
    const float* xcW  = (const float*)d_in[8];
    const float* xcb  = (const float*)d_in[9];
    const float* xoW  = (const float*)d_in[10];
    const float* xob  = (const float*)d_in[11];
    const float* cW1  = (const float*)d_in[12];
    const float* cb1  = (const float*)d_in[13];
    const float* cW2  = (const float*)d_in[14];
    const float* cb2  = (const float*)d_in[15];
    const float* oW1  = (const float*)d_in[16];
    const float* ob1  = (const float*)d_in[17];
    const float* oW2  = (const float*)d_in[18];
    const float* ob2  = (const float*)d_in[19];
    const float* coW1 = (const float*)d_in[20];
    const float* cob1 = (const float*)d_in[21];
    const float* coW2 = (const float*)d_in[22];
    const float* cob2 = (const float*)d_in[23];
    const int* esrc  = (const int*)d_in[24];
    const int* edst  = (const int*)d_in[25];
    const int* batch = (const int*)d_in[26];
    float* out = (float*)d_out;

    const int WD = (N + 1) / 2;              // packed words per histogram row
    const int EC = (E + CHNK - 1) / CHNK;    // edges per chunk

    size_t NH = (size_t)N * 128;
    bf16_t* B1  = (bf16_t*)d_ws;            // N*128
    bf16_t* B0  = B1 + NH;                  // N*128
    bf16_t* B0c = B0 + NH;                  // N*256 ([xc|xo])
    float* fbase = (float*)(B0c + 2 * NH);
    float* epreF = fbase;                   // 4N
    float* ntT   = epreF + 4 * (size_t)N;
    float* natt  = ntT + 2 * (size_t)N;
    float* mrsH  = natt + 2 * (size_t)N;    // 1536 (3 heads x 512)
    float* mrsH2 = mrsH + 1536;             // 768  (3 heads x 256)
    float* wU    = mrsH2 + 768;             // E (CSR order)
    float* wB0   = wU + E;                  // E
    float* wB1   = wB0 + E;                 // E
    float* gt3   = wB1 + E;                 // 3*G*128
    float* degU  = gt3 + (size_t)3 * G * 128; // N (float out-degree, from src hist)
    float* degC0 = degU + N;                // N (written by eattnatt)
    // zero zone: stZ + pools
    float* stZ   = degC0 + N;               // 1536
    float* xcp   = stZ + 1536;              // G*128
    float* xop   = xcp + (size_t)G * 128;   // G*128
    size_t zzBytes = (1536 + 2 * (size_t)G * 128) * 4;
    int* cntI   = (int*)(xop + (size_t)G * 128);   // 2N (totals, from chunkscan)
    int* ptrI   = cntI + 2 * N;             // 2N+1 (joint scan)
    int* srcC   = ptrI + 2 * N + 1;         // E
    int* dstC   = srcC + E;                 // E
    int* dstS   = dstC + E;                 // E (dst node per src-CSR slot)
    int* rankE  = dstS + E;                 // E (local dst rank)
    int* rankS  = rankE + E;                // E (local src rank)
    int* bsum   = rankS + E;                // up to 128
    uint32* cntD16 = (uint32*)(bsum + 128); // CHNK*WD
    uint32* cntS16 = cntD16 + (size_t)CHNK * WD;
    bf16_t* whiT = (bf16_t*)((((size_t)(cntS16 + (size_t)CHNK * WD)) + 15) & ~(size_t)15);
    bf16_t* wloT = whiT + 6 * 16384;
    float4* epre = (float4*)epreF;

    int gridE = (E + 255) / 256;
    int gridN = (N + 255) / 256;
    int gridG = (N + 63) / 64;
    int n2    = 2 * N;
    int nb2   = (n2 + 1023) / 1024;
    int gridCS = (2 * WD + 255) / 256;
    int span  = 4;
    // persistent-wave gathers: 2048 blocks = 8192 waves = 32 waves/CU resident
    const int PW_BLOCKS = 2048;
    const int NWAVES = PW_BLOCKS * 4;           // gather0 stride
    const int NWB = (PW_BLOCKS / 2) * 4;        // gatherP2 waves per branch

    hipMemsetAsync(stZ, 0, zzBytes, stream);

    // ---- prologue: hist(256) | wsplit(96) | statsF(256) ----
    k_prologue<<<608, 256, 0, stream>>>(Wf, cWs, xcW, xoW, whiT, wloT,
            esrc, edst, cntD16, cntS16, rankE, rankS, E, x, stZ, N, WD);

    // ---- chunk-offset scan + totals, then joint 2N ptr scan, atomic-free fill ----
    k_chunkscan<<<gridCS, 256, 0, stream>>>(cntD16, cntS16, cntI, degU, WD, N);
    k_scanA<<<nb2, 1024, 0, stream>>>(cntI, ptrI, bsum, n2);
    k_scanB<<<1, 64, 0, stream>>>(bsum, ptrI + n2, nb2);
    k_scanC<<<nb2, 1024, 0, stream>>>(ptrI, bsum, n2);
    k_fill<<<gridE, 256, 0, stream>>>(esrc, edst, rankE, rankS, cntD16, cntS16,
            ptrI, degU, srcC, dstC, dstS, wU, E, N, WD, EC);

    // ---- h = relu(BN(x) @ W_feat) -> B1 (bf16) ----
    k_gemm<1, 0><<<gridG, 256, 0, stream>>>(x, nullptr, 0, stZ, whiT, wloT, B1, 128, 0, N);

    // ---- 3 x [BN -> GCNConv -> relu], prep fused into last gather ----
    for (int i = 0; i < 3; ++i){
        float* st = stZ + 256 * (i + 1);
        k_statsB<<<256, 256, 0, stream>>>(B1, st, N);
        k_gemm<0, 1><<<gridG, 256, 0, stream>>>(B1, nullptr, 0, st,
                whiT + (size_t)(i + 1) * 16384, wloT + (size_t)(i + 1) * 16384,
                B0, 128, 0, N);
        if (i < 2)
            k_gather0<0><<<PW_BLOCKS, 256, 0, stream>>>(ptrI, srcC, wU, degU, B0,
                    cbs + i * 128, B1, eW, naW, epre, ntT, N, NWAVES);
        else
            k_gather0<1><<<PW_BLOCKS, 256, 0, stream>>>(ptrI, srcC, wU, degU, B0,
                    cbs + i * 128, B1, eW, naW, epre, ntT, N, NWAVES);
    }

    // ---- attention: natt | eatt | degC0 merged (no atomics) ----
    k_eattnatt<<<gridN + gridE + gridN, 256, 0, stream>>>(srcC, dstC, dstS, epre, ebv,
            wB0, wB1, degC0, ptrI, wU, degU, ntT, nab, natt, E, N, gridN, gridE);

    // ---- branch stats (vectorized) | branch weights merged ----
    k_stats2wB<<<256 + gridE, 256, 0, stream>>>(B1, natt, stZ + 1024, N,
            srcC, degC0, degU, wB0, wB1, E);

    // ---- dual branch GEMM into B0c, then ONE persistent branch-split gather ----
    k_gemm2<<<dim3(gridG, 2), 256, 0, stream>>>(B1, natt, stZ + 1024, whiT, wloT, B0c, N);
    k_gatherP2<<<PW_BLOCKS, 256, 0, stream>>>(ptrI, srcC, wB0, wB1, degC0, degU, B0c,
                                              xcb, xob, batch, xcp, xop, N, span, NWB);

    // ---- heads: 3 heads fused per stage ----
    k_gstats3<<<3, 1024, 0, stream>>>(xcp, xop, mrsH, G);
    k_hgemm3<<<dim3(G, 3), 128, 0, stream>>>(xcp, xop, mrsH, cW1, cb1, oW1, ob1,
                                             coW1, cob1, gt3);
    k_gstats3b<<<3, 1024, 0, stream>>>(gt3, mrsH2, G);
    k_hfinal3<<<dim3((G + 3) / 4, 3), 256, 0, stream>>>(gt3, mrsH2, cW2, cb2, oW2, ob2,
                                                        coW2, cob2, out, G);
}